// Round 6
// baseline (666.499 us; speedup 1.0000x reference)
//
#include <hip/hip_runtime.h>
#include <math.h>

// B=2048, A=32 -> R=65536 rows. E_IN=160, H=128, HE=256, NACT=32, G=3, TAU=1.
#define R_TOTAL 65536

typedef __attribute__((ext_vector_type(8))) short short8_t;
typedef __attribute__((ext_vector_type(4))) float f32x4_t;

__device__ __forceinline__ float sigmoidf_(float x) { return 1.f / (1.f + expf(-x)); }

__device__ __forceinline__ short f2bf(float x) {
  unsigned u = __float_as_uint(x);
  u += 0x7fff + ((u >> 16) & 1);   // round-to-nearest-even
  return (short)(u >> 16);
}

// Load 8 consecutive floats -> bf16 fragment (RNE).
__device__ __forceinline__ void load_afrag(const float* p, short8_t& h) {
  float4 u0 = *(const float4*)p;
  float4 u1 = *(const float4*)(p + 4);
  float v[8] = {u0.x, u0.y, u0.z, u0.w, u1.x, u1.y, u1.z, u1.w};
#pragma unroll
  for (int i = 0; i < 8; ++i) h[i] = f2bf(v[i]);
}

#define MFMA(ACC, A, B) ACC = __builtin_amdgcn_mfma_f32_16x16x32_bf16(A, B, ACC, 0, 0, 0)

// ---------------- fused fragment pack: all weights in one launch ----------------
// packed p = ((ct*KK + kk)*64 + lane)*8 + i ; e = kk*32 + (lane>>4)*8 + i ; c = ct*16 + (lane&15)
struct PackSeg {
  const float* W;
  int Ksrc, N, KK, blk0, nblk;
  size_t off;
};
struct PackArgs { PackSeg s[11]; };

__global__ __launch_bounds__(256) void pack_all_kernel(PackArgs a, short* __restrict__ P) {
  const int b = blockIdx.x;
  PackSeg seg = a.s[0];
#pragma unroll
  for (int i = 1; i < 11; ++i)
    if (b >= a.s[i].blk0) seg = a.s[i];
  int p = (b - seg.blk0) * 256 + threadIdx.x;
  int i = p & 7, lane = (p >> 3) & 63, kk = (p >> 9) % seg.KK, ct = p / (seg.KK * 512);
  int e = kk * 32 + (lane >> 4) * 8 + i;
  int c = ct * 16 + (lane & 15);
  float w = (e < seg.Ksrc) ? seg.W[(size_t)e * seg.N + c] : 0.f;
  P[seg.off + p] = f2bf(w);
}

// ---------------- generic MFMA GEMM: C[R,N] = act(A[R,K(lda)] @ W + bias) ----------------
template <int KK, int NCT, int ACT>
__global__ __launch_bounds__(256) void mfma_gemm_kernel(
    const float* A, int lda, const short* __restrict__ Wp,
    const float* __restrict__ bias, float* C) {
  const int tid = threadIdx.x;
  const int wave = tid >> 6, lane = tid & 63;
  const int cl = lane & 15, kg = lane >> 4;
  const int row0 = blockIdx.x * 128 + wave * 32;
  constexpr int N = NCT * 16;
  short8_t ah[2][KK];
#pragma unroll
  for (int m = 0; m < 2; ++m) {
    const float* ap = A + (size_t)(row0 + m * 16 + cl) * lda;
#pragma unroll
    for (int kk = 0; kk < KK; ++kk) load_afrag(ap + kk * 32 + kg * 8, ah[m][kk]);
  }
  for (int ct = 0; ct < NCT; ++ct) {
    f32x4_t a0 = (f32x4_t){0.f, 0.f, 0.f, 0.f};
    f32x4_t a1 = (f32x4_t){0.f, 0.f, 0.f, 0.f};
#pragma unroll
    for (int kk = 0; kk < KK; ++kk) {
      short8_t b_h = *(const short8_t*)(Wp + (((size_t)ct * KK + kk) * 64 + lane) * 8);
      MFMA(a0, ah[0][kk], b_h);
      MFMA(a1, ah[1][kk], b_h);
    }
    int col = ct * 16 + cl;
    float bv = bias ? bias[col] : 0.f;
#pragma unroll
    for (int j = 0; j < 4; ++j) {
      float v0 = a0[j] + bv, v1 = a1[j] + bv;
      if (ACT == 1) { v0 = fmaxf(v0, 0.f); v1 = fmaxf(v1, 0.f); }
      if (ACT == 2) { v0 = tanhf(v0); v1 = tanhf(v1); }
      C[(size_t)(row0 + kg * 4 + j) * N + col] = v0;
      C[(size_t)(row0 + 16 + kg * 4 + j) * N + col] = v1;
    }
  }
}

// ---------------- MFMA GRU: h = GRUCell(x, h_in) ----------------
__global__ __launch_bounds__(256) void gru_mfma_kernel(
    const float* __restrict__ X, const float* __restrict__ Hin,
    const short* __restrict__ WiP, const short* __restrict__ WhP,
    const float* __restrict__ gbi, const float* __restrict__ gbh,
    float* __restrict__ Hout) {
  const int tid = threadIdx.x;
  const int wave = tid >> 6, lane = tid & 63;
  const int cl = lane & 15, kg = lane >> 4;
  const int row0 = blockIdx.x * 128 + wave * 32;
  short8_t xh[2][4], hh[2][4];
#pragma unroll
  for (int m = 0; m < 2; ++m) {
    const float* xp = X + (size_t)(row0 + m * 16 + cl) * 128;
    const float* hp = Hin + (size_t)(row0 + m * 16 + cl) * 128;
#pragma unroll
    for (int kk = 0; kk < 4; ++kk) {
      load_afrag(xp + kk * 32 + kg * 8, xh[m][kk]);
      load_afrag(hp + kk * 32 + kg * 8, hh[m][kk]);
    }
  }
#define GLOAD(P, CT) *(const short8_t*)((P) + (((size_t)(CT) * 4 + kk) * 64 + lane) * 8)
  for (int ct = 0; ct < 8; ++ct) {
    f32x4_t aXr[2], aXz[2], aXn[2], aHr[2], aHz[2], aHn[2];
#pragma unroll
    for (int m = 0; m < 2; ++m) {
      aXr[m] = (f32x4_t){0.f, 0.f, 0.f, 0.f};
      aXz[m] = (f32x4_t){0.f, 0.f, 0.f, 0.f};
      aXn[m] = (f32x4_t){0.f, 0.f, 0.f, 0.f};
      aHr[m] = (f32x4_t){0.f, 0.f, 0.f, 0.f};
      aHz[m] = (f32x4_t){0.f, 0.f, 0.f, 0.f};
      aHn[m] = (f32x4_t){0.f, 0.f, 0.f, 0.f};
    }
#pragma unroll
    for (int kk = 0; kk < 4; ++kk) {
      short8_t b_h;
      b_h = GLOAD(WiP, ct);      MFMA(aXr[0], xh[0][kk], b_h); MFMA(aXr[1], xh[1][kk], b_h);
      b_h = GLOAD(WiP, ct + 8);  MFMA(aXz[0], xh[0][kk], b_h); MFMA(aXz[1], xh[1][kk], b_h);
      b_h = GLOAD(WiP, ct + 16); MFMA(aXn[0], xh[0][kk], b_h); MFMA(aXn[1], xh[1][kk], b_h);
      b_h = GLOAD(WhP, ct);      MFMA(aHr[0], hh[0][kk], b_h); MFMA(aHr[1], hh[1][kk], b_h);
      b_h = GLOAD(WhP, ct + 8);  MFMA(aHz[0], hh[0][kk], b_h); MFMA(aHz[1], hh[1][kk], b_h);
      b_h = GLOAD(WhP, ct + 16); MFMA(aHn[0], hh[0][kk], b_h); MFMA(aHn[1], hh[1][kk], b_h);
    }
    int col = ct * 16 + cl;
    float bir = gbi[col], biz = gbi[128 + col], bin = gbi[256 + col];
    float bhr = gbh[col], bhz = gbh[128 + col], bhn = gbh[256 + col];
#pragma unroll
    for (int m = 0; m < 2; ++m)
#pragma unroll
      for (int j = 0; j < 4; ++j) {
        int row = row0 + m * 16 + kg * 4 + j;
        float rg = sigmoidf_(aXr[m][j] + aHr[m][j] + bir + bhr);
        float zg = sigmoidf_(aXz[m][j] + aHz[m][j] + biz + bhz);
        float ng = tanhf(aXn[m][j] + bin + rg * (aHn[m][j] + bhn));
        float hv = Hin[(size_t)row * 128 + col];
        Hout[(size_t)row * 128 + col] = (1.f - zg) * ng + zg * hv;
      }
  }
#undef GLOAD
}

// ---------------- attention block ----------------
__global__ __launch_bounds__(256) void attn_kernel(
    const float* __restrict__ QK, float* __restrict__ attn_out, float* __restrict__ si) {
  __shared__ float qs[32][129];
  __shared__ float ks[32][129];
  __shared__ float p[32][33];
  __shared__ float a2[32][33];
  const int b = blockIdx.x;
  const int tid = threadIdx.x;
  const float* qb = QK + (size_t)b * 8192;
  for (int i = tid; i < 4096; i += 256) {
    int r = i >> 7, e = i & 127;
    qs[r][e] = qb[r * 256 + e];
    ks[r][e] = qb[r * 256 + 128 + e];
  }
  __syncthreads();
  const float scale = 0.088388347648318447f;  // 1/sqrt(128)
#pragma unroll
  for (int tI = 0; tI < 4; ++tI) {
    int t = tid + tI * 256;
    int i = t >> 5, j = t & 31;
    float s = 0.f;
    for (int e = 0; e < 128; ++e) s = fmaf(qs[i][e], ks[j][e], s);
    p[i][j] = (i == j) ? -1e9f : s * scale;
  }
  __syncthreads();
  if (tid < 32) {
    const int i = tid;
    float m = -1e30f;
    for (int j = 0; j < 32; ++j) m = fmaxf(m, p[i][j]);
    float sum = 0.f;
    for (int j = 0; j < 32; ++j) {
      float e = expf(p[i][j] - m);
      p[i][j] = e;
      sum += e;
    }
    float inv = 1.f / sum;
    for (int j = 0; j < 32; ++j) p[i][j] *= inv;
  }
  __syncthreads();
#pragma unroll
  for (int tI = 0; tI < 4; ++tI) {
    int t = tid + tI * 256;
    int i = t >> 5, j = t & 31;
    float v = (i == j) ? 0.f : 0.5f * (p[i][j] + p[j][i]);
    a2[i][j] = v;
    attn_out[(size_t)b * 1024 + t] = v;
  }
  __syncthreads();
  if (tid < 32) {
    const int i = tid;
    float d = 0.f, en = 0.f;
    for (int j = 0; j < 32; ++j) {
      float v = a2[i][j];
      d += v;
      float c = fmaxf(v, 1e-8f);
      en -= c * logf(c);
    }
    float* srow = si + ((size_t)b * 32 + i) * 64;
    for (int j = 0; j < 32; ++j) srow[j] = a2[i][j];
    srow[32] = d;
    srow[33] = en;
    for (int j = 34; j < 64; ++j) srow[j] = 0.f;
  }
}

// ---------------- group assign ----------------
__global__ __launch_bounds__(256) void group_kernel(
    const float* __restrict__ sf, const float* __restrict__ ga_w,
    const float* __restrict__ ga_b, const float* __restrict__ gemb,
    float* __restrict__ probs, float* __restrict__ tout) {
  const size_t r = (size_t)blockIdx.x * 4 + (threadIdx.x >> 6);
  const int lane = threadIdx.x & 63;
  const int e = lane * 4;
  const float4 s4 = *(const float4*)(sf + r * 256 + e);
  float lg[3];
#pragma unroll
  for (int g = 0; g < 3; ++g) {
    lg[g] = s4.x * ga_w[(e + 0) * 3 + g] + s4.y * ga_w[(e + 1) * 3 + g] +
            s4.z * ga_w[(e + 2) * 3 + g] + s4.w * ga_w[(e + 3) * 3 + g];
  }
#pragma unroll
  for (int off = 32; off; off >>= 1) {
#pragma unroll
    for (int g = 0; g < 3; ++g) lg[g] += __shfl_xor(lg[g], off, 64);
  }
#pragma unroll
  for (int g = 0; g < 3; ++g) lg[g] += ga_b[g];
  float m = fmaxf(lg[0], fmaxf(lg[1], lg[2]));
  float e0 = expf(lg[0] - m), e1 = expf(lg[1] - m), e2 = expf(lg[2] - m);
  float inv = 1.f / (e0 + e1 + e2);
  float p0 = e0 * inv, p1 = e1 * inv, p2 = e2 * inv;
  if (lane == 0) probs[r * 3 + 0] = p0;
  if (lane == 1) probs[r * 3 + 1] = p1;
  if (lane == 2) probs[r * 3 + 2] = p2;
  float4 t4;
  t4.x = s4.x + p0 * gemb[e + 0] + p1 * gemb[256 + e + 0] + p2 * gemb[512 + e + 0];
  t4.y = s4.y + p0 * gemb[e + 1] + p1 * gemb[256 + e + 1] + p2 * gemb[512 + e + 1];
  t4.z = s4.z + p0 * gemb[e + 2] + p1 * gemb[256 + e + 2] + p2 * gemb[512 + e + 2];
  t4.w = s4.w + p0 * gemb[e + 3] + p1 * gemb[256 + e + 3] + p2 * gemb[512 + e + 3];
  *(float4*)(tout + r * 256 + e) = t4;
}

// ---------------- MFMA hypernet q v4: column-split, no LDS, direct-L2 B reads ----------------
// Grid 512: blocks 0..255 = half 0 (h 0..63, chunks 0..127 + hb_w), 256..511 = half 1
// (h 64..127, chunks 128..255). 4 waves x 64 rows, BM=256. No barriers; W (2MB) L2-resident.
// Writes partial q to Qpart[half]; combine kernel sums + hb_b.
__global__ __launch_bounds__(256, 2) void hyper_q_nolds_kernel(
    const float* __restrict__ GS, const float* __restrict__ Hh,
    const short* __restrict__ Wp, const float* __restrict__ hwb,
    float* __restrict__ Qpart) {
  const int tid = threadIdx.x;
  const int wave = tid >> 6, lane = tid & 63;
  const int cl = lane & 15, kg = lane >> 4;
  const int half = blockIdx.x >> 8;
  const int wrow = (blockIdx.x & 255) * 256 + wave * 64;

  // ---- A (gs) -> registers as bf16 fragments: 4 m-frags x 8 kk ----
  short8_t ah[4][8];
#pragma unroll
  for (int m = 0; m < 4; ++m) {
    const float* ap = GS + (size_t)(wrow + m * 16 + cl) * 256;
#pragma unroll
    for (int kk = 0; kk < 8; ++kk) load_afrag(ap + kk * 32 + kg * 8, ah[m][kk]);
  }

  float qf[4][2][4] = {};  // [m][oh][j]
  const int ct_base = half * 128;

  for (int t2 = 0; t2 < 64; ++t2) {
    // h column for this wave's 64 rows (16 values/lane; same for cl group -> L1 broadcast)
    float hc[16];
    {
      const float* hp = Hh + (size_t)(wrow + kg * 4) * 128 + half * 64 + t2;
#pragma unroll
      for (int m = 0; m < 4; ++m)
#pragma unroll
        for (int j = 0; j < 4; ++j)
          hc[m * 4 + j] = hp[(size_t)(m * 16 + j) * 128];
    }
#pragma unroll
    for (int oh = 0; oh < 2; ++oh) {
      const int ct = ct_base + t2 * 2 + oh;
      const float wb = hwb[ct * 16 + cl];
      f32x4_t acc[4];
#pragma unroll
      for (int m = 0; m < 4; ++m) acc[m] = (f32x4_t){0.f, 0.f, 0.f, 0.f};
      const short* wp = Wp + ((size_t)ct * 8 * 64 + lane) * 8;
#pragma unroll
      for (int kk = 0; kk < 8; ++kk) {
        short8_t b_h = *(const short8_t*)(wp + (size_t)kk * 512);
#pragma unroll
        for (int m = 0; m < 4; ++m) MFMA(acc[m], ah[m][kk], b_h);
      }
#pragma unroll
      for (int m = 0; m < 4; ++m)
#pragma unroll
        for (int j = 0; j < 4; ++j)
          qf[m][oh][j] = fmaf(hc[m * 4 + j], acc[m][j] + wb, qf[m][oh][j]);
    }
  }

  // ---- half 0 adds fc2_b = gs @ hb_w via packed chunks 256/257 ----
  if (half == 0) {
#pragma unroll
    for (int oh = 0; oh < 2; ++oh) {
      f32x4_t bacc[4];
#pragma unroll
      for (int m = 0; m < 4; ++m) bacc[m] = (f32x4_t){0.f, 0.f, 0.f, 0.f};
#pragma unroll
      for (int kk = 0; kk < 8; ++kk) {
        short8_t b_h = *(const short8_t*)(Wp + (((size_t)(256 + oh) * 8 + kk) * 64 + lane) * 8);
#pragma unroll
        for (int m = 0; m < 4; ++m) MFMA(bacc[m], ah[m][kk], b_h);
      }
#pragma unroll
      for (int m = 0; m < 4; ++m)
#pragma unroll
        for (int j = 0; j < 4; ++j) qf[m][oh][j] += bacc[m][j];
    }
  }

  // ---- write partial q (rows disjoint per wave within a half) ----
  float* qp = Qpart + (size_t)half * 2097152;
#pragma unroll
  for (int m = 0; m < 4; ++m)
#pragma unroll
    for (int j = 0; j < 4; ++j) {
      const size_t r = (size_t)(wrow + m * 16 + kg * 4 + j) * 32;
      qp[r + cl] = qf[m][0][j];
      qp[r + 16 + cl] = qf[m][1][j];
    }
}

// ---------------- combine: q = qpart0 + qpart1 + hb_b ----------------
__global__ __launch_bounds__(256) void qcombine_kernel(
    const float* __restrict__ Qpart, const float* __restrict__ hbb,
    float* __restrict__ Qout) {
  int i = blockIdx.x * 256 + threadIdx.x;  // 524288 float4s
  float4 a = ((const float4*)Qpart)[i];
  float4 b = ((const float4*)(Qpart + 2097152))[i];
  float4 c = ((const float4*)hbb)[i & 7];
  ((float4*)Qout)[i] = make_float4(a.x + b.x + c.x, a.y + b.y + c.y,
                                   a.z + b.z + c.z, a.w + b.w + c.w);
}

extern "C" void kernel_launch(void* const* d_in, const int* in_sizes, int n_in,
                              void* d_out, int out_size, void* d_ws, size_t ws_size,
                              hipStream_t stream) {
  const float* inputs   = (const float*)d_in[0];
  const float* hidden   = (const float*)d_in[1];
  const float* fc1_w    = (const float*)d_in[2];
  const float* fc1_b    = (const float*)d_in[3];
  const float* gru_wi   = (const float*)d_in[4];
  const float* gru_wh   = (const float*)d_in[5];
  const float* gru_bi   = (const float*)d_in[6];
  const float* gru_bh   = (const float*)d_in[7];
  const float* attn_q_w = (const float*)d_in[8];
  const float* attn_k_w = (const float*)d_in[9];
  const float* se1_w    = (const float*)d_in[10];
  const float* se1_b    = (const float*)d_in[11];
  const float* se2_w    = (const float*)d_in[12];
  const float* se2_b    = (const float*)d_in[13];
  const float* ga_w     = (const float*)d_in[14];
  const float* ga_b     = (const float*)d_in[15];
  const float* gemb     = (const float*)d_in[16];
  const float* gd1_w    = (const float*)d_in[17];
  const float* gd1_b    = (const float*)d_in[18];
  const float* gd2_w    = (const float*)d_in[19];
  const float* gd2_b    = (const float*)d_in[20];
  const float* hb_w     = (const float*)d_in[21];
  const float* hb_b     = (const float*)d_in[22];
  const float* hw_w     = (const float*)d_in[23];
  const float* hw_b     = (const float*)d_in[24];

  float* out = (float*)d_out;
  float* q_out     = out;              // [R,32]
  float* h_out     = out + 2097152;    // [R,128]
  float* gs_out    = out + 10485760;   // [R,256]
  float* probs_out = out + 27262976;   // [R,3]
  float* attn_out  = out + 27459584;   // [B,32,32]

  // workspace layout:
  //   region0 [0, 64MiB):  qk [R,256] -> s1 -> t (gd1 in-place) -> qpart [2][R,32] (16MB)
  //   si      [64, 80MiB): [R,64] padded struct_input
  //   x1      [80, 112MiB): [R,128]
  //   packs   [112MiB, +2.9MiB)
  float* ws = (float*)d_ws;
  float* qk = ws;
  float* s1 = ws;
  float* t  = ws;
  float* qpart = ws;                   // reuses region0 after t is dead
  float* si = ws + 16777216;
  float* x1 = ws + 16777216 + 4194304;
  short* P  = (short*)((char*)d_ws + (size_t)112 * 1024 * 1024);

  // pack offsets (shorts); chunk = KK*512 shorts
  const size_t o_hw  = 0;        // K=256 KK=8, N=4096 -> 1,048,576
  const size_t o_hb  = 1048576;  // chunks 256..257 of hw base
  const size_t o_fc1 = 1056768;
  const size_t o_wi  = 1077248;
  const size_t o_wh  = 1126400;
  const size_t o_qkq = 1175552;
  const size_t o_qkk = 1191936;
  const size_t o_se1 = 1208320;
  const size_t o_se2 = 1224704;
  const size_t o_gd1 = 1290240;
  const size_t o_gd2 = 1355776;

  PackArgs pa;
  pa.s[0]  = {hw_w,     256, 4096, 8, 0,    4096, o_hw};
  pa.s[1]  = {hb_w,     256, 32,   8, 4096, 32,   o_hb};
  pa.s[2]  = {fc1_w,    160, 128,  5, 4128, 80,   o_fc1};
  pa.s[3]  = {gru_wi,   128, 384,  4, 4208, 192,  o_wi};
  pa.s[4]  = {gru_wh,   128, 384,  4, 4400, 192,  o_wh};
  pa.s[5]  = {attn_q_w, 128, 128,  4, 4592, 64,   o_qkq};
  pa.s[6]  = {attn_k_w, 128, 128,  4, 4656, 64,   o_qkk};
  pa.s[7]  = {se1_w,    34,  256,  2, 4720, 64,   o_se1};
  pa.s[8]  = {se2_w,    256, 256,  8, 4784, 256,  o_se2};
  pa.s[9]  = {gd1_w,    256, 256,  8, 5040, 256,  o_gd1};
  pa.s[10] = {gd2_w,    256, 256,  8, 5296, 256,  o_gd2};

  dim3 blk(256);
  // 0) pack ALL weights in one launch
  pack_all_kernel<<<5552, blk, 0, stream>>>(pa, P);
  // 1) x1 = relu(inputs @ fc1_w + fc1_b)            K=160 N=128
  mfma_gemm_kernel<5, 8, 1><<<512, blk, 0, stream>>>(inputs, 160, P + o_fc1, fc1_b, x1);
  // 2) h = GRUCell(x1, hidden)
  gru_mfma_kernel<<<512, blk, 0, stream>>>(x1, hidden, P + o_wi, P + o_wh, gru_bi, gru_bh, h_out);
  // 3) qk = h @ [attn_q_w | attn_k_w]               K=128 N=256
  mfma_gemm_kernel<4, 16, 0><<<512, blk, 0, stream>>>(h_out, 128, P + o_qkq, nullptr, qk);
  // 4) attention -> attn_out + padded struct_input
  attn_kernel<<<2048, blk, 0, stream>>>(qk, attn_out, si);
  // 5) s1 = relu(si @ se1_w + se1_b)                K=64(pad) N=256
  mfma_gemm_kernel<2, 16, 1><<<512, blk, 0, stream>>>(si, 64, P + o_se1, se1_b, s1);
  // 6) struct_feat = tanh(s1 @ se2_w + se2_b) -> staged in gs_out
  mfma_gemm_kernel<8, 16, 2><<<512, blk, 0, stream>>>(s1, 256, P + o_se2, se2_b, gs_out);
  // 7) probs + t = sf + probs@group_emb
  group_kernel<<<16384, blk, 0, stream>>>(gs_out, ga_w, ga_b, gemb, probs_out, t);
  // 8) g1 = relu(t @ gd1_w + gd1_b)  (in-place)
  mfma_gemm_kernel<8, 16, 1><<<512, blk, 0, stream>>>(t, 256, P + o_gd1, gd1_b, t);
  // 9) group_state = tanh(g1 @ gd2_w + gd2_b) -> gs_out
  mfma_gemm_kernel<8, 16, 2><<<512, blk, 0, stream>>>(t, 256, P + o_gd2, gd2_b, gs_out);
  // 10) q partials: column-split no-LDS MFMA hypernet (t dead -> qpart reuses region0)
  hyper_q_nolds_kernel<<<dim3(512), blk, 0, stream>>>(gs_out, h_out, P + o_hw, hw_b, qpart);
  // 11) q = qpart0 + qpart1 + hb_b
  qcombine_kernel<<<2048, blk, 0, stream>>>(qpart, hb_b, q_out);
}

// Round 7
// 571.455 us; speedup vs baseline: 1.1663x; 1.1663x over previous
//
#include <hip/hip_runtime.h>
#include <math.h>

// B=2048, A=32 -> R=65536 rows. E_IN=160, H=128, HE=256, NACT=32, G=3, TAU=1.
#define R_TOTAL 65536

typedef __attribute__((ext_vector_type(8))) short short8_t;
typedef __attribute__((ext_vector_type(4))) float f32x4_t;

__device__ __forceinline__ float sigmoidf_(float x) { return 1.f / (1.f + expf(-x)); }

__device__ __forceinline__ short f2bf(float x) {
  unsigned u = __float_as_uint(x);
  u += 0x7fff + ((u >> 16) & 1);   // round-to-nearest-even
  return (short)(u >> 16);
}

// Load 8 consecutive floats -> bf16 fragment (RNE).
__device__ __forceinline__ void load_afrag(const float* p, short8_t& h) {
  float4 u0 = *(const float4*)p;
  float4 u1 = *(const float4*)(p + 4);
  float v[8] = {u0.x, u0.y, u0.z, u0.w, u1.x, u1.y, u1.z, u1.w};
#pragma unroll
  for (int i = 0; i < 8; ++i) h[i] = f2bf(v[i]);
}

#define MFMA(ACC, A, B) ACC = __builtin_amdgcn_mfma_f32_16x16x32_bf16(A, B, ACC, 0, 0, 0)

// ---------------- fused fragment pack: all weights in one launch ----------------
// packed p = ((ct*KK + kk)*64 + lane)*8 + i ; e = kk*32 + (lane>>4)*8 + i ; c = ct*16 + (lane&15)
struct PackSeg {
  const float* W;
  int Ksrc, N, KK, blk0, nblk;
  size_t off;
};
struct PackArgs { PackSeg s[11]; };

__global__ __launch_bounds__(256) void pack_all_kernel(PackArgs a, short* __restrict__ P) {
  const int b = blockIdx.x;
  PackSeg seg = a.s[0];
#pragma unroll
  for (int i = 1; i < 11; ++i)
    if (b >= a.s[i].blk0) seg = a.s[i];
  int p = (b - seg.blk0) * 256 + threadIdx.x;
  int i = p & 7, lane = (p >> 3) & 63, kk = (p >> 9) % seg.KK, ct = p / (seg.KK * 512);
  int e = kk * 32 + (lane >> 4) * 8 + i;
  int c = ct * 16 + (lane & 15);
  float w = (e < seg.Ksrc) ? seg.W[(size_t)e * seg.N + c] : 0.f;
  P[seg.off + p] = f2bf(w);
}

// ---------------- generic MFMA GEMM: C[R,N] = act(A[R,K(lda)] @ W + bias) ----------------
template <int KK, int NCT, int ACT>
__global__ __launch_bounds__(256) void mfma_gemm_kernel(
    const float* A, int lda, const short* __restrict__ Wp,
    const float* __restrict__ bias, float* C) {
  const int tid = threadIdx.x;
  const int wave = tid >> 6, lane = tid & 63;
  const int cl = lane & 15, kg = lane >> 4;
  const int row0 = blockIdx.x * 128 + wave * 32;
  constexpr int N = NCT * 16;
  short8_t ah[2][KK];
#pragma unroll
  for (int m = 0; m < 2; ++m) {
    const float* ap = A + (size_t)(row0 + m * 16 + cl) * lda;
#pragma unroll
    for (int kk = 0; kk < KK; ++kk) load_afrag(ap + kk * 32 + kg * 8, ah[m][kk]);
  }
  for (int ct = 0; ct < NCT; ++ct) {
    f32x4_t a0 = (f32x4_t){0.f, 0.f, 0.f, 0.f};
    f32x4_t a1 = (f32x4_t){0.f, 0.f, 0.f, 0.f};
#pragma unroll
    for (int kk = 0; kk < KK; ++kk) {
      short8_t b_h = *(const short8_t*)(Wp + (((size_t)ct * KK + kk) * 64 + lane) * 8);
      MFMA(a0, ah[0][kk], b_h);
      MFMA(a1, ah[1][kk], b_h);
    }
    int col = ct * 16 + cl;
    float bv = bias ? bias[col] : 0.f;
#pragma unroll
    for (int j = 0; j < 4; ++j) {
      float v0 = a0[j] + bv, v1 = a1[j] + bv;
      if (ACT == 1) { v0 = fmaxf(v0, 0.f); v1 = fmaxf(v1, 0.f); }
      if (ACT == 2) { v0 = tanhf(v0); v1 = tanhf(v1); }
      C[(size_t)(row0 + kg * 4 + j) * N + col] = v0;
      C[(size_t)(row0 + 16 + kg * 4 + j) * N + col] = v1;
    }
  }
}

// ---------------- MFMA GRU: h = GRUCell(x, h_in) ----------------
__global__ __launch_bounds__(256) void gru_mfma_kernel(
    const float* __restrict__ X, const float* __restrict__ Hin,
    const short* __restrict__ WiP, const short* __restrict__ WhP,
    const float* __restrict__ gbi, const float* __restrict__ gbh,
    float* __restrict__ Hout) {
  const int tid = threadIdx.x;
  const int wave = tid >> 6, lane = tid & 63;
  const int cl = lane & 15, kg = lane >> 4;
  const int row0 = blockIdx.x * 128 + wave * 32;
  short8_t xh[2][4], hh[2][4];
#pragma unroll
  for (int m = 0; m < 2; ++m) {
    const float* xp = X + (size_t)(row0 + m * 16 + cl) * 128;
    const float* hp = Hin + (size_t)(row0 + m * 16 + cl) * 128;
#pragma unroll
    for (int kk = 0; kk < 4; ++kk) {
      load_afrag(xp + kk * 32 + kg * 8, xh[m][kk]);
      load_afrag(hp + kk * 32 + kg * 8, hh[m][kk]);
    }
  }
#define GLOAD(P, CT) *(const short8_t*)((P) + (((size_t)(CT) * 4 + kk) * 64 + lane) * 8)
  for (int ct = 0; ct < 8; ++ct) {
    f32x4_t aXr[2], aXz[2], aXn[2], aHr[2], aHz[2], aHn[2];
#pragma unroll
    for (int m = 0; m < 2; ++m) {
      aXr[m] = (f32x4_t){0.f, 0.f, 0.f, 0.f};
      aXz[m] = (f32x4_t){0.f, 0.f, 0.f, 0.f};
      aXn[m] = (f32x4_t){0.f, 0.f, 0.f, 0.f};
      aHr[m] = (f32x4_t){0.f, 0.f, 0.f, 0.f};
      aHz[m] = (f32x4_t){0.f, 0.f, 0.f, 0.f};
      aHn[m] = (f32x4_t){0.f, 0.f, 0.f, 0.f};
    }
#pragma unroll
    for (int kk = 0; kk < 4; ++kk) {
      short8_t b_h;
      b_h = GLOAD(WiP, ct);      MFMA(aXr[0], xh[0][kk], b_h); MFMA(aXr[1], xh[1][kk], b_h);
      b_h = GLOAD(WiP, ct + 8);  MFMA(aXz[0], xh[0][kk], b_h); MFMA(aXz[1], xh[1][kk], b_h);
      b_h = GLOAD(WiP, ct + 16); MFMA(aXn[0], xh[0][kk], b_h); MFMA(aXn[1], xh[1][kk], b_h);
      b_h = GLOAD(WhP, ct);      MFMA(aHr[0], hh[0][kk], b_h); MFMA(aHr[1], hh[1][kk], b_h);
      b_h = GLOAD(WhP, ct + 8);  MFMA(aHz[0], hh[0][kk], b_h); MFMA(aHz[1], hh[1][kk], b_h);
      b_h = GLOAD(WhP, ct + 16); MFMA(aHn[0], hh[0][kk], b_h); MFMA(aHn[1], hh[1][kk], b_h);
    }
    int col = ct * 16 + cl;
    float bir = gbi[col], biz = gbi[128 + col], bin = gbi[256 + col];
    float bhr = gbh[col], bhz = gbh[128 + col], bhn = gbh[256 + col];
#pragma unroll
    for (int m = 0; m < 2; ++m)
#pragma unroll
      for (int j = 0; j < 4; ++j) {
        int row = row0 + m * 16 + kg * 4 + j;
        float rg = sigmoidf_(aXr[m][j] + aHr[m][j] + bir + bhr);
        float zg = sigmoidf_(aXz[m][j] + aHz[m][j] + biz + bhz);
        float ng = tanhf(aXn[m][j] + bin + rg * (aHn[m][j] + bhn));
        float hv = Hin[(size_t)row * 128 + col];
        Hout[(size_t)row * 128 + col] = (1.f - zg) * ng + zg * hv;
      }
  }
#undef GLOAD
}

// ---------------- attention block ----------------
__global__ __launch_bounds__(256) void attn_kernel(
    const float* __restrict__ QK, float* __restrict__ attn_out, float* __restrict__ si) {
  __shared__ float qs[32][129];
  __shared__ float ks[32][129];
  __shared__ float p[32][33];
  __shared__ float a2[32][33];
  const int b = blockIdx.x;
  const int tid = threadIdx.x;
  const float* qb = QK + (size_t)b * 8192;
  for (int i = tid; i < 4096; i += 256) {
    int r = i >> 7, e = i & 127;
    qs[r][e] = qb[r * 256 + e];
    ks[r][e] = qb[r * 256 + 128 + e];
  }
  __syncthreads();
  const float scale = 0.088388347648318447f;  // 1/sqrt(128)
#pragma unroll
  for (int tI = 0; tI < 4; ++tI) {
    int t = tid + tI * 256;
    int i = t >> 5, j = t & 31;
    float s = 0.f;
    for (int e = 0; e < 128; ++e) s = fmaf(qs[i][e], ks[j][e], s);
    p[i][j] = (i == j) ? -1e9f : s * scale;
  }
  __syncthreads();
  if (tid < 32) {
    const int i = tid;
    float m = -1e30f;
    for (int j = 0; j < 32; ++j) m = fmaxf(m, p[i][j]);
    float sum = 0.f;
    for (int j = 0; j < 32; ++j) {
      float e = expf(p[i][j] - m);
      p[i][j] = e;
      sum += e;
    }
    float inv = 1.f / sum;
    for (int j = 0; j < 32; ++j) p[i][j] *= inv;
  }
  __syncthreads();
#pragma unroll
  for (int tI = 0; tI < 4; ++tI) {
    int t = tid + tI * 256;
    int i = t >> 5, j = t & 31;
    float v = (i == j) ? 0.f : 0.5f * (p[i][j] + p[j][i]);
    a2[i][j] = v;
    attn_out[(size_t)b * 1024 + t] = v;
  }
  __syncthreads();
  if (tid < 32) {
    const int i = tid;
    float d = 0.f, en = 0.f;
    for (int j = 0; j < 32; ++j) {
      float v = a2[i][j];
      d += v;
      float c = fmaxf(v, 1e-8f);
      en -= c * logf(c);
    }
    float* srow = si + ((size_t)b * 32 + i) * 64;
    for (int j = 0; j < 32; ++j) srow[j] = a2[i][j];
    srow[32] = d;
    srow[33] = en;
    for (int j = 34; j < 64; ++j) srow[j] = 0.f;
  }
}

// ---------------- group assign ----------------
__global__ __launch_bounds__(256) void group_kernel(
    const float* __restrict__ sf, const float* __restrict__ ga_w,
    const float* __restrict__ ga_b, const float* __restrict__ gemb,
    float* __restrict__ probs, float* __restrict__ tout) {
  const size_t r = (size_t)blockIdx.x * 4 + (threadIdx.x >> 6);
  const int lane = threadIdx.x & 63;
  const int e = lane * 4;
  const float4 s4 = *(const float4*)(sf + r * 256 + e);
  float lg[3];
#pragma unroll
  for (int g = 0; g < 3; ++g) {
    lg[g] = s4.x * ga_w[(e + 0) * 3 + g] + s4.y * ga_w[(e + 1) * 3 + g] +
            s4.z * ga_w[(e + 2) * 3 + g] + s4.w * ga_w[(e + 3) * 3 + g];
  }
#pragma unroll
  for (int off = 32; off; off >>= 1) {
#pragma unroll
    for (int g = 0; g < 3; ++g) lg[g] += __shfl_xor(lg[g], off, 64);
  }
#pragma unroll
  for (int g = 0; g < 3; ++g) lg[g] += ga_b[g];
  float m = fmaxf(lg[0], fmaxf(lg[1], lg[2]));
  float e0 = expf(lg[0] - m), e1 = expf(lg[1] - m), e2 = expf(lg[2] - m);
  float inv = 1.f / (e0 + e1 + e2);
  float p0 = e0 * inv, p1 = e1 * inv, p2 = e2 * inv;
  if (lane == 0) probs[r * 3 + 0] = p0;
  if (lane == 1) probs[r * 3 + 1] = p1;
  if (lane == 2) probs[r * 3 + 2] = p2;
  float4 t4;
  t4.x = s4.x + p0 * gemb[e + 0] + p1 * gemb[256 + e + 0] + p2 * gemb[512 + e + 0];
  t4.y = s4.y + p0 * gemb[e + 1] + p1 * gemb[256 + e + 1] + p2 * gemb[512 + e + 1];
  t4.z = s4.z + p0 * gemb[e + 2] + p1 * gemb[256 + e + 2] + p2 * gemb[512 + e + 2];
  t4.w = s4.w + p0 * gemb[e + 3] + p1 * gemb[256 + e + 3] + p2 * gemb[512 + e + 3];
  *(float4*)(tout + r * 256 + e) = t4;
}

// ---------------- MFMA hypernet q v5: column-split + LDS dbuf (conflict-free writes) --------
// Grid 512: blocks 0..255 = half 0 (h 0..63, chunks 0..127 + hb_w), 256..511 = half 1.
// 4 waves x 64 rows (BM=256). W chunk (8KB) double-buffered in LDS; staging writes are
// 16B-contiguous per thread (no bank conflicts). Partial q -> combine kernel.
__global__ __launch_bounds__(256, 2) void hyper_q_v5_kernel(
    const float* __restrict__ GS, const float* __restrict__ Hh,
    const short* __restrict__ Wp, const float* __restrict__ hwb,
    float* __restrict__ Qpart) {
  __shared__ short Bh[2][4096];   // 16 KB: two 8KB chunk buffers
  const int tid = threadIdx.x;
  const int wave = tid >> 6, lane = tid & 63;
  const int cl = lane & 15, kg = lane >> 4;
  const int half = blockIdx.x >> 8;
  const int wrow = (blockIdx.x & 255) * 256 + wave * 64;
  const int ct_base = half * 128;

  // ---- A (gs) -> registers as bf16 fragments: 4 m-frags x 8 kk ----
  short8_t ah[4][8];
#pragma unroll
  for (int m = 0; m < 4; ++m) {
    const float* ap = GS + (size_t)(wrow + m * 16 + cl) * 256;
#pragma unroll
    for (int kk = 0; kk < 8; ++kk) load_afrag(ap + kk * 32 + kg * 8, ah[m][kk]);
  }

  // ---- prologue: stage chunk ct_base into buf 0 (conflict-free: 16B contiguous/thread) ----
  {
    const short* wp0 = Wp + (size_t)ct_base * 4096;
    short8_t v0 = *(const short8_t*)(wp0 + tid * 8);
    short8_t v1 = *(const short8_t*)(wp0 + 2048 + tid * 8);
    *(short8_t*)&Bh[0][tid * 8] = v0;
    *(short8_t*)&Bh[0][2048 + tid * 8] = v1;
  }
  __syncthreads();

  float qf[4][2][4] = {};  // [m][oh][j]

#define COMPUTE_HALF(BUF, OH, WB)                                              \
  {                                                                            \
    f32x4_t acc[4];                                                            \
    _Pragma("unroll")                                                          \
    for (int m = 0; m < 4; ++m) acc[m] = (f32x4_t){0.f, 0.f, 0.f, 0.f};        \
    _Pragma("unroll")                                                          \
    for (int kk = 0; kk < 8; ++kk) {                                           \
      short8_t b_h = *(const short8_t*)&Bh[BUF][(kk * 64 + lane) * 8];         \
      _Pragma("unroll")                                                        \
      for (int m = 0; m < 4; ++m) MFMA(acc[m], ah[m][kk], b_h);                \
    }                                                                          \
    _Pragma("unroll")                                                          \
    for (int m = 0; m < 4; ++m)                                                \
      _Pragma("unroll")                                                        \
      for (int j = 0; j < 4; ++j)                                              \
        qf[m][OH][j] = fmaf(hc[m * 4 + j], acc[m][j] + (WB), qf[m][OH][j]);    \
  }

  for (int t2 = 0; t2 < 64; ++t2) {
    const int ct0 = ct_base + t2 * 2;
    // h column (half*64 + t2) for this wave's 64 rows
    float hc[16];
    {
      const float* hp = Hh + (size_t)(wrow + kg * 4) * 128 + half * 64 + t2;
#pragma unroll
      for (int m = 0; m < 4; ++m)
#pragma unroll
        for (int j = 0; j < 4; ++j)
          hc[m * 4 + j] = hp[(size_t)(m * 16 + j) * 128];
    }
    float wb0 = hwb[ct0 * 16 + cl];
    float wb1 = hwb[(ct0 + 1) * 16 + cl];
    // prefetch chunk ct0+1 into registers
    const short* wp1 = Wp + (size_t)(ct0 + 1) * 4096;
    short8_t s1a = *(const short8_t*)(wp1 + tid * 8);
    short8_t s1b = *(const short8_t*)(wp1 + 2048 + tid * 8);
    COMPUTE_HALF(0, 0, wb0)
    *(short8_t*)&Bh[1][tid * 8] = s1a;
    *(short8_t*)&Bh[1][2048 + tid * 8] = s1b;
    __syncthreads();
    short8_t s2a, s2b;
    if (t2 < 63) {
      const short* wp2 = Wp + (size_t)(ct0 + 2) * 4096;
      s2a = *(const short8_t*)(wp2 + tid * 8);
      s2b = *(const short8_t*)(wp2 + 2048 + tid * 8);
    }
    COMPUTE_HALF(1, 1, wb1)
    if (t2 < 63) {
      *(short8_t*)&Bh[0][tid * 8] = s2a;
      *(short8_t*)&Bh[0][2048 + tid * 8] = s2b;
    }
    __syncthreads();
  }
#undef COMPUTE_HALF

  // ---- half 0 adds fc2_b = gs @ hb_w via packed chunks 256/257 (direct from L2) ----
  if (half == 0) {
#pragma unroll
    for (int oh = 0; oh < 2; ++oh) {
      f32x4_t bacc[4];
#pragma unroll
      for (int m = 0; m < 4; ++m) bacc[m] = (f32x4_t){0.f, 0.f, 0.f, 0.f};
#pragma unroll
      for (int kk = 0; kk < 8; ++kk) {
        short8_t b_h = *(const short8_t*)(Wp + (((size_t)(256 + oh) * 8 + kk) * 64 + lane) * 8);
#pragma unroll
        for (int m = 0; m < 4; ++m) MFMA(bacc[m], ah[m][kk], b_h);
      }
#pragma unroll
      for (int m = 0; m < 4; ++m)
#pragma unroll
        for (int j = 0; j < 4; ++j) qf[m][oh][j] += bacc[m][j];
    }
  }

  // ---- write partial q (rows disjoint per wave within a half) ----
  float* qp = Qpart + (size_t)half * 2097152;
#pragma unroll
  for (int m = 0; m < 4; ++m)
#pragma unroll
    for (int j = 0; j < 4; ++j) {
      const size_t r = (size_t)(wrow + m * 16 + kg * 4 + j) * 32;
      qp[r + cl] = qf[m][0][j];
      qp[r + 16 + cl] = qf[m][1][j];
    }
}

// ---------------- combine: q = qpart0 + qpart1 + hb_b ----------------
__global__ __launch_bounds__(256) void qcombine_kernel(
    const float* __restrict__ Qpart, const float* __restrict__ hbb,
    float* __restrict__ Qout) {
  int i = blockIdx.x * 256 + threadIdx.x;  // 524288 float4s
  float4 a = ((const float4*)Qpart)[i];
  float4 b = ((const float4*)(Qpart + 2097152))[i];
  float4 c = ((const float4*)hbb)[i & 7];
  ((float4*)Qout)[i] = make_float4(a.x + b.x + c.x, a.y + b.y + c.y,
                                   a.z + b.z + c.z, a.w + b.w + c.w);
}

extern "C" void kernel_launch(void* const* d_in, const int* in_sizes, int n_in,
                              void* d_out, int out_size, void* d_ws, size_t ws_size,
                              hipStream_t stream) {
  const float* inputs   = (const float*)d_in[0];
  const float* hidden   = (const float*)d_in[1];
  const float* fc1_w    = (const float*)d_in[2];
  const float* fc1_b    = (const float*)d_in[3];
  const float* gru_wi   = (const float*)d_in[4];
  const float* gru_wh   = (const float*)d_in[5];
  const float* gru_bi   = (const float*)d_in[6];
  const float* gru_bh   = (const float*)d_in[7];
  const float* attn_q_w = (const float*)d_in[8];
  const float* attn_k_w = (const float*)d_in[9];
  const float* se1_w    = (const float*)d_in[10];
  const float* se1_b    = (const float*)d_in[11];
  const float* se2_w    = (const float*)d_in[12];
  const float* se2_b    = (const float*)d_in[13];
  const float* ga_w     = (const float*)d_in[14];
  const float* ga_b     = (const float*)d_in[15];
  const float* gemb     = (const float*)d_in[16];
  const float* gd1_w    = (const float*)d_in[17];
  const float* gd1_b    = (const float*)d_in[18];
  const float* gd2_w    = (const float*)d_in[19];
  const float* gd2_b    = (const float*)d_in[20];
  const float* hb_w     = (const float*)d_in[21];
  const float* hb_b     = (const float*)d_in[22];
  const float* hw_w     = (const float*)d_in[23];
  const float* hw_b     = (const float*)d_in[24];

  float* out = (float*)d_out;
  float* q_out     = out;              // [R,32]
  float* h_out     = out + 2097152;    // [R,128]
  float* gs_out    = out + 10485760;   // [R,256]
  float* probs_out = out + 27262976;   // [R,3]
  float* attn_out  = out + 27459584;   // [B,32,32]

  // workspace layout:
  //   region0 [0, 64MiB):  qk [R,256] -> s1 -> t (gd1 in-place) -> qpart [2][R,32] (16MB)
  //   si      [64, 80MiB): [R,64] padded struct_input
  //   x1      [80, 112MiB): [R,128]
  //   packs   [112MiB, +2.9MiB)
  float* ws = (float*)d_ws;
  float* qk = ws;
  float* s1 = ws;
  float* t  = ws;
  float* qpart = ws;                   // reuses region0 after t is dead
  float* si = ws + 16777216;
  float* x1 = ws + 16777216 + 4194304;
  short* P  = (short*)((char*)d_ws + (size_t)112 * 1024 * 1024);

  // pack offsets (shorts); chunk = KK*512 shorts
  const size_t o_hw  = 0;        // K=256 KK=8, N=4096 -> 1,048,576
  const size_t o_hb  = 1048576;  // chunks 256..257 of hw base
  const size_t o_fc1 = 1056768;
  const size_t o_wi  = 1077248;
  const size_t o_wh  = 1126400;
  const size_t o_qkq = 1175552;
  const size_t o_qkk = 1191936;
  const size_t o_se1 = 1208320;
  const size_t o_se2 = 1224704;
  const size_t o_gd1 = 1290240;
  const size_t o_gd2 = 1355776;

  PackArgs pa;
  pa.s[0]  = {hw_w,     256, 4096, 8, 0,    4096, o_hw};
  pa.s[1]  = {hb_w,     256, 32,   8, 4096, 32,   o_hb};
  pa.s[2]  = {fc1_w,    160, 128,  5, 4128, 80,   o_fc1};
  pa.s[3]  = {gru_wi,   128, 384,  4, 4208, 192,  o_wi};
  pa.s[4]  = {gru_wh,   128, 384,  4, 4400, 192,  o_wh};
  pa.s[5]  = {attn_q_w, 128, 128,  4, 4592, 64,   o_qkq};
  pa.s[6]  = {attn_k_w, 128, 128,  4, 4656, 64,   o_qkk};
  pa.s[7]  = {se1_w,    34,  256,  2, 4720, 64,   o_se1};
  pa.s[8]  = {se2_w,    256, 256,  8, 4784, 256,  o_se2};
  pa.s[9]  = {gd1_w,    256, 256,  8, 5040, 256,  o_gd1};
  pa.s[10] = {gd2_w,    256, 256,  8, 5296, 256,  o_gd2};

  dim3 blk(256);
  // 0) pack ALL weights in one launch
  pack_all_kernel<<<5552, blk, 0, stream>>>(pa, P);
  // 1) x1 = relu(inputs @ fc1_w + fc1_b)            K=160 N=128
  mfma_gemm_kernel<5, 8, 1><<<512, blk, 0, stream>>>(inputs, 160, P + o_fc1, fc1_b, x1);
  // 2) h = GRUCell(x1, hidden)
  gru_mfma_kernel<<<512, blk, 0, stream>>>(x1, hidden, P + o_wi, P + o_wh, gru_bi, gru_bh, h_out);
  // 3) qk = h @ [attn_q_w | attn_k_w]               K=128 N=256
  mfma_gemm_kernel<4, 16, 0><<<512, blk, 0, stream>>>(h_out, 128, P + o_qkq, nullptr, qk);
  // 4) attention -> attn_out + padded struct_input
  attn_kernel<<<2048, blk, 0, stream>>>(qk, attn_out, si);
  // 5) s1 = relu(si @ se1_w + se1_b)                K=64(pad) N=256
  mfma_gemm_kernel<2, 16, 1><<<512, blk, 0, stream>>>(si, 64, P + o_se1, se1_b, s1);
  // 6) struct_feat = tanh(s1 @ se2_w + se2_b) -> staged in gs_out
  mfma_gemm_kernel<8, 16, 2><<<512, blk, 0, stream>>>(s1, 256, P + o_se2, se2_b, gs_out);
  // 7) probs + t = sf + probs@group_emb
  group_kernel<<<16384, blk, 0, stream>>>(gs_out, ga_w, ga_b, gemb, probs_out, t);
  // 8) g1 = relu(t @ gd1_w + gd1_b)  (in-place)
  mfma_gemm_kernel<8, 16, 1><<<512, blk, 0, stream>>>(t, 256, P + o_gd1, gd1_b, t);
  // 9) group_state = tanh(g1 @ gd2_w + gd2_b) -> gs_out
  mfma_gemm_kernel<8, 16, 2><<<512, blk, 0, stream>>>(t, 256, P + o_gd2, gd2_b, gs_out);
  // 10) q partials: column-split LDS-dbuf MFMA hypernet
  hyper_q_v5_kernel<<<dim3(512), blk, 0, stream>>>(gs_out, h_out, P + o_hw, hw_b, qpart);
  // 11) q = qpart0 + qpart1 + hb_b
  qcombine_kernel<<<2048, blk, 0, stream>>>(qpart, hb_b, q_out);
}

// Round 8
// 519.049 us; speedup vs baseline: 1.2841x; 1.1010x over previous
//
#include <hip/hip_runtime.h>
#include <math.h>

// B=2048, A=32 -> R=65536 rows. E_IN=160, H=128, HE=256, NACT=32, G=3, TAU=1.
#define R_TOTAL 65536

typedef __attribute__((ext_vector_type(8))) short short8_t;
typedef __attribute__((ext_vector_type(4))) short short4_t;
typedef __attribute__((ext_vector_type(4))) float f32x4_t;

__device__ __forceinline__ float sigmoidf_(float x) { return 1.f / (1.f + expf(-x)); }

__device__ __forceinline__ short f2bf(float x) {
  unsigned u = __float_as_uint(x);
  u += 0x7fff + ((u >> 16) & 1);   // round-to-nearest-even
  return (short)(u >> 16);
}
__device__ __forceinline__ float bf2f(short s) {
  return __uint_as_float(((unsigned)(unsigned short)s) << 16);
}

// Load 8 consecutive floats -> bf16 fragment (RNE).
__device__ __forceinline__ void load_afrag(const float* p, short8_t& h) {
  float4 u0 = *(const float4*)p;
  float4 u1 = *(const float4*)(p + 4);
  float v[8] = {u0.x, u0.y, u0.z, u0.w, u1.x, u1.y, u1.z, u1.w};
#pragma unroll
  for (int i = 0; i < 8; ++i) h[i] = f2bf(v[i]);
}

#define MFMA(ACC, A, B) ACC = __builtin_amdgcn_mfma_f32_16x16x32_bf16(A, B, ACC, 0, 0, 0)

// ---------------- fused fragment pack: all weights in one launch ----------------
struct PackSeg {
  const float* W;
  int Ksrc, N, KK, blk0, nblk;
  size_t off;
};
struct PackArgs { PackSeg s[11]; };

__global__ __launch_bounds__(256) void pack_all_kernel(PackArgs a, short* __restrict__ P) {
  const int b = blockIdx.x;
  PackSeg seg = a.s[0];
#pragma unroll
  for (int i = 1; i < 11; ++i)
    if (b >= a.s[i].blk0) seg = a.s[i];
  int p = (b - seg.blk0) * 256 + threadIdx.x;
  int i = p & 7, lane = (p >> 3) & 63, kk = (p >> 9) % seg.KK, ct = p / (seg.KK * 512);
  int e = kk * 32 + (lane >> 4) * 8 + i;
  int c = ct * 16 + (lane & 15);
  float w = (e < seg.Ksrc) ? seg.W[(size_t)e * seg.N + c] : 0.f;
  P[seg.off + p] = f2bf(w);
}

// ---------------- generic MFMA GEMM: C[R,N] = act(A[R,K(lda)] @ W + bias) ----------------
// ABF/CBF: A/C stored as bf16 row-major (else fp32). In-place safe.
template <int KK, int NCT, int ACT, int ABF, int CBF>
__global__ __launch_bounds__(256) void mfma_gemm_kernel(
    const void* A_, int lda, const short* __restrict__ Wp,
    const float* __restrict__ bias, void* C_) {
  const int tid = threadIdx.x;
  const int wave = tid >> 6, lane = tid & 63;
  const int cl = lane & 15, kg = lane >> 4;
  const int row0 = blockIdx.x * 128 + wave * 32;
  constexpr int N = NCT * 16;
  short8_t ah[2][KK];
#pragma unroll
  for (int m = 0; m < 2; ++m) {
    if (ABF) {
      const short* ap = (const short*)A_ + (size_t)(row0 + m * 16 + cl) * lda;
#pragma unroll
      for (int kk = 0; kk < KK; ++kk)
        ah[m][kk] = *(const short8_t*)(ap + kk * 32 + kg * 8);
    } else {
      const float* ap = (const float*)A_ + (size_t)(row0 + m * 16 + cl) * lda;
#pragma unroll
      for (int kk = 0; kk < KK; ++kk) load_afrag(ap + kk * 32 + kg * 8, ah[m][kk]);
    }
  }
  for (int ct = 0; ct < NCT; ++ct) {
    f32x4_t a0 = (f32x4_t){0.f, 0.f, 0.f, 0.f};
    f32x4_t a1 = (f32x4_t){0.f, 0.f, 0.f, 0.f};
#pragma unroll
    for (int kk = 0; kk < KK; ++kk) {
      short8_t b_h = *(const short8_t*)(Wp + (((size_t)ct * KK + kk) * 64 + lane) * 8);
      MFMA(a0, ah[0][kk], b_h);
      MFMA(a1, ah[1][kk], b_h);
    }
    int col = ct * 16 + cl;
    float bv = bias ? bias[col] : 0.f;
#pragma unroll
    for (int j = 0; j < 4; ++j) {
      float v0 = a0[j] + bv, v1 = a1[j] + bv;
      if (ACT == 1) { v0 = fmaxf(v0, 0.f); v1 = fmaxf(v1, 0.f); }
      if (ACT == 2) { v0 = tanhf(v0); v1 = tanhf(v1); }
      size_t r0 = (size_t)(row0 + kg * 4 + j) * N + col;
      size_t r1 = (size_t)(row0 + 16 + kg * 4 + j) * N + col;
      if (CBF) {
        ((short*)C_)[r0] = f2bf(v0);
        ((short*)C_)[r1] = f2bf(v1);
      } else {
        ((float*)C_)[r0] = v0;
        ((float*)C_)[r1] = v1;
      }
    }
  }
}

// ---------------- MFMA GRU: h = GRUCell(x, h_in); x bf16, h_in fp32 ----------------
__global__ __launch_bounds__(256) void gru_mfma_kernel(
    const short* __restrict__ X, const float* __restrict__ Hin,
    const short* __restrict__ WiP, const short* __restrict__ WhP,
    const float* __restrict__ gbi, const float* __restrict__ gbh,
    float* __restrict__ Hout) {
  const int tid = threadIdx.x;
  const int wave = tid >> 6, lane = tid & 63;
  const int cl = lane & 15, kg = lane >> 4;
  const int row0 = blockIdx.x * 128 + wave * 32;
  short8_t xh[2][4], hh[2][4];
#pragma unroll
  for (int m = 0; m < 2; ++m) {
    const short* xp = X + (size_t)(row0 + m * 16 + cl) * 128;
    const float* hp = Hin + (size_t)(row0 + m * 16 + cl) * 128;
#pragma unroll
    for (int kk = 0; kk < 4; ++kk) {
      xh[m][kk] = *(const short8_t*)(xp + kk * 32 + kg * 8);
      load_afrag(hp + kk * 32 + kg * 8, hh[m][kk]);
    }
  }
#define GLOAD(P, CT) *(const short8_t*)((P) + (((size_t)(CT) * 4 + kk) * 64 + lane) * 8)
  for (int ct = 0; ct < 8; ++ct) {
    f32x4_t aXr[2], aXz[2], aXn[2], aHr[2], aHz[2], aHn[2];
#pragma unroll
    for (int m = 0; m < 2; ++m) {
      aXr[m] = (f32x4_t){0.f, 0.f, 0.f, 0.f};
      aXz[m] = (f32x4_t){0.f, 0.f, 0.f, 0.f};
      aXn[m] = (f32x4_t){0.f, 0.f, 0.f, 0.f};
      aHr[m] = (f32x4_t){0.f, 0.f, 0.f, 0.f};
      aHz[m] = (f32x4_t){0.f, 0.f, 0.f, 0.f};
      aHn[m] = (f32x4_t){0.f, 0.f, 0.f, 0.f};
    }
#pragma unroll
    for (int kk = 0; kk < 4; ++kk) {
      short8_t b_h;
      b_h = GLOAD(WiP, ct);      MFMA(aXr[0], xh[0][kk], b_h); MFMA(aXr[1], xh[1][kk], b_h);
      b_h = GLOAD(WiP, ct + 8);  MFMA(aXz[0], xh[0][kk], b_h); MFMA(aXz[1], xh[1][kk], b_h);
      b_h = GLOAD(WiP, ct + 16); MFMA(aXn[0], xh[0][kk], b_h); MFMA(aXn[1], xh[1][kk], b_h);
      b_h = GLOAD(WhP, ct);      MFMA(aHr[0], hh[0][kk], b_h); MFMA(aHr[1], hh[1][kk], b_h);
      b_h = GLOAD(WhP, ct + 8);  MFMA(aHz[0], hh[0][kk], b_h); MFMA(aHz[1], hh[1][kk], b_h);
      b_h = GLOAD(WhP, ct + 16); MFMA(aHn[0], hh[0][kk], b_h); MFMA(aHn[1], hh[1][kk], b_h);
    }
    int col = ct * 16 + cl;
    float bir = gbi[col], biz = gbi[128 + col], bin = gbi[256 + col];
    float bhr = gbh[col], bhz = gbh[128 + col], bhn = gbh[256 + col];
#pragma unroll
    for (int m = 0; m < 2; ++m)
#pragma unroll
      for (int j = 0; j < 4; ++j) {
        int row = row0 + m * 16 + kg * 4 + j;
        float rg = sigmoidf_(aXr[m][j] + aHr[m][j] + bir + bhr);
        float zg = sigmoidf_(aXz[m][j] + aHz[m][j] + biz + bhz);
        float ng = tanhf(aXn[m][j] + bin + rg * (aHn[m][j] + bhn));
        float hv = Hin[(size_t)row * 128 + col];
        Hout[(size_t)row * 128 + col] = (1.f - zg) * ng + zg * hv;
      }
  }
#undef GLOAD
}

// ---------------- attention block (reads qk bf16 [R,256], writes si bf16 [R,64]) --------
__global__ __launch_bounds__(256) void attn_kernel(
    const short* __restrict__ QK, float* __restrict__ attn_out, short* __restrict__ si) {
  __shared__ float qs[32][129];
  __shared__ float ks[32][129];
  __shared__ float p[32][33];
  __shared__ float a2[32][33];
  const int b = blockIdx.x;
  const int tid = threadIdx.x;
  const short* qb = QK + (size_t)b * 8192;
  {
    int r = tid >> 3, cg = tid & 7;
    const short* src = qb + r * 256 + cg * 32;
    float* dst = (cg < 4) ? &qs[r][cg * 32] : &ks[r][(cg - 4) * 32];
#pragma unroll
    for (int i = 0; i < 32; i += 8) {
      short8_t v = *(const short8_t*)(src + i);
#pragma unroll
      for (int j = 0; j < 8; ++j) dst[i + j] = bf2f(v[j]);
    }
  }
  __syncthreads();
  const float scale = 0.088388347648318447f;  // 1/sqrt(128)
#pragma unroll
  for (int tI = 0; tI < 4; ++tI) {
    int t = tid + tI * 256;
    int i = t >> 5, j = t & 31;
    float s = 0.f;
    for (int e = 0; e < 128; ++e) s = fmaf(qs[i][e], ks[j][e], s);
    p[i][j] = (i == j) ? -1e9f : s * scale;
  }
  __syncthreads();
  if (tid < 32) {
    const int i = tid;
    float m = -1e30f;
    for (int j = 0; j < 32; ++j) m = fmaxf(m, p[i][j]);
    float sum = 0.f;
    for (int j = 0; j < 32; ++j) {
      float e = expf(p[i][j] - m);
      p[i][j] = e;
      sum += e;
    }
    float inv = 1.f / sum;
    for (int j = 0; j < 32; ++j) p[i][j] *= inv;
  }
  __syncthreads();
#pragma unroll
  for (int tI = 0; tI < 4; ++tI) {
    int t = tid + tI * 256;
    int i = t >> 5, j = t & 31;
    float v = (i == j) ? 0.f : 0.5f * (p[i][j] + p[j][i]);
    a2[i][j] = v;
    attn_out[(size_t)b * 1024 + t] = v;
  }
  __syncthreads();
  if (tid < 32) {
    const int i = tid;
    float d = 0.f, en = 0.f;
    for (int j = 0; j < 32; ++j) {
      float v = a2[i][j];
      d += v;
      float c = fmaxf(v, 1e-8f);
      en -= c * logf(c);
    }
    short* srow = si + ((size_t)b * 32 + i) * 64;
    for (int j = 0; j < 32; ++j) srow[j] = f2bf(a2[i][j]);
    srow[32] = f2bf(d);
    srow[33] = f2bf(en);
    for (int j = 34; j < 64; ++j) srow[j] = 0;
  }
}

// ---------------- group assign (sf fp32 in, probs fp32 out, t bf16 out) ----------------
__global__ __launch_bounds__(256) void group_kernel(
    const float* __restrict__ sf, const float* __restrict__ ga_w,
    const float* __restrict__ ga_b, const float* __restrict__ gemb,
    float* __restrict__ probs, short* __restrict__ tout) {
  const size_t r = (size_t)blockIdx.x * 4 + (threadIdx.x >> 6);
  const int lane = threadIdx.x & 63;
  const int e = lane * 4;
  const float4 s4 = *(const float4*)(sf + r * 256 + e);
  float lg[3];
#pragma unroll
  for (int g = 0; g < 3; ++g) {
    lg[g] = s4.x * ga_w[(e + 0) * 3 + g] + s4.y * ga_w[(e + 1) * 3 + g] +
            s4.z * ga_w[(e + 2) * 3 + g] + s4.w * ga_w[(e + 3) * 3 + g];
  }
#pragma unroll
  for (int off = 32; off; off >>= 1) {
#pragma unroll
    for (int g = 0; g < 3; ++g) lg[g] += __shfl_xor(lg[g], off, 64);
  }
#pragma unroll
  for (int g = 0; g < 3; ++g) lg[g] += ga_b[g];
  float m = fmaxf(lg[0], fmaxf(lg[1], lg[2]));
  float e0 = expf(lg[0] - m), e1 = expf(lg[1] - m), e2 = expf(lg[2] - m);
  float inv = 1.f / (e0 + e1 + e2);
  float p0 = e0 * inv, p1 = e1 * inv, p2 = e2 * inv;
  if (lane == 0) probs[r * 3 + 0] = p0;
  if (lane == 1) probs[r * 3 + 1] = p1;
  if (lane == 2) probs[r * 3 + 2] = p2;
  short4_t o;
  o[0] = f2bf(s4.x + p0 * gemb[e + 0] + p1 * gemb[256 + e + 0] + p2 * gemb[512 + e + 0]);
  o[1] = f2bf(s4.y + p0 * gemb[e + 1] + p1 * gemb[256 + e + 1] + p2 * gemb[512 + e + 1]);
  o[2] = f2bf(s4.z + p0 * gemb[e + 2] + p1 * gemb[256 + e + 2] + p2 * gemb[512 + e + 2]);
  o[3] = f2bf(s4.w + p0 * gemb[e + 3] + p1 * gemb[256 + e + 3] + p2 * gemb[512 + e + 3]);
  *(short4_t*)(tout + r * 256 + e) = o;
}

// ---------------- MFMA hypernet q v6: quarter-split + LDS h-block + LDS W dbuf ------------
// Grid 1024: quarter = bid>>8 covers h cols [q*32,(q+1)*32), W chunks [q*64,(q+1)*64).
// 4 waves x 64 rows (BM=256). Wave's h block (64x32) staged in padded LDS once.
__global__ __launch_bounds__(256, 2) void hyper_q_v6_kernel(
    const float* __restrict__ GS, const float* __restrict__ Hh,
    const short* __restrict__ Wp, const float* __restrict__ hwb,
    float* __restrict__ Qpart) {
  __shared__ short Bh[2][4096];        // 16 KB W double buffer
  __shared__ float h_lds[4][64][33];   // 33 KB, pad 33 -> conflict-free reads
  const int tid = threadIdx.x;
  const int wave = tid >> 6, lane = tid & 63;
  const int cl = lane & 15, kg = lane >> 4;
  const int quarter = blockIdx.x >> 8;
  const int wrow = (blockIdx.x & 255) * 256 + wave * 64;
  const int ct_base = quarter * 64;

  // ---- stage h block: lane owns row `lane`, 32 cols of this quarter ----
  {
    const float* hp = Hh + (size_t)(wrow + lane) * 128 + quarter * 32;
#pragma unroll
    for (int i = 0; i < 32; i += 4) {
      float4 v = *(const float4*)(hp + i);
      h_lds[wave][lane][i + 0] = v.x;
      h_lds[wave][lane][i + 1] = v.y;
      h_lds[wave][lane][i + 2] = v.z;
      h_lds[wave][lane][i + 3] = v.w;
    }
  }

  // ---- A (gs) -> registers as bf16 fragments: 4 m-frags x 8 kk ----
  short8_t ah[4][8];
#pragma unroll
  for (int m = 0; m < 4; ++m) {
    const float* ap = GS + (size_t)(wrow + m * 16 + cl) * 256;
#pragma unroll
    for (int kk = 0; kk < 8; ++kk) load_afrag(ap + kk * 32 + kg * 8, ah[m][kk]);
  }

  // ---- prologue: stage chunk ct_base into buf 0 ----
  {
    const short* wp0 = Wp + (size_t)ct_base * 4096;
    short8_t v0 = *(const short8_t*)(wp0 + tid * 8);
    short8_t v1 = *(const short8_t*)(wp0 + 2048 + tid * 8);
    *(short8_t*)&Bh[0][tid * 8] = v0;
    *(short8_t*)&Bh[0][2048 + tid * 8] = v1;
  }
  __syncthreads();

  float qf[4][2][4] = {};  // [m][oh][j]

#define COMPUTE_HALF(BUF, OH, WB)                                              \
  {                                                                            \
    f32x4_t acc[4];                                                            \
    _Pragma("unroll")                                                          \
    for (int m = 0; m < 4; ++m) acc[m] = (f32x4_t){0.f, 0.f, 0.f, 0.f};        \
    _Pragma("unroll")                                                          \
    for (int kk = 0; kk < 8; ++kk) {                                           \
      short8_t b_h = *(const short8_t*)&Bh[BUF][(kk * 64 + lane) * 8];         \
      _Pragma("unroll")                                                        \
      for (int m = 0; m < 4; ++m) MFMA(acc[m], ah[m][kk], b_h);                \
    }                                                                          \
    _Pragma("unroll")                                                          \
    for (int m = 0; m < 4; ++m)                                                \
      _Pragma("unroll")                                                        \
      for (int j = 0; j < 4; ++j)                                              \
        qf[m][OH][j] = fmaf(hc[m * 4 + j], acc[m][j] + (WB), qf[m][OH][j]);    \
  }

  for (int t2 = 0; t2 < 32; ++t2) {
    const int ct0 = ct_base + t2 * 2;
    float hc[16];
#pragma unroll
    for (int m = 0; m < 4; ++m)
#pragma unroll
      for (int j = 0; j < 4; ++j)
        hc[m * 4 + j] = h_lds[wave][m * 16 + kg * 4 + j][t2];
    float wb0 = hwb[ct0 * 16 + cl];
    float wb1 = hwb[(ct0 + 1) * 16 + cl];
    const short* wp1 = Wp + (size_t)(ct0 + 1) * 4096;
    short8_t s1a = *(const short8_t*)(wp1 + tid * 8);
    short8_t s1b = *(const short8_t*)(wp1 + 2048 + tid * 8);
    COMPUTE_HALF(0, 0, wb0)
    *(short8_t*)&Bh[1][tid * 8] = s1a;
    *(short8_t*)&Bh[1][2048 + tid * 8] = s1b;
    __syncthreads();
    short8_t s2a, s2b;
    if (t2 < 31) {
      const short* wp2 = Wp + (size_t)(ct0 + 2) * 4096;
      s2a = *(const short8_t*)(wp2 + tid * 8);
      s2b = *(const short8_t*)(wp2 + 2048 + tid * 8);
    }
    COMPUTE_HALF(1, 1, wb1)
    if (t2 < 31) {
      *(short8_t*)&Bh[0][tid * 8] = s2a;
      *(short8_t*)&Bh[0][2048 + tid * 8] = s2b;
    }
    __syncthreads();
  }
#undef COMPUTE_HALF

  // ---- quarter 0 adds fc2_b = gs @ hb_w via packed chunks 256/257 (direct L2) ----
  if (quarter == 0) {
#pragma unroll
    for (int oh = 0; oh < 2; ++oh) {
      f32x4_t bacc[4];
#pragma unroll
      for (int m = 0; m < 4; ++m) bacc[m] = (f32x4_t){0.f, 0.f, 0.f, 0.f};
#pragma unroll
      for (int kk = 0; kk < 8; ++kk) {
        short8_t b_h = *(const short8_t*)(Wp + (((size_t)(256 + oh) * 8 + kk) * 64 + lane) * 8);
#pragma unroll
        for (int m = 0; m < 4; ++m) MFMA(bacc[m], ah[m][kk], b_h);
      }
#pragma unroll
      for (int m = 0; m < 4; ++m)
#pragma unroll
        for (int j = 0; j < 4; ++j) qf[m][oh][j] += bacc[m][j];
    }
  }

  // ---- write partial q ----
  float* qp = Qpart + (size_t)quarter * 2097152;
#pragma unroll
  for (int m = 0; m < 4; ++m)
#pragma unroll
    for (int j = 0; j < 4; ++j) {
      const size_t r = (size_t)(wrow + m * 16 + kg * 4 + j) * 32;
      qp[r + cl] = qf[m][0][j];
      qp[r + 16 + cl] = qf[m][1][j];
    }
}

// ---------------- combine: q = sum(qpart[0..3]) + hb_b ----------------
__global__ __launch_bounds__(256) void qcombine_kernel(
    const float* __restrict__ Qpart, const float* __restrict__ hbb,
    float* __restrict__ Qout) {
  int i = blockIdx.x * 256 + threadIdx.x;  // 524288 float4s
  float4 a = ((const float4*)Qpart)[i];
  float4 b = ((const float4*)(Qpart + 2097152))[i];
  float4 c = ((const float4*)(Qpart + 4194304))[i];
  float4 d = ((const float4*)(Qpart + 6291456))[i];
  float4 e = ((const float4*)hbb)[i & 7];
  ((float4*)Qout)[i] = make_float4(a.x + b.x + c.x + d.x + e.x,
                                   a.y + b.y + c.y + d.y + e.y,
                                   a.z + b.z + c.z + d.z + e.z,
                                   a.w + b.w + c.w + d.w + e.w);
}

extern "C" void kernel_launch(void* const* d_in, const int* in_sizes, int n_in,
                              void* d_out, int out_size, void* d_ws, size_t ws_size,
                              hipStream_t stream) {
  const float* inputs   = (const float*)d_in[0];
  const float* hidden   = (const float*)d_in[1];
  const float* fc1_w    = (const float*)d_in[2];
  const float* fc1_b    = (const float*)d_in[3];
  const float* gru_wi   = (const float*)d_in[4];
  const float* gru_wh   = (const float*)d_in[5];
  const float* gru_bi   = (const float*)d_in[6];
  const float* gru_bh   = (const float*)d_in[7];
  const float* attn_q_w = (const float*)d_in[8];
  const float* attn_k_w = (const float*)d_in[9];
  const float* se1_w    = (const float*)d_in[10];
  const float* se1_b    = (const float*)d_in[11];
  const float* se2_w    = (const float*)d_in[12];
  const float* se2_b    = (const float*)d_in[13];
  const float* ga_w     = (const float*)d_in[14];
  const float* ga_b     = (const float*)d_in[15];
  const float* gemb     = (const float*)d_in[16];
  const float* gd1_w    = (const float*)d_in[17];
  const float* gd1_b    = (const float*)d_in[18];
  const float* gd2_w    = (const float*)d_in[19];
  const float* gd2_b    = (const float*)d_in[20];
  const float* hb_w     = (const float*)d_in[21];
  const float* hb_b     = (const float*)d_in[22];
  const float* hw_w     = (const float*)d_in[23];
  const float* hw_b     = (const float*)d_in[24];

  float* out = (float*)d_out;
  float* q_out     = out;              // [R,32]
  float* h_out     = out + 2097152;    // [R,128]
  float* gs_out    = out + 10485760;   // [R,256]
  float* probs_out = out + 27262976;   // [R,3]
  float* attn_out  = out + 27459584;   // [B,32,32]

  // workspace layout (bytes):
  //   region0 [0, 64MiB): qk bf16 [R,256] (33.5MB) -> s1 bf16 -> t bf16 (gd1 in-place)
  //                       -> qpart f32 [4][R,32] (32MB)
  //   si   [64MiB, +8MiB): bf16 [R,64]
  //   x1   [80MiB, +16MiB): bf16 [R,128]
  //   packs [112MiB, +2.9MiB)
  char* wsb = (char*)d_ws;
  short* qk = (short*)wsb;
  short* s1 = (short*)wsb;
  short* t  = (short*)wsb;
  float* qpart = (float*)wsb;
  short* si = (short*)(wsb + (size_t)64 * 1024 * 1024);
  short* x1 = (short*)(wsb + (size_t)80 * 1024 * 1024);
  short* P  = (short*)(wsb + (size_t)112 * 1024 * 1024);

  // pack offsets (shorts); chunk = KK*512 shorts
  const size_t o_hw  = 0;        // K=256 KK=8, N=4096 -> 1,048,576 (+hb chunks 256..257)
  const size_t o_hb  = 1048576;
  const size_t o_fc1 = 1056768;
  const size_t o_wi  = 1077248;
  const size_t o_wh  = 1126400;
  const size_t o_qkq = 1175552;
  const size_t o_qkk = 1191936;
  const size_t o_se1 = 1208320;
  const size_t o_se2 = 1224704;
  const size_t o_gd1 = 1290240;
  const size_t o_gd2 = 1355776;

  PackArgs pa;
  pa.s[0]  = {hw_w,     256, 4096, 8, 0,    4096, o_hw};
  pa.s[1]  = {hb_w,     256, 32,   8, 4096, 32,   o_hb};
  pa.s[2]  = {fc1_w,    160, 128,  5, 4128, 80,   o_fc1};
  pa.s[3]  = {gru_wi,   128, 384,  4, 4208, 192,  o_wi};
  pa.s[4]  = {gru_wh,   128, 384,  4, 4400, 192,  o_wh};
  pa.s[5]  = {attn_q_w, 128, 128,  4, 4592, 64,   o_qkq};
  pa.s[6]  = {attn_k_w, 128, 128,  4, 4656, 64,   o_qkk};
  pa.s[7]  = {se1_w,    34,  256,  2, 4720, 64,   o_se1};
  pa.s[8]  = {se2_w,    256, 256,  8, 4784, 256,  o_se2};
  pa.s[9]  = {gd1_w,    256, 256,  8, 5040, 256,  o_gd1};
  pa.s[10] = {gd2_w,    256, 256,  8, 5296, 256,  o_gd2};

  dim3 blk(256);
  // 0) pack ALL weights in one launch
  pack_all_kernel<<<5552, blk, 0, stream>>>(pa, P);
  // 1) x1 = relu(inputs @ fc1_w + fc1_b)  f32 -> bf16
  mfma_gemm_kernel<5, 8, 1, 0, 1><<<512, blk, 0, stream>>>(inputs, 160, P + o_fc1, fc1_b, x1);
  // 2) h = GRUCell(x1 bf16, hidden f32) -> h_out f32
  gru_mfma_kernel<<<512, blk, 0, stream>>>(x1, hidden, P + o_wi, P + o_wh, gru_bi, gru_bh, h_out);
  // 3) qk = h @ [q|k]  f32 -> bf16
  mfma_gemm_kernel<4, 16, 0, 0, 1><<<512, blk, 0, stream>>>(h_out, 128, P + o_qkq, nullptr, qk);
  // 4) attention -> attn_out f32 + si bf16
  attn_kernel<<<2048, blk, 0, stream>>>(qk, attn_out, si);
  // 5) s1 = relu(si @ se1_w + se1_b)  bf16 -> bf16
  mfma_gemm_kernel<2, 16, 1, 1, 1><<<512, blk, 0, stream>>>(si, 64, P + o_se1, se1_b, s1);
  // 6) struct_feat = tanh(s1 @ se2_w + se2_b) -> gs_out f32 (staged)
  mfma_gemm_kernel<8, 16, 2, 1, 0><<<512, blk, 0, stream>>>(s1, 256, P + o_se2, se2_b, gs_out);
  // 7) probs f32 + t bf16
  group_kernel<<<16384, blk, 0, stream>>>(gs_out, ga_w, ga_b, gemb, probs_out, t);
  // 8) g1 = relu(t @ gd1_w + gd1_b)  bf16 in-place
  mfma_gemm_kernel<8, 16, 1, 1, 1><<<512, blk, 0, stream>>>(t, 256, P + o_gd1, gd1_b, t);
  // 9) group_state = tanh(g1 @ gd2_w + gd2_b) -> gs_out f32
  mfma_gemm_kernel<8, 16, 2, 1, 0><<<512, blk, 0, stream>>>(t, 256, P + o_gd2, gd2_b, gs_out);
  // 10) q partials: quarter-split LDS-dbuf MFMA hypernet (t dead -> qpart reuses region0)
  hyper_q_v6_kernel<<<dim3(1024), blk, 0, stream>>>(gs_out, h_out, P + o_hw, hw_b, qpart);
  // 11) q = sum(qpart) + hb_b
  qcombine_kernel<<<2048, blk, 0, stream>>>(qpart, hb_b, q_out);
}

// Round 9
// 427.959 us; speedup vs baseline: 1.5574x; 1.2128x over previous
//
#include <hip/hip_runtime.h>
#include <math.h>

// B=2048, A=32 -> R=65536 rows. E_IN=160, H=128, HE=256, NACT=32, G=3, TAU=1.
#define R_TOTAL 65536

typedef __attribute__((ext_vector_type(8))) short short8_t;
typedef __attribute__((ext_vector_type(4))) short short4_t;
typedef __attribute__((ext_vector_type(4))) float f32x4_t;

__device__ __forceinline__ float sigmoidf_(float x) { return 1.f / (1.f + expf(-x)); }

__device__ __forceinline__ short f2bf(float x) {
  unsigned u = __float_as_uint(x);
  u += 0x7fff + ((u >> 16) & 1);   // round-to-nearest-even
  return (short)(u >> 16);
}
__device__ __forceinline__ float bf2f(short s) {
  return __uint_as_float(((unsigned)(unsigned short)s) << 16);
}

// Load 8 consecutive floats -> bf16 fragment (RNE).
__device__ __forceinline__ void load_afrag(const float* p, short8_t& h) {
  float4 u0 = *(const float4*)p;
  float4 u1 = *(const float4*)(p + 4);
  float v[8] = {u0.x, u0.y, u0.z, u0.w, u1.x, u1.y, u1.z, u1.w};
#pragma unroll
  for (int i = 0; i < 8; ++i) h[i] = f2bf(v[i]);
}

#define MFMA(ACC, A, B) ACC = __builtin_amdgcn_mfma_f32_16x16x32_bf16(A, B, ACC, 0, 0, 0)

// ---------------- fused fragment pack: all weights in one launch ----------------
struct PackSeg {
  const float* W;
  int Ksrc, N, KK, blk0, nblk;
  size_t off;
};
struct PackArgs { PackSeg s[11]; };

__global__ __launch_bounds__(256) void pack_all_kernel(PackArgs a, short* __restrict__ P) {
  const int b = blockIdx.x;
  PackSeg seg = a.s[0];
#pragma unroll
  for (int i = 1; i < 11; ++i)
    if (b >= a.s[i].blk0) seg = a.s[i];
  int p = (b - seg.blk0) * 256 + threadIdx.x;
  int i = p & 7, lane = (p >> 3) & 63, kk = (p >> 9) % seg.KK, ct = p / (seg.KK * 512);
  int e = kk * 32 + (lane >> 4) * 8 + i;
  int c = ct * 16 + (lane & 15);
  float w = (e < seg.Ksrc) ? seg.W[(size_t)e * seg.N + c] : 0.f;
  P[seg.off + p] = f2bf(w);
}

// ---------------- generic MFMA GEMM: C[R,N] = act(A[R,K(lda)] @ W + bias) ----------------
template <int KK, int NCT, int ACT, int ABF, int CBF>
__global__ __launch_bounds__(256) void mfma_gemm_kernel(
    const void* A_, int lda, const short* __restrict__ Wp,
    const float* __restrict__ bias, void* C_) {
  const int tid = threadIdx.x;
  const int wave = tid >> 6, lane = tid & 63;
  const int cl = lane & 15, kg = lane >> 4;
  const int row0 = blockIdx.x * 128 + wave * 32;
  constexpr int N = NCT * 16;
  short8_t ah[2][KK];
#pragma unroll
  for (int m = 0; m < 2; ++m) {
    if (ABF) {
      const short* ap = (const short*)A_ + (size_t)(row0 + m * 16 + cl) * lda;
#pragma unroll
      for (int kk = 0; kk < KK; ++kk)
        ah[m][kk] = *(const short8_t*)(ap + kk * 32 + kg * 8);
    } else {
      const float* ap = (const float*)A_ + (size_t)(row0 + m * 16 + cl) * lda;
#pragma unroll
      for (int kk = 0; kk < KK; ++kk) load_afrag(ap + kk * 32 + kg * 8, ah[m][kk]);
    }
  }
  for (int ct = 0; ct < NCT; ++ct) {
    f32x4_t a0 = (f32x4_t){0.f, 0.f, 0.f, 0.f};
    f32x4_t a1 = (f32x4_t){0.f, 0.f, 0.f, 0.f};
#pragma unroll
    for (int kk = 0; kk < KK; ++kk) {
      short8_t b_h = *(const short8_t*)(Wp + (((size_t)ct * KK + kk) * 64 + lane) * 8);
      MFMA(a0, ah[0][kk], b_h);
      MFMA(a1, ah[1][kk], b_h);
    }
    int col = ct * 16 + cl;
    float bv = bias ? bias[col] : 0.f;
#pragma unroll
    for (int j = 0; j < 4; ++j) {
      float v0 = a0[j] + bv, v1 = a1[j] + bv;
      if (ACT == 1) { v0 = fmaxf(v0, 0.f); v1 = fmaxf(v1, 0.f); }
      if (ACT == 2) { v0 = tanhf(v0); v1 = tanhf(v1); }
      size_t r0 = (size_t)(row0 + kg * 4 + j) * N + col;
      size_t r1 = (size_t)(row0 + 16 + kg * 4 + j) * N + col;
      if (CBF) {
        ((short*)C_)[r0] = f2bf(v0);
        ((short*)C_)[r1] = f2bf(v1);
      } else {
        ((float*)C_)[r0] = v0;
        ((float*)C_)[r1] = v1;
      }
    }
  }
}

// ---------------- fused two-layer MLP: C = tanh(relu(A@W1+b1)@W2+b2) ----------------
// A bf16 [R,lda]; mid result (128x256 bf16) staged in XOR-swizzled LDS.
// CDUAL: also write bf16 copy of C.
template <int KK1, int CDUAL>
__global__ __launch_bounds__(256) void fused2_kernel(
    const short* __restrict__ A, int lda,
    const short* __restrict__ W1p, const float* __restrict__ b1,
    const short* __restrict__ W2p, const float* __restrict__ b2,
    float* __restrict__ C, short* __restrict__ C16) {
  __shared__ short mid[128 * 256];   // 64 KB
  const int tid = threadIdx.x;
  const int wave = tid >> 6, lane = tid & 63;
  const int cl = lane & 15, kg = lane >> 4;
  const int row0g = blockIdx.x * 128 + wave * 32;
  const int row0l = wave * 32;

  // ---- stage 1: mid = relu(A@W1 + b1) -> swizzled LDS ----
  {
    short8_t ah1[2][KK1];
#pragma unroll
    for (int m = 0; m < 2; ++m) {
      const short* ap = A + (size_t)(row0g + m * 16 + cl) * lda;
#pragma unroll
      for (int kk = 0; kk < KK1; ++kk)
        ah1[m][kk] = *(const short8_t*)(ap + kk * 32 + kg * 8);
    }
    for (int ct = 0; ct < 16; ++ct) {
      f32x4_t a0 = (f32x4_t){0.f, 0.f, 0.f, 0.f};
      f32x4_t a1 = (f32x4_t){0.f, 0.f, 0.f, 0.f};
#pragma unroll
      for (int kk = 0; kk < KK1; ++kk) {
        short8_t b_h = *(const short8_t*)(W1p + (((size_t)ct * KK1 + kk) * 64 + lane) * 8);
        MFMA(a0, ah1[0][kk], b_h);
        MFMA(a1, ah1[1][kk], b_h);
      }
      int col = ct * 16 + cl;
      float bv = b1[col];
      int c2hi = (col * 2) & ~15, c2lo = (col * 2) & 15;
#pragma unroll
      for (int j = 0; j < 4; ++j) {
        float v0 = fmaxf(a0[j] + bv, 0.f);
        float v1 = fmaxf(a1[j] + bv, 0.f);
        int r0 = row0l + kg * 4 + j;
        int r1 = row0l + 16 + kg * 4 + j;
        int ad0 = ((r0 * 512 + c2hi) ^ ((r0 & 7) << 4)) + c2lo;
        int ad1 = ((r1 * 512 + c2hi) ^ ((r1 & 7) << 4)) + c2lo;
        *(short*)((char*)mid + ad0) = f2bf(v0);
        *(short*)((char*)mid + ad1) = f2bf(v1);
      }
    }
  }
  __syncthreads();

  // ---- stage 2: C = tanh(mid@W2 + b2) ----
  short8_t ah2[2][8];
#pragma unroll
  for (int m = 0; m < 2; ++m) {
    int row = row0l + m * 16 + cl;
#pragma unroll
    for (int kk = 0; kk < 8; ++kk) {
      int ad = (row * 512 + kk * 64 + kg * 16) ^ ((row & 7) << 4);
      ah2[m][kk] = *(const short8_t*)((const char*)mid + ad);
    }
  }
  for (int ct = 0; ct < 16; ++ct) {
    f32x4_t a0 = (f32x4_t){0.f, 0.f, 0.f, 0.f};
    f32x4_t a1 = (f32x4_t){0.f, 0.f, 0.f, 0.f};
#pragma unroll
    for (int kk = 0; kk < 8; ++kk) {
      short8_t b_h = *(const short8_t*)(W2p + (((size_t)ct * 8 + kk) * 64 + lane) * 8);
      MFMA(a0, ah2[0][kk], b_h);
      MFMA(a1, ah2[1][kk], b_h);
    }
    int col = ct * 16 + cl;
    float bv = b2[col];
#pragma unroll
    for (int j = 0; j < 4; ++j) {
      float v0 = tanhf(a0[j] + bv);
      float v1 = tanhf(a1[j] + bv);
      size_t r0 = (size_t)(row0g + kg * 4 + j) * 256 + col;
      size_t r1 = (size_t)(row0g + 16 + kg * 4 + j) * 256 + col;
      C[r0] = v0;
      C[r1] = v1;
      if (CDUAL) {
        C16[r0] = f2bf(v0);
        C16[r1] = f2bf(v1);
      }
    }
  }
}

// ---------------- MFMA GRU: h = GRUCell(x, h_in); x bf16, h_in fp32 ----------------
__global__ __launch_bounds__(256) void gru_mfma_kernel(
    const short* __restrict__ X, const float* __restrict__ Hin,
    const short* __restrict__ WiP, const short* __restrict__ WhP,
    const float* __restrict__ gbi, const float* __restrict__ gbh,
    float* __restrict__ Hout) {
  const int tid = threadIdx.x;
  const int wave = tid >> 6, lane = tid & 63;
  const int cl = lane & 15, kg = lane >> 4;
  const int row0 = blockIdx.x * 128 + wave * 32;
  short8_t xh[2][4], hh[2][4];
#pragma unroll
  for (int m = 0; m < 2; ++m) {
    const short* xp = X + (size_t)(row0 + m * 16 + cl) * 128;
    const float* hp = Hin + (size_t)(row0 + m * 16 + cl) * 128;
#pragma unroll
    for (int kk = 0; kk < 4; ++kk) {
      xh[m][kk] = *(const short8_t*)(xp + kk * 32 + kg * 8);
      load_afrag(hp + kk * 32 + kg * 8, hh[m][kk]);
    }
  }
#define GLOAD(P, CT) *(const short8_t*)((P) + (((size_t)(CT) * 4 + kk) * 64 + lane) * 8)
  for (int ct = 0; ct < 8; ++ct) {
    f32x4_t aXr[2], aXz[2], aXn[2], aHr[2], aHz[2], aHn[2];
#pragma unroll
    for (int m = 0; m < 2; ++m) {
      aXr[m] = (f32x4_t){0.f, 0.f, 0.f, 0.f};
      aXz[m] = (f32x4_t){0.f, 0.f, 0.f, 0.f};
      aXn[m] = (f32x4_t){0.f, 0.f, 0.f, 0.f};
      aHr[m] = (f32x4_t){0.f, 0.f, 0.f, 0.f};
      aHz[m] = (f32x4_t){0.f, 0.f, 0.f, 0.f};
      aHn[m] = (f32x4_t){0.f, 0.f, 0.f, 0.f};
    }
#pragma unroll
    for (int kk = 0; kk < 4; ++kk) {
      short8_t b_h;
      b_h = GLOAD(WiP, ct);      MFMA(aXr[0], xh[0][kk], b_h); MFMA(aXr[1], xh[1][kk], b_h);
      b_h = GLOAD(WiP, ct + 8);  MFMA(aXz[0], xh[0][kk], b_h); MFMA(aXz[1], xh[1][kk], b_h);
      b_h = GLOAD(WiP, ct + 16); MFMA(aXn[0], xh[0][kk], b_h); MFMA(aXn[1], xh[1][kk], b_h);
      b_h = GLOAD(WhP, ct);      MFMA(aHr[0], hh[0][kk], b_h); MFMA(aHr[1], hh[1][kk], b_h);
      b_h = GLOAD(WhP, ct + 8);  MFMA(aHz[0], hh[0][kk], b_h); MFMA(aHz[1], hh[1][kk], b_h);
      b_h = GLOAD(WhP, ct + 16); MFMA(aHn[0], hh[0][kk], b_h); MFMA(aHn[1], hh[1][kk], b_h);
    }
    int col = ct * 16 + cl;
    float bir = gbi[col], biz = gbi[128 + col], bin = gbi[256 + col];
    float bhr = gbh[col], bhz = gbh[128 + col], bhn = gbh[256 + col];
#pragma unroll
    for (int m = 0; m < 2; ++m)
#pragma unroll
      for (int j = 0; j < 4; ++j) {
        int row = row0 + m * 16 + kg * 4 + j;
        float rg = sigmoidf_(aXr[m][j] + aHr[m][j] + bir + bhr);
        float zg = sigmoidf_(aXz[m][j] + aHz[m][j] + biz + bhz);
        float ng = tanhf(aXn[m][j] + bin + rg * (aHn[m][j] + bhn));
        float hv = Hin[(size_t)row * 128 + col];
        Hout[(size_t)row * 128 + col] = (1.f - zg) * ng + zg * hv;
      }
  }
#undef GLOAD
}

// ---------------- attention block (reads qk bf16 [R,256], writes si bf16 [R,64]) --------
__global__ __launch_bounds__(256) void attn_kernel(
    const short* __restrict__ QK, float* __restrict__ attn_out, short* __restrict__ si) {
  __shared__ float qs[32][129];
  __shared__ float ks[32][129];
  __shared__ float p[32][33];
  __shared__ float a2[32][33];
  const int b = blockIdx.x;
  const int tid = threadIdx.x;
  const short* qb = QK + (size_t)b * 8192;
  {
    int r = tid >> 3, cg = tid & 7;
    const short* src = qb + r * 256 + cg * 32;
    float* dst = (cg < 4) ? &qs[r][cg * 32] : &ks[r][(cg - 4) * 32];
#pragma unroll
    for (int i = 0; i < 32; i += 8) {
      short8_t v = *(const short8_t*)(src + i);
#pragma unroll
      for (int j = 0; j < 8; ++j) dst[i + j] = bf2f(v[j]);
    }
  }
  __syncthreads();
  const float scale = 0.088388347648318447f;  // 1/sqrt(128)
#pragma unroll
  for (int tI = 0; tI < 4; ++tI) {
    int t = tid + tI * 256;
    int i = t >> 5, j = t & 31;
    float s = 0.f;
    for (int e = 0; e < 128; ++e) s = fmaf(qs[i][e], ks[j][e], s);
    p[i][j] = (i == j) ? -1e9f : s * scale;
  }
  __syncthreads();
  if (tid < 32) {
    const int i = tid;
    float m = -1e30f;
    for (int j = 0; j < 32; ++j) m = fmaxf(m, p[i][j]);
    float sum = 0.f;
    for (int j = 0; j < 32; ++j) {
      float e = expf(p[i][j] - m);
      p[i][j] = e;
      sum += e;
    }
    float inv = 1.f / sum;
    for (int j = 0; j < 32; ++j) p[i][j] *= inv;
  }
  __syncthreads();
#pragma unroll
  for (int tI = 0; tI < 4; ++tI) {
    int t = tid + tI * 256;
    int i = t >> 5, j = t & 31;
    float v = (i == j) ? 0.f : 0.5f * (p[i][j] + p[j][i]);
    a2[i][j] = v;
    attn_out[(size_t)b * 1024 + t] = v;
  }
  __syncthreads();
  if (tid < 32) {
    const int i = tid;
    float d = 0.f, en = 0.f;
    for (int j = 0; j < 32; ++j) {
      float v = a2[i][j];
      d += v;
      float c = fmaxf(v, 1e-8f);
      en -= c * logf(c);
    }
    short* srow = si + ((size_t)b * 32 + i) * 64;
    for (int j = 0; j < 32; ++j) srow[j] = f2bf(a2[i][j]);
    srow[32] = f2bf(d);
    srow[33] = f2bf(en);
    for (int j = 34; j < 64; ++j) srow[j] = 0;
  }
}

// ---------------- group assign (sf fp32 in, probs fp32 out, t bf16 out) ----------------
__global__ __launch_bounds__(256) void group_kernel(
    const float* __restrict__ sf, const float* __restrict__ ga_w,
    const float* __restrict__ ga_b, const float* __restrict__ gemb,
    float* __restrict__ probs, short* __restrict__ tout) {
  const size_t r = (size_t)blockIdx.x * 4 + (threadIdx.x >> 6);
  const int lane = threadIdx.x & 63;
  const int e = lane * 4;
  const float4 s4 = *(const float4*)(sf + r * 256 + e);
  float lg[3];
#pragma unroll
  for (int g = 0; g < 3; ++g) {
    lg[g] = s4.x * ga_w[(e + 0) * 3 + g] + s4.y * ga_w[(e + 1) * 3 + g] +
            s4.z * ga_w[(e + 2) * 3 + g] + s4.w * ga_w[(e + 3) * 3 + g];
  }
#pragma unroll
  for (int off = 32; off; off >>= 1) {
#pragma unroll
    for (int g = 0; g < 3; ++g) lg[g] += __shfl_xor(lg[g], off, 64);
  }
#pragma unroll
  for (int g = 0; g < 3; ++g) lg[g] += ga_b[g];
  float m = fmaxf(lg[0], fmaxf(lg[1], lg[2]));
  float e0 = expf(lg[0] - m), e1 = expf(lg[1] - m), e2 = expf(lg[2] - m);
  float inv = 1.f / (e0 + e1 + e2);
  float p0 = e0 * inv, p1 = e1 * inv, p2 = e2 * inv;
  if (lane == 0) probs[r * 3 + 0] = p0;
  if (lane == 1) probs[r * 3 + 1] = p1;
  if (lane == 2) probs[r * 3 + 2] = p2;
  short4_t o;
  o[0] = f2bf(s4.x + p0 * gemb[e + 0] + p1 * gemb[256 + e + 0] + p2 * gemb[512 + e + 0]);
  o[1] = f2bf(s4.y + p0 * gemb[e + 1] + p1 * gemb[256 + e + 1] + p2 * gemb[512 + e + 1]);
  o[2] = f2bf(s4.z + p0 * gemb[e + 2] + p1 * gemb[256 + e + 2] + p2 * gemb[512 + e + 2]);
  o[3] = f2bf(s4.w + p0 * gemb[e + 3] + p1 * gemb[256 + e + 3] + p2 * gemb[512 + e + 3]);
  *(short4_t*)(tout + r * 256 + e) = o;
}

// ---------------- MFMA hypernet q v7: half-split, bf16 A, ct-pair LDS dbuf --------------
// Grid 512: half = bid>>8 covers h cols [half*64,(half+1)*64), W chunks [half*128,+128).
// 4 waves x 64 rows. Two 16KB buffers each holding a ct-PAIR -> 1 barrier per t2 (64 total).
__global__ __launch_bounds__(256, 2) void hyper_q_v7_kernel(
    const short* __restrict__ GS16, const float* __restrict__ Hh,
    const short* __restrict__ Wp, const float* __restrict__ hwb,
    float* __restrict__ Qpart) {
  __shared__ short Bh[2][8192];   // 2 x 16KB (each = ct pair)
  const int tid = threadIdx.x;
  const int wave = tid >> 6, lane = tid & 63;
  const int cl = lane & 15, kg = lane >> 4;
  const int half = blockIdx.x >> 8;
  const int wrow = (blockIdx.x & 255) * 256 + wave * 64;
  const int ct_base = half * 128;

  // ---- A (gs bf16) -> registers: 4 m-frags x 8 kk, direct 16B loads ----
  short8_t ah[4][8];
#pragma unroll
  for (int m = 0; m < 4; ++m) {
    const short* ap = GS16 + (size_t)(wrow + m * 16 + cl) * 256;
#pragma unroll
    for (int kk = 0; kk < 8; ++kk) ah[m][kk] = *(const short8_t*)(ap + kk * 32 + kg * 8);
  }

  // ---- prologue: stage ct pair {base, base+1} into buf 0 ----
  {
    const short* wp0 = Wp + (size_t)ct_base * 4096;
#pragma unroll
    for (int k = 0; k < 4; ++k)
      *(short8_t*)&Bh[0][k * 2048 + tid * 8] = *(const short8_t*)(wp0 + k * 2048 + tid * 8);
  }
  __syncthreads();

  float qf[4][2][4] = {};  // [m][oh][j]
  int cur = 0;

#define COMPUTE_CT(BUFP, OH, WB)                                               \
  {                                                                            \
    f32x4_t acc[4];                                                            \
    _Pragma("unroll")                                                          \
    for (int m = 0; m < 4; ++m) acc[m] = (f32x4_t){0.f, 0.f, 0.f, 0.f};        \
    _Pragma("unroll")                                                          \
    for (int kk = 0; kk < 8; ++kk) {                                           \
      short8_t b_h = *(const short8_t*)((BUFP) + ((OH) * 4096 + (kk * 64 + lane) * 8)); \
      _Pragma("unroll")                                                        \
      for (int m = 0; m < 4; ++m) MFMA(acc[m], ah[m][kk], b_h);                \
    }                                                                          \
    _Pragma("unroll")                                                          \
    for (int m = 0; m < 4; ++m)                                                \
      _Pragma("unroll")                                                        \
      for (int j = 0; j < 4; ++j)                                              \
        qf[m][OH][j] = fmaf(hc[m * 4 + j], acc[m][j] + (WB), qf[m][OH][j]);    \
  }

  for (int t2 = 0; t2 < 64; ++t2) {
    const int ct0 = ct_base + t2 * 2;
    // h column (half*64 + t2) for this wave's 64 rows
    float hc[16];
    {
      const float* hp = Hh + (size_t)(wrow + kg * 4) * 128 + half * 64 + t2;
#pragma unroll
      for (int m = 0; m < 4; ++m)
#pragma unroll
        for (int j = 0; j < 4; ++j)
          hc[m * 4 + j] = hp[(size_t)(m * 16 + j) * 128];
    }
    float wb0 = hwb[ct0 * 16 + cl];
    float wb1 = hwb[(ct0 + 1) * 16 + cl];
    // prefetch next ct pair to registers
    short8_t s[4];
    if (t2 < 63) {
      const short* wpn = Wp + (size_t)(ct0 + 2) * 4096;
#pragma unroll
      for (int k = 0; k < 4; ++k) s[k] = *(const short8_t*)(wpn + k * 2048 + tid * 8);
    }
    const short* bufp = &Bh[cur][0];
    COMPUTE_CT(bufp, 0, wb0)
    COMPUTE_CT(bufp, 1, wb1)
    if (t2 < 63) {
      short* bufn = &Bh[cur ^ 1][0];
#pragma unroll
      for (int k = 0; k < 4; ++k) *(short8_t*)(bufn + k * 2048 + tid * 8) = s[k];
    }
    __syncthreads();
    cur ^= 1;
  }
#undef COMPUTE_CT

  // ---- half 0 adds fc2_b = gs @ hb_w via packed chunks 256/257 (direct L2) ----
  if (half == 0) {
#pragma unroll
    for (int oh = 0; oh < 2; ++oh) {
      f32x4_t bacc[4];
#pragma unroll
      for (int m = 0; m < 4; ++m) bacc[m] = (f32x4_t){0.f, 0.f, 0.f, 0.f};
#pragma unroll
      for (int kk = 0; kk < 8; ++kk) {
        short8_t b_h = *(const short8_t*)(Wp + (((size_t)(256 + oh) * 8 + kk) * 64 + lane) * 8);
#pragma unroll
        for (int m = 0; m < 4; ++m) MFMA(bacc[m], ah[m][kk], b_h);
      }
#pragma unroll
      for (int m = 0; m < 4; ++m)
#pragma unroll
        for (int j = 0; j < 4; ++j) qf[m][oh][j] += bacc[m][j];
    }
  }

  // ---- write partial q ----
  float* qp = Qpart + (size_t)half * 2097152;
#pragma unroll
  for (int m = 0; m < 4; ++m)
#pragma unroll
    for (int j = 0; j < 4; ++j) {
      const size_t r = (size_t)(wrow + m * 16 + kg * 4 + j) * 32;
      qp[r + cl] = qf[m][0][j];
      qp[r + 16 + cl] = qf[m][1][j];
    }
}

// ---------------- combine: q = qpart0 + qpart1 + hb_b ----------------
__global__ __launch_bounds__(256) void qcombine_kernel(
    const float* __restrict__ Qpart, const float* __restrict__ hbb,
    float* __restrict__ Qout) {
  int i = blockIdx.x * 256 + threadIdx.x;  // 524288 float4s
  float4 a = ((const float4*)Qpart)[i];
  float4 b = ((const float4*)(Qpart + 2097152))[i];
  float4 e = ((const float4*)hbb)[i & 7];
  ((float4*)Qout)[i] = make_float4(a.x + b.x + e.x, a.y + b.y + e.y,
                                   a.z + b.z + e.z, a.w + b.w + e.w);
}

extern "C" void kernel_launch(void* const* d_in, const int* in_sizes, int n_in,
                              void* d_out, int out_size, void* d_ws, size_t ws_size,
                              hipStream_t stream) {
  const float* inputs   = (const float*)d_in[0];
  const float* hidden   = (const float*)d_in[1];
  const float* fc1_w    = (const float*)d_in[2];
  const float* fc1_b    = (const float*)d_in[3];
  const float* gru_wi   = (const float*)d_in[4];
  const float* gru_wh   = (const float*)d_in[5];
  const float* gru_bi   = (const float*)d_in[6];
  const float* gru_bh   = (const float*)d_in[7];
  const float* attn_q_w = (const float*)d_in[8];
  const float* attn_k_w = (const float*)d_in[9];
  const float* se1_w    = (const float*)d_in[10];
  const float* se1_b    = (const float*)d_in[11];
  const float* se2_w    = (const float*)d_in[12];
  const float* se2_b    = (const float*)d_in[13];
  const float* ga_w     = (const float*)d_in[14];
  const float* ga_b     = (const float*)d_in[15];
  const float* gemb     = (const float*)d_in[16];
  const float* gd1_w    = (const float*)d_in[17];
  const float* gd1_b    = (const float*)d_in[18];
  const float* gd2_w    = (const float*)d_in[19];
  const float* gd2_b    = (const float*)d_in[20];
  const float* hb_w     = (const float*)d_in[21];
  const float* hb_b     = (const float*)d_in[22];
  const float* hw_w     = (const float*)d_in[23];
  const float* hw_b     = (const float*)d_in[24];

  float* out = (float*)d_out;
  float* q_out     = out;              // [R,32]
  float* h_out     = out + 2097152;    // [R,128]
  float* gs_out    = out + 10485760;   // [R,256]
  float* probs_out = out + 27262976;   // [R,3]
  float* attn_out  = out + 27459584;   // [B,32,32]

  // workspace layout (bytes):
  //   region0 [0, 64MiB): qk bf16 [R,256] -> t bf16 [R,256] -> qpart f32 [2][R,32] (16MB)
  //   [64MiB): si bf16 [R,64] (8MB, dead after fused_se) -> gs16 bf16 [R,256] (33.5MB)
  //   [98MiB): x1 bf16 [R,128] (16MB)
  //   [120MiB): packs (2.8MB)
  char* wsb = (char*)d_ws;
  short* qk = (short*)wsb;
  short* t  = (short*)wsb;
  float* qpart = (float*)wsb;
  short* si   = (short*)(wsb + (size_t)64 * 1024 * 1024);
  short* gs16 = (short*)(wsb + (size_t)64 * 1024 * 1024);
  short* x1   = (short*)(wsb + (size_t)98 * 1024 * 1024);
  short* P    = (short*)(wsb + (size_t)120 * 1024 * 1024);

  // pack offsets (shorts); chunk = KK*512 shorts
  const size_t o_hw  = 0;        // K=256 KK=8, N=4096 -> 1,048,576 (+hb chunks 256..257)
  const size_t o_hb  = 1048576;
  const size_t o_fc1 = 1056768;
  const size_t o_wi  = 1077248;
  const size_t o_wh  = 1126400;
  const size_t o_qkq = 1175552;
  const size_t o_qkk = 1191936;
  const size_t o_se1 = 1208320;
  const size_t o_se2 = 1224704;
  const size_t o_gd1 = 1290240;
  const size_t o_gd2 = 1355776;

  PackArgs pa;
  pa.s[0]  = {hw_w,     256, 4096, 8, 0,    4096, o_hw};
  pa.s[1]  = {hb_w,     256, 32,   8, 4096, 32,   o_hb};
  pa.s[2]  = {fc1_w,    160, 128,  5, 4128, 80,   o_fc1};
  pa.s[3]  = {gru_wi,   128, 384,  4, 4208, 192,  o_wi};
  pa.s[4]  = {gru_wh,   128, 384,  4, 4400, 192,  o_wh};
  pa.s[5]  = {attn_q_w, 128, 128,  4, 4592, 64,   o_qkq};
  pa.s[6]  = {attn_k_w, 128, 128,  4, 4656, 64,   o_qkk};
  pa.s[7]  = {se1_w,    34,  256,  2, 4720, 64,   o_se1};
  pa.s[8]  = {se2_w,    256, 256,  8, 4784, 256,  o_se2};
  pa.s[9]  = {gd1_w,    256, 256,  8, 5040, 256,  o_gd1};
  pa.s[10] = {gd2_w,    256, 256,  8, 5296, 256,  o_gd2};

  dim3 blk(256);
  // 0) pack ALL weights in one launch
  pack_all_kernel<<<5552, blk, 0, stream>>>(pa, P);
  // 1) x1 = relu(inputs @ fc1_w + fc1_b)  f32 -> bf16
  mfma_gemm_kernel<5, 8, 1, 0, 1><<<512, blk, 0, stream>>>(inputs, 160, P + o_fc1, fc1_b, x1);
  // 2) h = GRUCell(x1 bf16, hidden f32) -> h_out f32
  gru_mfma_kernel<<<512, blk, 0, stream>>>(x1, hidden, P + o_wi, P + o_wh, gru_bi, gru_bh, h_out);
  // 3) qk = h @ [q|k]  f32 -> bf16
  mfma_gemm_kernel<4, 16, 0, 0, 1><<<512, blk, 0, stream>>>(h_out, 128, P + o_qkq, nullptr, qk);
  // 4) attention -> attn_out f32 + si bf16
  attn_kernel<<<2048, blk, 0, stream>>>(qk, attn_out, si);
  // 5+6) struct_feat = tanh(relu(si@se1+b1)@se2+b2) -> gs_out f32 (fused)
  fused2_kernel<2, 0><<<512, blk, 0, stream>>>(si, 64, P + o_se1, se1_b, P + o_se2, se2_b,
                                               gs_out, nullptr);
  // 7) probs f32 + t bf16
  group_kernel<<<16384, blk, 0, stream>>>(gs_out, ga_w, ga_b, gemb, probs_out, t);
  // 8+9) group_state = tanh(relu(t@gd1+b1)@gd2+b2) -> gs_out f32 + gs16 bf16 (fused, dual)
  fused2_kernel<8, 1><<<512, blk, 0, stream>>>(t, 256, P + o_gd1, gd1_b, P + o_gd2, gd2_b,
                                               gs_out, gs16);
  // 10) q partials: half-split ct-pair-dbuf MFMA hypernet (t dead -> qpart reuses region0)
  hyper_q_v7_kernel<<<dim3(512), blk, 0, stream>>>(gs16, h_out, P + o_hw, hw_b, qpart);
  // 11) q = qpart0 + qpart1 + hb_b
  qcombine_kernel<<<2048, blk, 0, stream>>>(qpart, hb_b, q_out);
}

// Round 10
// 414.292 us; speedup vs baseline: 1.6088x; 1.0330x over previous
//
#include <hip/hip_runtime.h>
#include <math.h>

// B=2048, A=32 -> R=65536 rows. E_IN=160, H=128, HE=256, NACT=32, G=3, TAU=1.
#define R_TOTAL 65536

typedef __attribute__((ext_vector_type(8))) short short8_t;
typedef __attribute__((ext_vector_type(4))) short short4_t;
typedef __attribute__((ext_vector_type(4))) float f32x4_t;

__device__ __forceinline__ float sigmoidf_(float x) { return 1.f / (1.f + expf(-x)); }

__device__ __forceinline__ short f2bf(float x) {
  unsigned u = __float_as_uint(x);
  u += 0x7fff + ((u >> 16) & 1);   // round-to-nearest-even
  return (short)(u >> 16);
}
__device__ __forceinline__ float bf2f(short s) {
  return __uint_as_float(((unsigned)(unsigned short)s) << 16);
}

// Load 8 consecutive floats -> bf16 fragment (RNE).
__device__ __forceinline__ void load_afrag(const float* p, short8_t& h) {
  float4 u0 = *(const float4*)p;
  float4 u1 = *(const float4*)(p + 4);
  float v[8] = {u0.x, u0.y, u0.z, u0.w, u1.x, u1.y, u1.z, u1.w};
#pragma unroll
  for (int i = 0; i < 8; ++i) h[i] = f2bf(v[i]);
}

#define MFMA(ACC, A, B) ACC = __builtin_amdgcn_mfma_f32_16x16x32_bf16(A, B, ACC, 0, 0, 0)

// ---------------- fused fragment pack: all weights in one launch ----------------
struct PackSeg {
  const float* W;
  int Ksrc, N, KK, blk0, nblk;
  size_t off;
};
struct PackArgs { PackSeg s[11]; };

__global__ __launch_bounds__(256) void pack_all_kernel(PackArgs a, short* __restrict__ P) {
  const int b = blockIdx.x;
  PackSeg seg = a.s[0];
#pragma unroll
  for (int i = 1; i < 11; ++i)
    if (b >= a.s[i].blk0) seg = a.s[i];
  int p = (b - seg.blk0) * 256 + threadIdx.x;
  int i = p & 7, lane = (p >> 3) & 63, kk = (p >> 9) % seg.KK, ct = p / (seg.KK * 512);
  int e = kk * 32 + (lane >> 4) * 8 + i;
  int c = ct * 16 + (lane & 15);
  float w = (e < seg.Ksrc) ? seg.W[(size_t)e * seg.N + c] : 0.f;
  P[seg.off + p] = f2bf(w);
}

// ---------------- fused fc1 + GRU: h = GRUCell(relu(inputs@fc1+b), h_in) ----------------
// Stage 1: x = relu(inputs@fc1W+b1) -> swizzled LDS (128x128 bf16, 32 KB).
// Stage 2: GRU with x frags from LDS, h frags from global f32.
__global__ __launch_bounds__(256) void gru_fused_kernel(
    const float* __restrict__ inputs, const float* __restrict__ Hin,
    const short* __restrict__ Fc1p, const float* __restrict__ fc1b,
    const short* __restrict__ WiP, const short* __restrict__ WhP,
    const float* __restrict__ gbi, const float* __restrict__ gbh,
    float* __restrict__ Hout) {
  __shared__ short mid[128 * 128];   // 32 KB, 256B rows, XOR-swizzled
  const int tid = threadIdx.x;
  const int wave = tid >> 6, lane = tid & 63;
  const int cl = lane & 15, kg = lane >> 4;
  const int row0g = blockIdx.x * 128 + wave * 32;
  const int row0l = wave * 32;

  // ---- stage 1: x = relu(inputs @ fc1 + b) ----
  {
    short8_t ah1[2][5];
#pragma unroll
    for (int m = 0; m < 2; ++m) {
      const float* ap = inputs + (size_t)(row0g + m * 16 + cl) * 160;
#pragma unroll
      for (int kk = 0; kk < 5; ++kk) load_afrag(ap + kk * 32 + kg * 8, ah1[m][kk]);
    }
    for (int ct = 0; ct < 8; ++ct) {
      f32x4_t a0 = (f32x4_t){0.f, 0.f, 0.f, 0.f};
      f32x4_t a1 = (f32x4_t){0.f, 0.f, 0.f, 0.f};
#pragma unroll
      for (int kk = 0; kk < 5; ++kk) {
        short8_t b_h = *(const short8_t*)(Fc1p + (((size_t)ct * 5 + kk) * 64 + lane) * 8);
        MFMA(a0, ah1[0][kk], b_h);
        MFMA(a1, ah1[1][kk], b_h);
      }
      int col = ct * 16 + cl;
      float bv = fc1b[col];
      int c2hi = (col * 2) & ~15, c2lo = (col * 2) & 15;
#pragma unroll
      for (int j = 0; j < 4; ++j) {
        float v0 = fmaxf(a0[j] + bv, 0.f);
        float v1 = fmaxf(a1[j] + bv, 0.f);
        int r0 = row0l + kg * 4 + j;
        int r1 = row0l + 16 + kg * 4 + j;
        int ad0 = ((r0 * 256 + c2hi) ^ ((r0 & 7) << 4)) + c2lo;
        int ad1 = ((r1 * 256 + c2hi) ^ ((r1 & 7) << 4)) + c2lo;
        *(short*)((char*)mid + ad0) = f2bf(v0);
        *(short*)((char*)mid + ad1) = f2bf(v1);
      }
    }
  }
  __syncthreads();

  // ---- stage 2: GRU ----
  short8_t xh[2][4], hh[2][4];
#pragma unroll
  for (int m = 0; m < 2; ++m) {
    int row = row0l + m * 16 + cl;
    const float* hp = Hin + (size_t)(row0g + m * 16 + cl) * 128;
#pragma unroll
    for (int kk = 0; kk < 4; ++kk) {
      int ad = (row * 256 + kk * 64 + kg * 16) ^ ((row & 7) << 4);
      xh[m][kk] = *(const short8_t*)((const char*)mid + ad);
      load_afrag(hp + kk * 32 + kg * 8, hh[m][kk]);
    }
  }
#define GLOAD(P, CT) *(const short8_t*)((P) + (((size_t)(CT) * 4 + kk) * 64 + lane) * 8)
  for (int ct = 0; ct < 8; ++ct) {
    f32x4_t aXr[2], aXz[2], aXn[2], aHr[2], aHz[2], aHn[2];
#pragma unroll
    for (int m = 0; m < 2; ++m) {
      aXr[m] = (f32x4_t){0.f, 0.f, 0.f, 0.f};
      aXz[m] = (f32x4_t){0.f, 0.f, 0.f, 0.f};
      aXn[m] = (f32x4_t){0.f, 0.f, 0.f, 0.f};
      aHr[m] = (f32x4_t){0.f, 0.f, 0.f, 0.f};
      aHz[m] = (f32x4_t){0.f, 0.f, 0.f, 0.f};
      aHn[m] = (f32x4_t){0.f, 0.f, 0.f, 0.f};
    }
#pragma unroll
    for (int kk = 0; kk < 4; ++kk) {
      short8_t b_h;
      b_h = GLOAD(WiP, ct);      MFMA(aXr[0], xh[0][kk], b_h); MFMA(aXr[1], xh[1][kk], b_h);
      b_h = GLOAD(WiP, ct + 8);  MFMA(aXz[0], xh[0][kk], b_h); MFMA(aXz[1], xh[1][kk], b_h);
      b_h = GLOAD(WiP, ct + 16); MFMA(aXn[0], xh[0][kk], b_h); MFMA(aXn[1], xh[1][kk], b_h);
      b_h = GLOAD(WhP, ct);      MFMA(aHr[0], hh[0][kk], b_h); MFMA(aHr[1], hh[1][kk], b_h);
      b_h = GLOAD(WhP, ct + 8);  MFMA(aHz[0], hh[0][kk], b_h); MFMA(aHz[1], hh[1][kk], b_h);
      b_h = GLOAD(WhP, ct + 16); MFMA(aHn[0], hh[0][kk], b_h); MFMA(aHn[1], hh[1][kk], b_h);
    }
    int col = ct * 16 + cl;
    float bir = gbi[col], biz = gbi[128 + col], bin = gbi[256 + col];
    float bhr = gbh[col], bhz = gbh[128 + col], bhn = gbh[256 + col];
#pragma unroll
    for (int m = 0; m < 2; ++m)
#pragma unroll
      for (int j = 0; j < 4; ++j) {
        int row = row0g + m * 16 + kg * 4 + j;
        float rg = sigmoidf_(aXr[m][j] + aHr[m][j] + bir + bhr);
        float zg = sigmoidf_(aXz[m][j] + aHz[m][j] + biz + bhz);
        float ng = tanhf(aXn[m][j] + bin + rg * (aHn[m][j] + bhn));
        float hv = Hin[(size_t)row * 128 + col];
        Hout[(size_t)row * 128 + col] = (1.f - zg) * ng + zg * hv;
      }
  }
#undef GLOAD
}

// ---------------- fused attention: q/k projection (MFMA) + scores + softmax ----------------
// One b per block; wave w computes proj (w>>1: 0=q,1=k) cols [(w&1)*64, +64).
__global__ __launch_bounds__(256) void attn_fused_kernel(
    const float* __restrict__ Hh, const short* __restrict__ QKp,
    float* __restrict__ attn_out, short* __restrict__ si) {
  __shared__ float qs[32][129];
  __shared__ float ks[32][129];
  __shared__ float p[32][33];
  __shared__ float a2[32][33];
  const int b = blockIdx.x;
  const int tid = threadIdx.x;
  const int wave = tid >> 6, lane = tid & 63;
  const int cl = lane & 15, kg = lane >> 4;

  // ---- q/k projection via MFMA ----
  {
    short8_t ahf[2][4];
#pragma unroll
    for (int m = 0; m < 2; ++m) {
      const float* ap = Hh + (size_t)(b * 32 + m * 16 + cl) * 128;
#pragma unroll
      for (int kk = 0; kk < 4; ++kk) load_afrag(ap + kk * 32 + kg * 8, ahf[m][kk]);
    }
    const int proj = wave >> 1;
    const short* Wbase = QKp + (size_t)proj * 16384;
    float* dst = proj ? &ks[0][0] : &qs[0][0];
#pragma unroll
    for (int ct4 = 0; ct4 < 4; ++ct4) {
      int ct = (wave & 1) * 4 + ct4;
      f32x4_t a0 = (f32x4_t){0.f, 0.f, 0.f, 0.f};
      f32x4_t a1 = (f32x4_t){0.f, 0.f, 0.f, 0.f};
#pragma unroll
      for (int kk = 0; kk < 4; ++kk) {
        short8_t b_h = *(const short8_t*)(Wbase + (((size_t)ct * 4 + kk) * 64 + lane) * 8);
        MFMA(a0, ahf[0][kk], b_h);
        MFMA(a1, ahf[1][kk], b_h);
      }
      int col = ct * 16 + cl;
#pragma unroll
      for (int j = 0; j < 4; ++j) {
        dst[(kg * 4 + j) * 129 + col] = a0[j];
        dst[(16 + kg * 4 + j) * 129 + col] = a1[j];
      }
    }
  }
  __syncthreads();

  const float scale = 0.088388347648318447f;  // 1/sqrt(128)
#pragma unroll
  for (int tI = 0; tI < 4; ++tI) {
    int t = tid + tI * 256;
    int i = t >> 5, j = t & 31;
    float s = 0.f;
    for (int e = 0; e < 128; ++e) s = fmaf(qs[i][e], ks[j][e], s);
    p[i][j] = (i == j) ? -1e9f : s * scale;
  }
  __syncthreads();
  if (tid < 32) {
    const int i = tid;
    float m = -1e30f;
    for (int j = 0; j < 32; ++j) m = fmaxf(m, p[i][j]);
    float sum = 0.f;
    for (int j = 0; j < 32; ++j) {
      float e = expf(p[i][j] - m);
      p[i][j] = e;
      sum += e;
    }
    float inv = 1.f / sum;
    for (int j = 0; j < 32; ++j) p[i][j] *= inv;
  }
  __syncthreads();
#pragma unroll
  for (int tI = 0; tI < 4; ++tI) {
    int t = tid + tI * 256;
    int i = t >> 5, j = t & 31;
    float v = (i == j) ? 0.f : 0.5f * (p[i][j] + p[j][i]);
    a2[i][j] = v;
    attn_out[(size_t)b * 1024 + t] = v;
  }
  __syncthreads();
  if (tid < 32) {
    const int i = tid;
    float d = 0.f, en = 0.f;
    for (int j = 0; j < 32; ++j) {
      float v = a2[i][j];
      d += v;
      float c = fmaxf(v, 1e-8f);
      en -= c * logf(c);
    }
    short* srow = si + ((size_t)b * 32 + i) * 64;
    for (int j = 0; j < 32; ++j) srow[j] = f2bf(a2[i][j]);
    srow[32] = f2bf(d);
    srow[33] = f2bf(en);
    for (int j = 34; j < 64; ++j) srow[j] = 0;
  }
}

// ---------------- fused two-layer MLP: C = tanh(relu(A@W1+b1)@W2+b2) ----------------
// A bf16 [R,lda]; mid (128x256 bf16) in XOR-swizzled LDS. CMODE: 0 f32, 1 dual, 2 bf16.
template <int KK1, int CMODE>
__global__ __launch_bounds__(256) void fused2_kernel(
    const short* __restrict__ A, int lda,
    const short* __restrict__ W1p, const float* __restrict__ b1,
    const short* __restrict__ W2p, const float* __restrict__ b2,
    float* __restrict__ C, short* __restrict__ C16) {
  __shared__ short mid[128 * 256];   // 64 KB
  const int tid = threadIdx.x;
  const int wave = tid >> 6, lane = tid & 63;
  const int cl = lane & 15, kg = lane >> 4;
  const int row0g = blockIdx.x * 128 + wave * 32;
  const int row0l = wave * 32;

  {
    short8_t ah1[2][KK1];
#pragma unroll
    for (int m = 0; m < 2; ++m) {
      const short* ap = A + (size_t)(row0g + m * 16 + cl) * lda;
#pragma unroll
      for (int kk = 0; kk < KK1; ++kk)
        ah1[m][kk] = *(const short8_t*)(ap + kk * 32 + kg * 8);
    }
    for (int ct = 0; ct < 16; ++ct) {
      f32x4_t a0 = (f32x4_t){0.f, 0.f, 0.f, 0.f};
      f32x4_t a1 = (f32x4_t){0.f, 0.f, 0.f, 0.f};
#pragma unroll
      for (int kk = 0; kk < KK1; ++kk) {
        short8_t b_h = *(const short8_t*)(W1p + (((size_t)ct * KK1 + kk) * 64 + lane) * 8);
        MFMA(a0, ah1[0][kk], b_h);
        MFMA(a1, ah1[1][kk], b_h);
      }
      int col = ct * 16 + cl;
      float bv = b1[col];
      int c2hi = (col * 2) & ~15, c2lo = (col * 2) & 15;
#pragma unroll
      for (int j = 0; j < 4; ++j) {
        float v0 = fmaxf(a0[j] + bv, 0.f);
        float v1 = fmaxf(a1[j] + bv, 0.f);
        int r0 = row0l + kg * 4 + j;
        int r1 = row0l + 16 + kg * 4 + j;
        int ad0 = ((r0 * 512 + c2hi) ^ ((r0 & 7) << 4)) + c2lo;
        int ad1 = ((r1 * 512 + c2hi) ^ ((r1 & 7) << 4)) + c2lo;
        *(short*)((char*)mid + ad0) = f2bf(v0);
        *(short*)((char*)mid + ad1) = f2bf(v1);
      }
    }
  }
  __syncthreads();

  short8_t ah2[2][8];
#pragma unroll
  for (int m = 0; m < 2; ++m) {
    int row = row0l + m * 16 + cl;
#pragma unroll
    for (int kk = 0; kk < 8; ++kk) {
      int ad = (row * 512 + kk * 64 + kg * 16) ^ ((row & 7) << 4);
      ah2[m][kk] = *(const short8_t*)((const char*)mid + ad);
    }
  }
  for (int ct = 0; ct < 16; ++ct) {
    f32x4_t a0 = (f32x4_t){0.f, 0.f, 0.f, 0.f};
    f32x4_t a1 = (f32x4_t){0.f, 0.f, 0.f, 0.f};
#pragma unroll
    for (int kk = 0; kk < 8; ++kk) {
      short8_t b_h = *(const short8_t*)(W2p + (((size_t)ct * 8 + kk) * 64 + lane) * 8);
      MFMA(a0, ah2[0][kk], b_h);
      MFMA(a1, ah2[1][kk], b_h);
    }
    int col = ct * 16 + cl;
    float bv = b2[col];
#pragma unroll
    for (int j = 0; j < 4; ++j) {
      float v0 = tanhf(a0[j] + bv);
      float v1 = tanhf(a1[j] + bv);
      size_t r0 = (size_t)(row0g + kg * 4 + j) * 256 + col;
      size_t r1 = (size_t)(row0g + 16 + kg * 4 + j) * 256 + col;
      if (CMODE <= 1) { C[r0] = v0; C[r1] = v1; }
      if (CMODE >= 1) { C16[r0] = f2bf(v0); C16[r1] = f2bf(v1); }
    }
  }
}

// ---------------- fused group + group_decoder ----------------
// Reads sf16 bf16 [R,256]; computes probs (out) + t in-register; then
// gs = tanh(relu(t@gd1+b1)@gd2+b2) -> C f32 + C16 bf16.
__global__ __launch_bounds__(256) void fused_gd_group_kernel(
    const short* __restrict__ SF16,
    const float* __restrict__ ga_w, const float* __restrict__ ga_b,
    const float* __restrict__ gemb, float* __restrict__ probs,
    const short* __restrict__ W1p, const float* __restrict__ b1,
    const short* __restrict__ W2p, const float* __restrict__ b2,
    float* __restrict__ C, short* __restrict__ C16) {
  __shared__ short mid[128 * 256];   // 64 KB
  const int tid = threadIdx.x;
  const int wave = tid >> 6, lane = tid & 63;
  const int cl = lane & 15, kg = lane >> 4;
  const int row0g = blockIdx.x * 128 + wave * 32;
  const int row0l = wave * 32;

  // ---- group assign inline: sf frags -> logits -> probs -> t frags ----
  short8_t ah1[2][8];
  {
    short8_t sfr[2][8];
    float lg[2][3] = {};
#pragma unroll
    for (int m = 0; m < 2; ++m) {
      const short* ap = SF16 + (size_t)(row0g + m * 16 + cl) * 256;
#pragma unroll
      for (int kk = 0; kk < 8; ++kk) {
        short8_t s = *(const short8_t*)(ap + kk * 32 + kg * 8);
        sfr[m][kk] = s;
        int e0 = kk * 32 + kg * 8;
#pragma unroll
        for (int i = 0; i < 8; ++i) {
          float v = bf2f(s[i]);
          lg[m][0] = fmaf(v, ga_w[(e0 + i) * 3 + 0], lg[m][0]);
          lg[m][1] = fmaf(v, ga_w[(e0 + i) * 3 + 1], lg[m][1]);
          lg[m][2] = fmaf(v, ga_w[(e0 + i) * 3 + 2], lg[m][2]);
        }
      }
    }
    // reduce across kg groups (lanes ^16, ^32)
#pragma unroll
    for (int m = 0; m < 2; ++m)
#pragma unroll
      for (int g = 0; g < 3; ++g) {
        lg[m][g] += __shfl_xor(lg[m][g], 16, 64);
        lg[m][g] += __shfl_xor(lg[m][g], 32, 64);
      }
#pragma unroll
    for (int m = 0; m < 2; ++m) {
      float l0 = lg[m][0] + ga_b[0], l1 = lg[m][1] + ga_b[1], l2 = lg[m][2] + ga_b[2];
      float mx = fmaxf(l0, fmaxf(l1, l2));
      float e0 = expf(l0 - mx), e1 = expf(l1 - mx), e2 = expf(l2 - mx);
      float inv = 1.f / (e0 + e1 + e2);
      float p0 = e0 * inv, p1 = e1 * inv, p2 = e2 * inv;
      if (kg == 0) {
        size_t r = (size_t)(row0g + m * 16 + cl) * 3;
        probs[r + 0] = p0;
        probs[r + 1] = p1;
        probs[r + 2] = p2;
      }
      // t frag = sf + p @ emb
#pragma unroll
      for (int kk = 0; kk < 8; ++kk) {
        int e0i = kk * 32 + kg * 8;
        short8_t tf;
#pragma unroll
        for (int i = 0; i < 8; ++i) {
          float tv = bf2f(sfr[m][kk][i]) + p0 * gemb[e0i + i] +
                     p1 * gemb[256 + e0i + i] + p2 * gemb[512 + e0i + i];
          tf[i] = f2bf(tv);
        }
        ah1[m][kk] = tf;
      }
    }
  }

  // ---- stage 1: mid = relu(t@gd1 + b1) -> swizzled LDS ----
  for (int ct = 0; ct < 16; ++ct) {
    f32x4_t a0 = (f32x4_t){0.f, 0.f, 0.f, 0.f};
    f32x4_t a1 = (f32x4_t){0.f, 0.f, 0.f, 0.f};
#pragma unroll
    for (int kk = 0; kk < 8; ++kk) {
      short8_t b_h = *(const short8_t*)(W1p + (((size_t)ct * 8 + kk) * 64 + lane) * 8);
      MFMA(a0, ah1[0][kk], b_h);
      MFMA(a1, ah1[1][kk], b_h);
    }
    int col = ct * 16 + cl;
    float bv = b1[col];
    int c2hi = (col * 2) & ~15, c2lo = (col * 2) & 15;
#pragma unroll
    for (int j = 0; j < 4; ++j) {
      float v0 = fmaxf(a0[j] + bv, 0.f);
      float v1 = fmaxf(a1[j] + bv, 0.f);
      int r0 = row0l + kg * 4 + j;
      int r1 = row0l + 16 + kg * 4 + j;
      int ad0 = ((r0 * 512 + c2hi) ^ ((r0 & 7) << 4)) + c2lo;
      int ad1 = ((r1 * 512 + c2hi) ^ ((r1 & 7) << 4)) + c2lo;
      *(short*)((char*)mid + ad0) = f2bf(v0);
      *(short*)((char*)mid + ad1) = f2bf(v1);
    }
  }
  __syncthreads();

  // ---- stage 2: gs = tanh(mid@gd2 + b2) -> C f32 + C16 bf16 ----
  short8_t ah2[2][8];
#pragma unroll
  for (int m = 0; m < 2; ++m) {
    int row = row0l + m * 16 + cl;
#pragma unroll
    for (int kk = 0; kk < 8; ++kk) {
      int ad = (row * 512 + kk * 64 + kg * 16) ^ ((row & 7) << 4);
      ah2[m][kk] = *(const short8_t*)((const char*)mid + ad);
    }
  }
  for (int ct = 0; ct < 16; ++ct) {
    f32x4_t a0 = (f32x4_t){0.f, 0.f, 0.f, 0.f};
    f32x4_t a1 = (f32x4_t){0.f, 0.f, 0.f, 0.f};
#pragma unroll
    for (int kk = 0; kk < 8; ++kk) {
      short8_t b_h = *(const short8_t*)(W2p + (((size_t)ct * 8 + kk) * 64 + lane) * 8);
      MFMA(a0, ah2[0][kk], b_h);
      MFMA(a1, ah2[1][kk], b_h);
    }
    int col = ct * 16 + cl;
    float bv = b2[col];
#pragma unroll
    for (int j = 0; j < 4; ++j) {
      float v0 = tanhf(a0[j] + bv);
      float v1 = tanhf(a1[j] + bv);
      size_t r0 = (size_t)(row0g + kg * 4 + j) * 256 + col;
      size_t r1 = (size_t)(row0g + 16 + kg * 4 + j) * 256 + col;
      C[r0] = v0;
      C[r1] = v1;
      C16[r0] = f2bf(v0);
      C16[r1] = f2bf(v1);
    }
  }
}

// ---------------- MFMA hypernet q v7: half-split, bf16 A, ct-pair LDS dbuf --------------
__global__ __launch_bounds__(256, 2) void hyper_q_v7_kernel(
    const short* __restrict__ GS16, const float* __restrict__ Hh,
    const short* __restrict__ Wp, const float* __restrict__ hwb,
    float* __restrict__ Qpart) {
  __shared__ short Bh[2][8192];   // 2 x 16KB (each = ct pair)
  const int tid = threadIdx.x;
  const int wave = tid >> 6, lane = tid & 63;
  const int cl = lane & 15, kg = lane >> 4;
  const int half = blockIdx.x >> 8;
  const int wrow = (blockIdx.x & 255) * 256 + wave * 64;
  const int ct_base = half * 128;

  short8_t ah[4][8];
#pragma unroll
  for (int m = 0; m < 4; ++m) {
    const short* ap = GS16 + (size_t)(wrow + m * 16 + cl) * 256;
#pragma unroll
    for (int kk = 0; kk < 8; ++kk) ah[m][kk] = *(const short8_t*)(ap + kk * 32 + kg * 8);
  }

  {
    const short* wp0 = Wp + (size_t)ct_base * 4096;
#pragma unroll
    for (int k = 0; k < 4; ++k)
      *(short8_t*)&Bh[0][k * 2048 + tid * 8] = *(const short8_t*)(wp0 + k * 2048 + tid * 8);
  }
  __syncthreads();

  float qf[4][2][4] = {};
  int cur = 0;

#define COMPUTE_CT(BUFP, OH, WB)                                               \
  {                                                                            \
    f32x4_t acc[4];                                                            \
    _Pragma("unroll")                                                          \
    for (int m = 0; m < 4; ++m) acc[m] = (f32x4_t){0.f, 0.f, 0.f, 0.f};        \
    _Pragma("unroll")                                                          \
    for (int kk = 0; kk < 8; ++kk) {                                           \
      short8_t b_h = *(const short8_t*)((BUFP) + ((OH) * 4096 + (kk * 64 + lane) * 8)); \
      _Pragma("unroll")                                                        \
      for (int m = 0; m < 4; ++m) MFMA(acc[m], ah[m][kk], b_h);                \
    }                                                                          \
    _Pragma("unroll")                                                          \
    for (int m = 0; m < 4; ++m)                                                \
      _Pragma("unroll")                                                        \
      for (int j = 0; j < 4; ++j)                                              \
        qf[m][OH][j] = fmaf(hc[m * 4 + j], acc[m][j] + (WB), qf[m][OH][j]);    \
  }

  for (int t2 = 0; t2 < 64; ++t2) {
    const int ct0 = ct_base + t2 * 2;
    float hc[16];
    {
      const float* hp = Hh + (size_t)(wrow + kg * 4) * 128 + half * 64 + t2;
#pragma unroll
      for (int m = 0; m < 4; ++m)
#pragma unroll
        for (int j = 0; j < 4; ++j)
          hc[m * 4 + j] = hp[(size_t)(m * 16 + j) * 128];
    }
    float wb0 = hwb[ct0 * 16 + cl];
    float wb1 = hwb[(ct0 + 1) * 16 + cl];
    short8_t s[4];
    if (t2 < 63) {
      const short* wpn = Wp + (size_t)(ct0 + 2) * 4096;
#pragma unroll
      for (int k = 0; k < 4; ++k) s[k] = *(const short8_t*)(wpn + k * 2048 + tid * 8);
    }
    const short* bufp = &Bh[cur][0];
    COMPUTE_CT(bufp, 0, wb0)
    COMPUTE_CT(bufp, 1, wb1)
    if (t2 < 63) {
      short* bufn = &Bh[cur ^ 1][0];
#pragma unroll
      for (int k = 0; k < 4; ++k) *(short8_t*)(bufn + k * 2048 + tid * 8) = s[k];
    }
    __syncthreads();
    cur ^= 1;
  }
#undef COMPUTE_CT

  if (half == 0) {
#pragma unroll
    for (int oh = 0; oh < 2; ++oh) {
      f32x4_t bacc[4];
#pragma unroll
      for (int m = 0; m < 4; ++m) bacc[m] = (f32x4_t){0.f, 0.f, 0.f, 0.f};
#pragma unroll
      for (int kk = 0; kk < 8; ++kk) {
        short8_t b_h = *(const short8_t*)(Wp + (((size_t)(256 + oh) * 8 + kk) * 64 + lane) * 8);
#pragma unroll
        for (int m = 0; m < 4; ++m) MFMA(bacc[m], ah[m][kk], b_h);
      }
#pragma unroll
      for (int m = 0; m < 4; ++m)
#pragma unroll
        for (int j = 0; j < 4; ++j) qf[m][oh][j] += bacc[m][j];
    }
  }

  float* qp = Qpart + (size_t)half * 2097152;
#pragma unroll
  for (int m = 0; m < 4; ++m)
#pragma unroll
    for (int j = 0; j < 4; ++j) {
      const size_t r = (size_t)(wrow + m * 16 + kg * 4 + j) * 32;
      qp[r + cl] = qf[m][0][j];
      qp[r + 16 + cl] = qf[m][1][j];
    }
}

// ---------------- combine: q = qpart0 + qpart1 + hb_b ----------------
__global__ __launch_bounds__(256) void qcombine_kernel(
    const float* __restrict__ Qpart, const float* __restrict__ hbb,
    float* __restrict__ Qout) {
  int i = blockIdx.x * 256 + threadIdx.x;  // 524288 float4s
  float4 a = ((const float4*)Qpart)[i];
  float4 b = ((const float4*)(Qpart + 2097152))[i];
  float4 e = ((const float4*)hbb)[i & 7];
  ((float4*)Qout)[i] = make_float4(a.x + b.x + e.x, a.y + b.y + e.y,
                                   a.z + b.z + e.z, a.w + b.w + e.w);
}

extern "C" void kernel_launch(void* const* d_in, const int* in_sizes, int n_in,
                              void* d_out, int out_size, void* d_ws, size_t ws_size,
                              hipStream_t stream) {
  const float* inputs   = (const float*)d_in[0];
  const float* hidden   = (const float*)d_in[1];
  const float* fc1_w    = (const float*)d_in[2];
  const float* fc1_b    = (const float*)d_in[3];
  const float* gru_wi   = (const float*)d_in[4];
  const float* gru_wh   = (const float*)d_in[5];
  const float* gru_bi   = (const float*)d_in[6];
  const float* gru_bh   = (const float*)d_in[7];
  const float* attn_q_w = (const float*)d_in[8];
  const float* attn_k_w = (const float*)d_in[9];
  const float* se1_w    = (const float*)d_in[10];
  const float* se1_b    = (const float*)d_in[11];
  const float* se2_w    = (const float*)d_in[12];
  const float* se2_b    = (const float*)d_in[13];
  const float* ga_w     = (const float*)d_in[14];
  const float* ga_b     = (const float*)d_in[15];
  const float* gemb     = (const float*)d_in[16];
  const float* gd1_w    = (const float*)d_in[17];
  const float* gd1_b    = (const float*)d_in[18];
  const float* gd2_w    = (const float*)d_in[19];
  const float* gd2_b    = (const float*)d_in[20];
  const float* hb_w     = (const float*)d_in[21];
  const float* hb_b     = (const float*)d_in[22];
  const float* hw_w     = (const float*)d_in[23];
  const float* hw_b     = (const float*)d_in[24];

  float* out = (float*)d_out;
  float* q_out     = out;              // [R,32]
  float* h_out     = out + 2097152;    // [R,128]
  float* gs_out    = out + 10485760;   // [R,256]
  float* probs_out = out + 27262976;   // [R,3]
  float* attn_out  = out + 27459584;   // [B,32,32]

  // workspace layout (bytes), all regions disjoint:
  //   [0,16M):   qpart f32 [2][R,32]
  //   [16M,24M): si bf16 [R,64]
  //   [24M,56M): sf16 bf16 [R,256]
  //   [56M,88M): gs16 bf16 [R,256]
  //   [88M,+2.8M): packs
  char* wsb = (char*)d_ws;
  float* qpart = (float*)wsb;
  short* si   = (short*)(wsb + (size_t)16 * 1024 * 1024);
  short* sf16 = (short*)(wsb + (size_t)24 * 1024 * 1024);
  short* gs16 = (short*)(wsb + (size_t)56 * 1024 * 1024);
  short* P    = (short*)(wsb + (size_t)88 * 1024 * 1024);

  // pack offsets (shorts); chunk = KK*512 shorts
  const size_t o_hw  = 0;        // K=256 KK=8, N=4096 (+hb chunks 256..257)
  const size_t o_hb  = 1048576;
  const size_t o_fc1 = 1056768;
  const size_t o_wi  = 1077248;
  const size_t o_wh  = 1126400;
  const size_t o_qkq = 1175552;
  const size_t o_qkk = 1191936;  // must be o_qkq + 16384 (attn assumes contiguity)
  const size_t o_se1 = 1208320;
  const size_t o_se2 = 1224704;
  const size_t o_gd1 = 1290240;
  const size_t o_gd2 = 1355776;

  PackArgs pa;
  pa.s[0]  = {hw_w,     256, 4096, 8, 0,    4096, o_hw};
  pa.s[1]  = {hb_w,     256, 32,   8, 4096, 32,   o_hb};
  pa.s[2]  = {fc1_w,    160, 128,  5, 4128, 80,   o_fc1};
  pa.s[3]  = {gru_wi,   128, 384,  4, 4208, 192,  o_wi};
  pa.s[4]  = {gru_wh,   128, 384,  4, 4400, 192,  o_wh};
  pa.s[5]  = {attn_q_w, 128, 128,  4, 4592, 64,   o_qkq};
  pa.s[6]  = {attn_k_w, 128, 128,  4, 4656, 64,   o_qkk};
  pa.s[7]  = {se1_w,    34,  256,  2, 4720, 64,   o_se1};
  pa.s[8]  = {se2_w,    256, 256,  8, 4784, 256,  o_se2};
  pa.s[9]  = {gd1_w,    256, 256,  8, 5040, 256,  o_gd1};
  pa.s[10] = {gd2_w,    256, 256,  8, 5296, 256,  o_gd2};

  dim3 blk(256);
  // 0) pack ALL weights in one launch
  pack_all_kernel<<<5552, blk, 0, stream>>>(pa, P);
  // 1) h = GRUCell(relu(inputs@fc1+b), hidden) -> h_out f32  (fc1 fused)
  gru_fused_kernel<<<512, blk, 0, stream>>>(inputs, hidden, P + o_fc1, fc1_b,
                                            P + o_wi, P + o_wh, gru_bi, gru_bh, h_out);
  // 2) attention (q/k proj fused) -> attn_out f32 + si bf16
  attn_fused_kernel<<<2048, blk, 0, stream>>>(h_out, P + o_qkq, attn_out, si);
  // 3) struct_feat = tanh(relu(si@se1+b1)@se2+b2) -> sf16 bf16 only
  fused2_kernel<2, 2><<<512, blk, 0, stream>>>(si, 64, P + o_se1, se1_b, P + o_se2, se2_b,
                                               nullptr, sf16);
  // 4) group assign + group_state = tanh(relu(t@gd1+b1)@gd2+b2) -> probs + gs_out f32 + gs16
  fused_gd_group_kernel<<<512, blk, 0, stream>>>(sf16, ga_w, ga_b, gemb, probs_out,
                                                 P + o_gd1, gd1_b, P + o_gd2, gd2_b,
                                                 gs_out, gs16);
  // 5) q partials: half-split ct-pair-dbuf MFMA hypernet
  hyper_q_v7_kernel<<<dim3(512), blk, 0, stream>>>(gs16, h_out, P + o_hw, hw_b, qpart);
  // 6) q = qpart0 + qpart1 + hb_b
  qcombine_kernel<<<2048, blk, 0, stream>>>(qpart, hb_b, q_out);
}

// Round 11
// 371.277 us; speedup vs baseline: 1.7952x; 1.1159x over previous
//
#include <hip/hip_runtime.h>
#include <math.h>

// B=2048, A=32 -> R=65536 rows. E_IN=160, H=128, HE=256, NACT=32, G=3, TAU=1.
#define R_TOTAL 65536

typedef __attribute__((ext_vector_type(8))) short short8_t;
typedef __attribute__((ext_vector_type(4))) short short4_t;
typedef __attribute__((ext_vector_type(4))) float f32x4_t;

__device__ __forceinline__ float sigmoidf_(float x) { return 1.f / (1.f + expf(-x)); }

__device__ __forceinline__ short f2bf(float x) {
  unsigned u = __float_as_uint(x);
  u += 0x7fff + ((u >> 16) & 1);   // round-to-nearest-even
  return (short)(u >> 16);
}
__device__ __forceinline__ float bf2f(short s) {
  return __uint_as_float(((unsigned)(unsigned short)s) << 16);
}

// Load 8 consecutive floats -> bf16 fragment (RNE).
__device__ __forceinline__ void load_afrag(const float* p, short8_t& h) {
  float4 u0 = *(const float4*)p;
  float4 u1 = *(const float4*)(p + 4);
  float v[8] = {u0.x, u0.y, u0.z, u0.w, u1.x, u1.y, u1.z, u1.w};
#pragma unroll
  for (int i = 0; i < 8; ++i) h[i] = f2bf(v[i]);
}

#define MFMA(ACC, A, B) ACC = __builtin_amdgcn_mfma_f32_16x16x32_bf16(A, B, ACC, 0, 0, 0)

// ---------------- fused fragment pack: all weights in one launch ----------------
struct PackSeg {
  const float* W;
  int Ksrc, N, KK, blk0, nblk;
  size_t off;
};
struct PackArgs { PackSeg s[11]; };

__global__ __launch_bounds__(256) void pack_all_kernel(PackArgs a, short* __restrict__ P) {
  const int b = blockIdx.x;
  PackSeg seg = a.s[0];
#pragma unroll
  for (int i = 1; i < 11; ++i)
    if (b >= a.s[i].blk0) seg = a.s[i];
  int p = (b - seg.blk0) * 256 + threadIdx.x;
  int i = p & 7, lane = (p >> 3) & 63, kk = (p >> 9) % seg.KK, ct = p / (seg.KK * 512);
  int e = kk * 32 + (lane >> 4) * 8 + i;
  int c = ct * 16 + (lane & 15);
  float w = (e < seg.Ksrc) ? seg.W[(size_t)e * seg.N + c] : 0.f;
  P[seg.off + p] = f2bf(w);
}

// ---------------- fused fc1 + GRU: h = GRUCell(relu(inputs@fc1+b), h_in) ----------------
__global__ __launch_bounds__(256) void gru_fused_kernel(
    const float* __restrict__ inputs, const float* __restrict__ Hin,
    const short* __restrict__ Fc1p, const float* __restrict__ fc1b,
    const short* __restrict__ WiP, const short* __restrict__ WhP,
    const float* __restrict__ gbi, const float* __restrict__ gbh,
    float* __restrict__ Hout) {
  __shared__ short mid[128 * 128];   // 32 KB, 256B rows, XOR-swizzled
  const int tid = threadIdx.x;
  const int wave = tid >> 6, lane = tid & 63;
  const int cl = lane & 15, kg = lane >> 4;
  const int row0g = blockIdx.x * 128 + wave * 32;
  const int row0l = wave * 32;

  // ---- stage 1: x = relu(inputs @ fc1 + b) ----
  {
    short8_t ah1[2][5];
#pragma unroll
    for (int m = 0; m < 2; ++m) {
      const float* ap = inputs + (size_t)(row0g + m * 16 + cl) * 160;
#pragma unroll
      for (int kk = 0; kk < 5; ++kk) load_afrag(ap + kk * 32 + kg * 8, ah1[m][kk]);
    }
    for (int ct = 0; ct < 8; ++ct) {
      f32x4_t a0 = (f32x4_t){0.f, 0.f, 0.f, 0.f};
      f32x4_t a1 = (f32x4_t){0.f, 0.f, 0.f, 0.f};
#pragma unroll
      for (int kk = 0; kk < 5; ++kk) {
        short8_t b_h = *(const short8_t*)(Fc1p + (((size_t)ct * 5 + kk) * 64 + lane) * 8);
        MFMA(a0, ah1[0][kk], b_h);
        MFMA(a1, ah1[1][kk], b_h);
      }
      int col = ct * 16 + cl;
      float bv = fc1b[col];
      int c2hi = (col * 2) & ~15, c2lo = (col * 2) & 15;
#pragma unroll
      for (int j = 0; j < 4; ++j) {
        float v0 = fmaxf(a0[j] + bv, 0.f);
        float v1 = fmaxf(a1[j] + bv, 0.f);
        int r0 = row0l + kg * 4 + j;
        int r1 = row0l + 16 + kg * 4 + j;
        int ad0 = ((r0 * 256 + c2hi) ^ ((r0 & 7) << 4)) + c2lo;
        int ad1 = ((r1 * 256 + c2hi) ^ ((r1 & 7) << 4)) + c2lo;
        *(short*)((char*)mid + ad0) = f2bf(v0);
        *(short*)((char*)mid + ad1) = f2bf(v1);
      }
    }
  }
  __syncthreads();

  // ---- stage 2: GRU ----
  short8_t xh[2][4], hh[2][4];
#pragma unroll
  for (int m = 0; m < 2; ++m) {
    int row = row0l + m * 16 + cl;
    const float* hp = Hin + (size_t)(row0g + m * 16 + cl) * 128;
#pragma unroll
    for (int kk = 0; kk < 4; ++kk) {
      int ad = (row * 256 + kk * 64 + kg * 16) ^ ((row & 7) << 4);
      xh[m][kk] = *(const short8_t*)((const char*)mid + ad);
      load_afrag(hp + kk * 32 + kg * 8, hh[m][kk]);
    }
  }
#define GLOAD(P, CT) *(const short8_t*)((P) + (((size_t)(CT) * 4 + kk) * 64 + lane) * 8)
  for (int ct = 0; ct < 8; ++ct) {
    f32x4_t aXr[2], aXz[2], aXn[2], aHr[2], aHz[2], aHn[2];
#pragma unroll
    for (int m = 0; m < 2; ++m) {
      aXr[m] = (f32x4_t){0.f, 0.f, 0.f, 0.f};
      aXz[m] = (f32x4_t){0.f, 0.f, 0.f, 0.f};
      aXn[m] = (f32x4_t){0.f, 0.f, 0.f, 0.f};
      aHr[m] = (f32x4_t){0.f, 0.f, 0.f, 0.f};
      aHz[m] = (f32x4_t){0.f, 0.f, 0.f, 0.f};
      aHn[m] = (f32x4_t){0.f, 0.f, 0.f, 0.f};
    }
#pragma unroll
    for (int kk = 0; kk < 4; ++kk) {
      short8_t b_h;
      b_h = GLOAD(WiP, ct);      MFMA(aXr[0], xh[0][kk], b_h); MFMA(aXr[1], xh[1][kk], b_h);
      b_h = GLOAD(WiP, ct + 8);  MFMA(aXz[0], xh[0][kk], b_h); MFMA(aXz[1], xh[1][kk], b_h);
      b_h = GLOAD(WiP, ct + 16); MFMA(aXn[0], xh[0][kk], b_h); MFMA(aXn[1], xh[1][kk], b_h);
      b_h = GLOAD(WhP, ct);      MFMA(aHr[0], hh[0][kk], b_h); MFMA(aHr[1], hh[1][kk], b_h);
      b_h = GLOAD(WhP, ct + 8);  MFMA(aHz[0], hh[0][kk], b_h); MFMA(aHz[1], hh[1][kk], b_h);
      b_h = GLOAD(WhP, ct + 16); MFMA(aHn[0], hh[0][kk], b_h); MFMA(aHn[1], hh[1][kk], b_h);
    }
    int col = ct * 16 + cl;
    float bir = gbi[col], biz = gbi[128 + col], bin = gbi[256 + col];
    float bhr = gbh[col], bhz = gbh[128 + col], bhn = gbh[256 + col];
#pragma unroll
    for (int m = 0; m < 2; ++m)
#pragma unroll
      for (int j = 0; j < 4; ++j) {
        int row = row0g + m * 16 + kg * 4 + j;
        float rg = sigmoidf_(aXr[m][j] + aHr[m][j] + bir + bhr);
        float zg = sigmoidf_(aXz[m][j] + aHz[m][j] + biz + bhz);
        float ng = tanhf(aXn[m][j] + bin + rg * (aHn[m][j] + bhn));
        float hv = Hin[(size_t)row * 128 + col];
        Hout[(size_t)row * 128 + col] = (1.f - zg) * ng + zg * hv;
      }
  }
#undef GLOAD
}

// ---------------- fused attention v2: MFMA proj + MFMA scores + parallel softmax --------
// One b per block. Proj -> swizzled bf16 LDS; scores: wave (mi,nj) tile via 4 MFMAs
// (B-frag of k^T == A-style frag of k). Softmax/si: 8 threads per row, shfl reduce.
__global__ __launch_bounds__(256) void attn_fused_kernel(
    const float* __restrict__ Hh, const short* __restrict__ QKp,
    float* __restrict__ attn_out, short* __restrict__ si) {
  __shared__ short qkb[2][32 * 128];   // 2 x 8 KB, 256B rows, XOR-swizzled
  __shared__ float p[32][33];
  __shared__ float a2[32][33];
  const int b = blockIdx.x;
  const int tid = threadIdx.x;
  const int wave = tid >> 6, lane = tid & 63;
  const int cl = lane & 15, kg = lane >> 4;

  // ---- proj: q/k = h @ Wq/Wk -> bf16 LDS ----
  {
    short8_t ahf[2][4];
#pragma unroll
    for (int m = 0; m < 2; ++m) {
      const float* ap = Hh + (size_t)(b * 32 + m * 16 + cl) * 128;
#pragma unroll
      for (int kk = 0; kk < 4; ++kk) load_afrag(ap + kk * 32 + kg * 8, ahf[m][kk]);
    }
    const int proj = wave >> 1;
    const short* Wbase = QKp + (size_t)proj * 16384;
    short* dst = &qkb[proj][0];
#pragma unroll
    for (int ct4 = 0; ct4 < 4; ++ct4) {
      int ct = (wave & 1) * 4 + ct4;
      f32x4_t a0 = (f32x4_t){0.f, 0.f, 0.f, 0.f};
      f32x4_t a1 = (f32x4_t){0.f, 0.f, 0.f, 0.f};
#pragma unroll
      for (int kk = 0; kk < 4; ++kk) {
        short8_t b_h = *(const short8_t*)(Wbase + (((size_t)ct * 4 + kk) * 64 + lane) * 8);
        MFMA(a0, ahf[0][kk], b_h);
        MFMA(a1, ahf[1][kk], b_h);
      }
      int col = ct * 16 + cl;
      int c2hi = (col * 2) & ~15, c2lo = (col * 2) & 15;
#pragma unroll
      for (int j = 0; j < 4; ++j) {
        int r0 = kg * 4 + j;
        int r1 = 16 + kg * 4 + j;
        int ad0 = ((r0 * 256 + c2hi) ^ ((r0 & 7) << 4)) + c2lo;
        int ad1 = ((r1 * 256 + c2hi) ^ ((r1 & 7) << 4)) + c2lo;
        *(short*)((char*)dst + ad0) = f2bf(a0[j]);
        *(short*)((char*)dst + ad1) = f2bf(a1[j]);
      }
    }
  }
  __syncthreads();

  // ---- scores via MFMA: wave computes tile (mi, nj) ----
  {
    const int mi = wave >> 1, nj = wave & 1;
    short8_t qf[4], kf[4];
    int rq = mi * 16 + cl, rk = nj * 16 + cl;
#pragma unroll
    for (int kk = 0; kk < 4; ++kk) {
      int adq = (rq * 256 + kk * 64 + kg * 16) ^ ((rq & 7) << 4);
      int adk = (rk * 256 + kk * 64 + kg * 16) ^ ((rk & 7) << 4);
      qf[kk] = *(const short8_t*)((const char*)&qkb[0][0] + adq);
      kf[kk] = *(const short8_t*)((const char*)&qkb[1][0] + adk);
    }
    f32x4_t acc = (f32x4_t){0.f, 0.f, 0.f, 0.f};
#pragma unroll
    for (int kk = 0; kk < 4; ++kk) MFMA(acc, qf[kk], kf[kk]);
    const float scale = 0.088388347648318447f;  // 1/sqrt(128)
#pragma unroll
    for (int j = 0; j < 4; ++j) {
      int r = mi * 16 + kg * 4 + j;
      int c = nj * 16 + cl;
      p[r][c] = (r == c) ? -1e9f : acc[j] * scale;
    }
  }
  __syncthreads();

  // ---- softmax: 8 threads per row ----
  {
    int row = tid >> 3, g = tid & 7;
    float v[4];
    float mx = -1e30f;
#pragma unroll
    for (int c0 = 0; c0 < 4; ++c0) {
      v[c0] = p[row][g * 4 + c0];
      mx = fmaxf(mx, v[c0]);
    }
#pragma unroll
    for (int off = 1; off < 8; off <<= 1) mx = fmaxf(mx, __shfl_xor(mx, off, 64));
    float s = 0.f;
#pragma unroll
    for (int c0 = 0; c0 < 4; ++c0) {
      v[c0] = expf(v[c0] - mx);
      s += v[c0];
    }
#pragma unroll
    for (int off = 1; off < 8; off <<= 1) s += __shfl_xor(s, off, 64);
    float inv = 1.f / s;
#pragma unroll
    for (int c0 = 0; c0 < 4; ++c0) p[row][g * 4 + c0] = v[c0] * inv;
  }
  __syncthreads();

  // ---- symmetrize + attn_out ----
#pragma unroll
  for (int tI = 0; tI < 4; ++tI) {
    int t = tid + tI * 256;
    int i = t >> 5, j = t & 31;
    float v = (i == j) ? 0.f : 0.5f * (p[i][j] + p[j][i]);
    a2[i][j] = v;
    attn_out[(size_t)b * 1024 + t] = v;
  }
  __syncthreads();

  // ---- struct input: 8 threads per row ----
  {
    int row = tid >> 3, g = tid & 7;
    float vv[4];
    float d = 0.f, en = 0.f;
#pragma unroll
    for (int c0 = 0; c0 < 4; ++c0) {
      float v = a2[row][g * 4 + c0];
      vv[c0] = v;
      d += v;
      float c = fmaxf(v, 1e-8f);
      en -= c * logf(c);
    }
#pragma unroll
    for (int off = 1; off < 8; off <<= 1) {
      d += __shfl_xor(d, off, 64);
      en += __shfl_xor(en, off, 64);
    }
    short* srow = si + ((size_t)b * 32 + row) * 64;
#pragma unroll
    for (int c0 = 0; c0 < 4; ++c0) srow[g * 4 + c0] = f2bf(vv[c0]);
    if (g == 0) {
      srow[32] = f2bf(d);
      srow[33] = f2bf(en);
    }
    for (int z = 34 + g; z < 64; z += 8) srow[z] = 0;
  }
}

// ---------------- fused two-layer MLP: C = tanh(relu(A@W1+b1)@W2+b2) ----------------
// A bf16 [R,lda]; mid (128x256 bf16) in XOR-swizzled LDS. CMODE: 0 f32, 1 dual, 2 bf16.
template <int KK1, int CMODE>
__global__ __launch_bounds__(256) void fused2_kernel(
    const short* __restrict__ A, int lda,
    const short* __restrict__ W1p, const float* __restrict__ b1,
    const short* __restrict__ W2p, const float* __restrict__ b2,
    float* __restrict__ C, short* __restrict__ C16) {
  __shared__ short mid[128 * 256];   // 64 KB
  const int tid = threadIdx.x;
  const int wave = tid >> 6, lane = tid & 63;
  const int cl = lane & 15, kg = lane >> 4;
  const int row0g = blockIdx.x * 128 + wave * 32;
  const int row0l = wave * 32;

  {
    short8_t ah1[2][KK1];
#pragma unroll
    for (int m = 0; m < 2; ++m) {
      const short* ap = A + (size_t)(row0g + m * 16 + cl) * lda;
#pragma unroll
      for (int kk = 0; kk < KK1; ++kk)
        ah1[m][kk] = *(const short8_t*)(ap + kk * 32 + kg * 8);
    }
    for (int ct = 0; ct < 16; ++ct) {
      f32x4_t a0 = (f32x4_t){0.f, 0.f, 0.f, 0.f};
      f32x4_t a1 = (f32x4_t){0.f, 0.f, 0.f, 0.f};
#pragma unroll
      for (int kk = 0; kk < KK1; ++kk) {
        short8_t b_h = *(const short8_t*)(W1p + (((size_t)ct * KK1 + kk) * 64 + lane) * 8);
        MFMA(a0, ah1[0][kk], b_h);
        MFMA(a1, ah1[1][kk], b_h);
      }
      int col = ct * 16 + cl;
      float bv = b1[col];
      int c2hi = (col * 2) & ~15, c2lo = (col * 2) & 15;
#pragma unroll
      for (int j = 0; j < 4; ++j) {
        float v0 = fmaxf(a0[j] + bv, 0.f);
        float v1 = fmaxf(a1[j] + bv, 0.f);
        int r0 = row0l + kg * 4 + j;
        int r1 = row0l + 16 + kg * 4 + j;
        int ad0 = ((r0 * 512 + c2hi) ^ ((r0 & 7) << 4)) + c2lo;
        int ad1 = ((r1 * 512 + c2hi) ^ ((r1 & 7) << 4)) + c2lo;
        *(short*)((char*)mid + ad0) = f2bf(v0);
        *(short*)((char*)mid + ad1) = f2bf(v1);
      }
    }
  }
  __syncthreads();

  short8_t ah2[2][8];
#pragma unroll
  for (int m = 0; m < 2; ++m) {
    int row = row0l + m * 16 + cl;
#pragma unroll
    for (int kk = 0; kk < 8; ++kk) {
      int ad = (row * 512 + kk * 64 + kg * 16) ^ ((row & 7) << 4);
      ah2[m][kk] = *(const short8_t*)((const char*)mid + ad);
    }
  }
  for (int ct = 0; ct < 16; ++ct) {
    f32x4_t a0 = (f32x4_t){0.f, 0.f, 0.f, 0.f};
    f32x4_t a1 = (f32x4_t){0.f, 0.f, 0.f, 0.f};
#pragma unroll
    for (int kk = 0; kk < 8; ++kk) {
      short8_t b_h = *(const short8_t*)(W2p + (((size_t)ct * 8 + kk) * 64 + lane) * 8);
      MFMA(a0, ah2[0][kk], b_h);
      MFMA(a1, ah2[1][kk], b_h);
    }
    int col = ct * 16 + cl;
    float bv = b2[col];
#pragma unroll
    for (int j = 0; j < 4; ++j) {
      float v0 = tanhf(a0[j] + bv);
      float v1 = tanhf(a1[j] + bv);
      size_t r0 = (size_t)(row0g + kg * 4 + j) * 256 + col;
      size_t r1 = (size_t)(row0g + 16 + kg * 4 + j) * 256 + col;
      if (CMODE <= 1) { C[r0] = v0; C[r1] = v1; }
      if (CMODE >= 1) { C16[r0] = f2bf(v0); C16[r1] = f2bf(v1); }
    }
  }
}

// ---------------- fused group + group_decoder ----------------
__global__ __launch_bounds__(256) void fused_gd_group_kernel(
    const short* __restrict__ SF16,
    const float* __restrict__ ga_w, const float* __restrict__ ga_b,
    const float* __restrict__ gemb, float* __restrict__ probs,
    const short* __restrict__ W1p, const float* __restrict__ b1,
    const short* __restrict__ W2p, const float* __restrict__ b2,
    float* __restrict__ C, short* __restrict__ C16) {
  __shared__ short mid[128 * 256];   // 64 KB
  const int tid = threadIdx.x;
  const int wave = tid >> 6, lane = tid & 63;
  const int cl = lane & 15, kg = lane >> 4;
  const int row0g = blockIdx.x * 128 + wave * 32;
  const int row0l = wave * 32;

  short8_t ah1[2][8];
  {
    short8_t sfr[2][8];
    float lg[2][3] = {};
#pragma unroll
    for (int m = 0; m < 2; ++m) {
      const short* ap = SF16 + (size_t)(row0g + m * 16 + cl) * 256;
#pragma unroll
      for (int kk = 0; kk < 8; ++kk) {
        short8_t s = *(const short8_t*)(ap + kk * 32 + kg * 8);
        sfr[m][kk] = s;
        int e0 = kk * 32 + kg * 8;
#pragma unroll
        for (int i = 0; i < 8; ++i) {
          float v = bf2f(s[i]);
          lg[m][0] = fmaf(v, ga_w[(e0 + i) * 3 + 0], lg[m][0]);
          lg[m][1] = fmaf(v, ga_w[(e0 + i) * 3 + 1], lg[m][1]);
          lg[m][2] = fmaf(v, ga_w[(e0 + i) * 3 + 2], lg[m][2]);
        }
      }
    }
#pragma unroll
    for (int m = 0; m < 2; ++m)
#pragma unroll
      for (int g = 0; g < 3; ++g) {
        lg[m][g] += __shfl_xor(lg[m][g], 16, 64);
        lg[m][g] += __shfl_xor(lg[m][g], 32, 64);
      }
#pragma unroll
    for (int m = 0; m < 2; ++m) {
      float l0 = lg[m][0] + ga_b[0], l1 = lg[m][1] + ga_b[1], l2 = lg[m][2] + ga_b[2];
      float mx = fmaxf(l0, fmaxf(l1, l2));
      float e0 = expf(l0 - mx), e1 = expf(l1 - mx), e2 = expf(l2 - mx);
      float inv = 1.f / (e0 + e1 + e2);
      float p0 = e0 * inv, p1 = e1 * inv, p2 = e2 * inv;
      if (kg == 0) {
        size_t r = (size_t)(row0g + m * 16 + cl) * 3;
        probs[r + 0] = p0;
        probs[r + 1] = p1;
        probs[r + 2] = p2;
      }
#pragma unroll
      for (int kk = 0; kk < 8; ++kk) {
        int e0i = kk * 32 + kg * 8;
        short8_t tf;
#pragma unroll
        for (int i = 0; i < 8; ++i) {
          float tv = bf2f(sfr[m][kk][i]) + p0 * gemb[e0i + i] +
                     p1 * gemb[256 + e0i + i] + p2 * gemb[512 + e0i + i];
          tf[i] = f2bf(tv);
        }
        ah1[m][kk] = tf;
      }
    }
  }

  for (int ct = 0; ct < 16; ++ct) {
    f32x4_t a0 = (f32x4_t){0.f, 0.f, 0.f, 0.f};
    f32x4_t a1 = (f32x4_t){0.f, 0.f, 0.f, 0.f};
#pragma unroll
    for (int kk = 0; kk < 8; ++kk) {
      short8_t b_h = *(const short8_t*)(W1p + (((size_t)ct * 8 + kk) * 64 + lane) * 8);
      MFMA(a0, ah1[0][kk], b_h);
      MFMA(a1, ah1[1][kk], b_h);
    }
    int col = ct * 16 + cl;
    float bv = b1[col];
    int c2hi = (col * 2) & ~15, c2lo = (col * 2) & 15;
#pragma unroll
    for (int j = 0; j < 4; ++j) {
      float v0 = fmaxf(a0[j] + bv, 0.f);
      float v1 = fmaxf(a1[j] + bv, 0.f);
      int r0 = row0l + kg * 4 + j;
      int r1 = row0l + 16 + kg * 4 + j;
      int ad0 = ((r0 * 512 + c2hi) ^ ((r0 & 7) << 4)) + c2lo;
      int ad1 = ((r1 * 512 + c2hi) ^ ((r1 & 7) << 4)) + c2lo;
      *(short*)((char*)mid + ad0) = f2bf(v0);
      *(short*)((char*)mid + ad1) = f2bf(v1);
    }
  }
  __syncthreads();

  short8_t ah2[2][8];
#pragma unroll
  for (int m = 0; m < 2; ++m) {
    int row = row0l + m * 16 + cl;
#pragma unroll
    for (int kk = 0; kk < 8; ++kk) {
      int ad = (row * 512 + kk * 64 + kg * 16) ^ ((row & 7) << 4);
      ah2[m][kk] = *(const short8_t*)((const char*)mid + ad);
    }
  }
  for (int ct = 0; ct < 16; ++ct) {
    f32x4_t a0 = (f32x4_t){0.f, 0.f, 0.f, 0.f};
    f32x4_t a1 = (f32x4_t){0.f, 0.f, 0.f, 0.f};
#pragma unroll
    for (int kk = 0; kk < 8; ++kk) {
      short8_t b_h = *(const short8_t*)(W2p + (((size_t)ct * 8 + kk) * 64 + lane) * 8);
      MFMA(a0, ah2[0][kk], b_h);
      MFMA(a1, ah2[1][kk], b_h);
    }
    int col = ct * 16 + cl;
    float bv = b2[col];
#pragma unroll
    for (int j = 0; j < 4; ++j) {
      float v0 = tanhf(a0[j] + bv);
      float v1 = tanhf(a1[j] + bv);
      size_t r0 = (size_t)(row0g + kg * 4 + j) * 256 + col;
      size_t r1 = (size_t)(row0g + 16 + kg * 4 + j) * 256 + col;
      C[r0] = v0;
      C[r1] = v1;
      C16[r0] = f2bf(v0);
      C16[r1] = f2bf(v1);
    }
  }
}

// ---------------- MFMA hypernet q v8: quarter-split, bf16 A, ct-pair LDS dbuf ----------
// Grid 1024: quarter = bid>>8 covers h cols [q*32,(q+1)*32), W chunks [q*64,+64).
// 4 waves x 64 rows; 4 blocks/CU (32 KB LDS, 128 VGPR) -> 4 waves/SIMD TLP.
__global__ __launch_bounds__(256, 2) void hyper_q_v8_kernel(
    const short* __restrict__ GS16, const float* __restrict__ Hh,
    const short* __restrict__ Wp, const float* __restrict__ hwb,
    float* __restrict__ Qpart) {
  __shared__ short Bh[2][8192];   // 2 x 16KB (each = ct pair)
  const int tid = threadIdx.x;
  const int wave = tid >> 6, lane = tid & 63;
  const int cl = lane & 15, kg = lane >> 4;
  const int quarter = blockIdx.x >> 8;
  const int wrow = (blockIdx.x & 255) * 256 + wave * 64;
  const int ct_base = quarter * 64;

  short8_t ah[4][8];
#pragma unroll
  for (int m = 0; m < 4; ++m) {
    const short* ap = GS16 + (size_t)(wrow + m * 16 + cl) * 256;
#pragma unroll
    for (int kk = 0; kk < 8; ++kk) ah[m][kk] = *(const short8_t*)(ap + kk * 32 + kg * 8);
  }

  {
    const short* wp0 = Wp + (size_t)ct_base * 4096;
#pragma unroll
    for (int k = 0; k < 4; ++k)
      *(short8_t*)&Bh[0][k * 2048 + tid * 8] = *(const short8_t*)(wp0 + k * 2048 + tid * 8);
  }
  __syncthreads();

  float qf[4][2][4] = {};
  int cur = 0;

#define COMPUTE_CT(BUFP, OH, WB)                                               \
  {                                                                            \
    f32x4_t acc[4];                                                            \
    _Pragma("unroll")                                                          \
    for (int m = 0; m < 4; ++m) acc[m] = (f32x4_t){0.f, 0.f, 0.f, 0.f};        \
    _Pragma("unroll")                                                          \
    for (int kk = 0; kk < 8; ++kk) {                                           \
      short8_t b_h = *(const short8_t*)((BUFP) + ((OH) * 4096 + (kk * 64 + lane) * 8)); \
      _Pragma("unroll")                                                        \
      for (int m = 0; m < 4; ++m) MFMA(acc[m], ah[m][kk], b_h);                \
    }                                                                          \
    _Pragma("unroll")                                                          \
    for (int m = 0; m < 4; ++m)                                                \
      _Pragma("unroll")                                                        \
      for (int j = 0; j < 4; ++j)                                              \
        qf[m][OH][j] = fmaf(hc[m * 4 + j], acc[m][j] + (WB), qf[m][OH][j]);    \
  }

  for (int t2 = 0; t2 < 32; ++t2) {
    const int ct0 = ct_base + t2 * 2;
    float hc[16];
    {
      const float* hp = Hh + (size_t)(wrow + kg * 4) * 128 + quarter * 32 + t2;
#pragma unroll
      for (int m = 0; m < 4; ++m)
#pragma unroll
        for (int j = 0; j < 4; ++j)
          hc[m * 4 + j] = hp[(size_t)(m * 16 + j) * 128];
    }
    float wb0 = hwb[ct0 * 16 + cl];
    float wb1 = hwb[(ct0 + 1) * 16 + cl];
    short8_t s[4];
    if (t2 < 31) {
      const short* wpn = Wp + (size_t)(ct0 + 2) * 4096;
#pragma unroll
      for (int k = 0; k < 4; ++k) s[k] = *(const short8_t*)(wpn + k * 2048 + tid * 8);
    }
    const short* bufp = &Bh[cur][0];
    COMPUTE_CT(bufp, 0, wb0)
    COMPUTE_CT(bufp, 1, wb1)
    if (t2 < 31) {
      short* bufn = &Bh[cur ^ 1][0];
#pragma unroll
      for (int k = 0; k < 4; ++k) *(short8_t*)(bufn + k * 2048 + tid * 8) = s[k];
    }
    __syncthreads();
    cur ^= 1;
  }
#undef COMPUTE_CT

  if (quarter == 0) {
#pragma unroll
    for (int oh = 0; oh < 2; ++oh) {
      f32x4_t bacc[4];
#pragma unroll
      for (int m = 0; m < 4; ++m) bacc[m] = (f32x4_t){0.f, 0.f, 0.f, 0.f};
#pragma unroll
      for (int kk = 0; kk < 8; ++kk) {
        short8_t b_h = *(const short8_t*)(Wp + (((size_t)(256 + oh) * 8 + kk) * 64 + lane) * 8);
#pragma unroll
        for (int m = 0; m < 4; ++m) MFMA(bacc[m], ah[m][kk], b_h);
      }
#pragma unroll
      for (int m = 0; m < 4; ++m)
#pragma unroll
        for (int j = 0; j < 4; ++j) qf[m][oh][j] += bacc[m][j];
    }
  }

  float* qp = Qpart + (size_t)quarter * 2097152;
#pragma unroll
  for (int m = 0; m < 4; ++m)
#pragma unroll
    for (int j = 0; j < 4; ++j) {
      const size_t r = (size_t)(wrow + m * 16 + kg * 4 + j) * 32;
      qp[r + cl] = qf[m][0][j];
      qp[r + 16 + cl] = qf[m][1][j];
    }
}

// ---------------- combine: q = sum(qpart[0..3]) + hb_b ----------------
__global__ __launch_bounds__(256) void qcombine_kernel(
    const float* __restrict__ Qpart, const float* __restrict__ hbb,
    float* __restrict__ Qout) {
  int i = blockIdx.x * 256 + threadIdx.x;  // 524288 float4s
  float4 a = ((const float4*)Qpart)[i];
  float4 b = ((const float4*)(Qpart + 2097152))[i];
  float4 c = ((const float4*)(Qpart + 4194304))[i];
  float4 d = ((const float4*)(Qpart + 6291456))[i];
  float4 e = ((const float4*)hbb)[i & 7];
  ((float4*)Qout)[i] = make_float4(a.x + b.x + c.x + d.x + e.x,
                                   a.y + b.y + c.y + d.y + e.y,
                                   a.z + b.z + c.z + d.z + e.z,
                                   a.w + b.w + c.w + d.w + e.w);
}

extern "C" void kernel_launch(void* const* d_in, const int* in_sizes, int n_in,
                              void* d_out, int out_size, void* d_ws, size_t ws_size,
                              hipStream_t stream) {
  const float* inputs   = (const float*)d_in[0];
  const float* hidden   = (const float*)d_in[1];
  const float* fc1_w    = (const float*)d_in[2];
  const float* fc1_b    = (const float*)d_in[3];
  const float* gru_wi   = (const float*)d_in[4];
  const float* gru_wh   = (const float*)d_in[5];
  const float* gru_bi   = (const float*)d_in[6];
  const float* gru_bh   = (const float*)d_in[7];
  const float* attn_q_w = (const float*)d_in[8];
  const float* attn_k_w = (const float*)d_in[9];
  const float* se1_w    = (const float*)d_in[10];
  const float* se1_b    = (const float*)d_in[11];
  const float* se2_w    = (const float*)d_in[12];
  const float* se2_b    = (const float*)d_in[13];
  const float* ga_w     = (const float*)d_in[14];
  const float* ga_b     = (const float*)d_in[15];
  const float* gemb     = (const float*)d_in[16];
  const float* gd1_w    = (const float*)d_in[17];
  const float* gd1_b    = (const float*)d_in[18];
  const float* gd2_w    = (const float*)d_in[19];
  const float* gd2_b    = (const float*)d_in[20];
  const float* hb_w     = (const float*)d_in[21];
  const float* hb_b     = (const float*)d_in[22];
  const float* hw_w     = (const float*)d_in[23];
  const float* hw_b     = (const float*)d_in[24];

  float* out = (float*)d_out;
  float* q_out     = out;              // [R,32]
  float* h_out     = out + 2097152;    // [R,128]
  float* gs_out    = out + 10485760;   // [R,256]
  float* probs_out = out + 27262976;   // [R,3]
  float* attn_out  = out + 27459584;   // [B,32,32]

  // workspace layout (bytes), all regions disjoint:
  //   [0,32M):   qpart f32 [4][R,32]
  //   [32M,40M): si bf16 [R,64]
  //   [40M,72M): sf16 bf16 [R,256]
  //   [72M,104M): gs16 bf16 [R,256]
  //   [104M,+2.9M): packs
  char* wsb = (char*)d_ws;
  float* qpart = (float*)wsb;
  short* si   = (short*)(wsb + (size_t)32 * 1024 * 1024);
  short* sf16 = (short*)(wsb + (size_t)40 * 1024 * 1024);
  short* gs16 = (short*)(wsb + (size_t)72 * 1024 * 1024);
  short* P    = (short*)(wsb + (size_t)104 * 1024 * 1024);

  // pack offsets (shorts); chunk = KK*512 shorts
  const size_t o_hw  = 0;        // K=256 KK=8, N=4096 (+hb chunks 256..257)
  const size_t o_hb  = 1048576;
  const size_t o_fc1 = 1056768;
  const size_t o_wi  = 1077248;
  const size_t o_wh  = 1126400;
  const size_t o_qkq = 1175552;
  const size_t o_qkk = 1191936;  // must be o_qkq + 16384 (attn assumes contiguity)
  const size_t o_se1 = 1208320;
  const size_t o_se2 = 1224704;
  const size_t o_gd1 = 1290240;
  const size_t o_gd2 = 1355776;

  PackArgs pa;
  pa.s[0]  = {hw_w,     256, 4096, 8, 0,    4096, o_hw};
  pa.s[1]  = {hb_w,     256, 32,   8, 4096, 32,   o_hb};
  pa.s[2]  = {fc1_w,    160, 128,  5, 4128, 80,   o_fc1};
  pa.s[3]  = {gru_wi,   128, 384,  4, 4208, 192,  o_wi};
  pa.s[4]  = {gru_wh,   128, 384,  4, 4400, 192,  o_wh};
  pa.s[5]  = {attn_q_w, 128, 128,  4, 4592, 64,   o_qkq};
  pa.s[6]  = {attn_k_w, 128, 128,  4, 4656, 64,   o_qkk};
  pa.s[7]  = {se1_w,    34,  256,  2, 4720, 64,   o_se1};
  pa.s[8]  = {se2_w,    256, 256,  8, 4784, 256,  o_se2};
  pa.s[9]  = {gd1_w,    256, 256,  8, 5040, 256,  o_gd1};
  pa.s[10] = {gd2_w,    256, 256,  8, 5296, 256,  o_gd2};

  dim3 blk(256);
  // 0) pack ALL weights in one launch
  pack_all_kernel<<<5552, blk, 0, stream>>>(pa, P);
  // 1) h = GRUCell(relu(inputs@fc1+b), hidden) -> h_out f32  (fc1 fused)
  gru_fused_kernel<<<512, blk, 0, stream>>>(inputs, hidden, P + o_fc1, fc1_b,
                                            P + o_wi, P + o_wh, gru_bi, gru_bh, h_out);
  // 2) attention v2 (MFMA proj + MFMA scores + parallel softmax) -> attn_out f32 + si bf16
  attn_fused_kernel<<<2048, blk, 0, stream>>>(h_out, P + o_qkq, attn_out, si);
  // 3) struct_feat = tanh(relu(si@se1+b1)@se2+b2) -> sf16 bf16 only
  fused2_kernel<2, 2><<<512, blk, 0, stream>>>(si, 64, P + o_se1, se1_b, P + o_se2, se2_b,
                                               nullptr, sf16);
  // 4) group assign + group_state -> probs + gs_out f32 + gs16
  fused_gd_group_kernel<<<512, blk, 0, stream>>>(sf16, ga_w, ga_b, gemb, probs_out,
                                                 P + o_gd1, gd1_b, P + o_gd2, gd2_b,
                                                 gs_out, gs16);
  // 5) q partials: quarter-split ct-pair-dbuf MFMA hypernet
  hyper_q_v8_kernel<<<dim3(1024), blk, 0, stream>>>(gs16, h_out, P + o_hw, hw_b, qpart);
  // 6) q = sum(qpart) + hb_b
  qcombine_kernel<<<2048, blk, 0, stream>>>(qpart, hb_b, q_out);
}

// Round 12
// 357.137 us; speedup vs baseline: 1.8662x; 1.0396x over previous
//
#include <hip/hip_runtime.h>
#include <math.h>

// B=2048, A=32 -> R=65536 rows. E_IN=160, H=128, HE=256, NACT=32, G=3, TAU=1.
#define R_TOTAL 65536

typedef __attribute__((ext_vector_type(8))) short short8_t;
typedef __attribute__((ext_vector_type(4))) short short4_t;
typedef __attribute__((ext_vector_type(4))) float f32x4_t;

__device__ __forceinline__ float sigmoidf_(float x) { return 1.f / (1.f + expf(-x)); }

__device__ __forceinline__ short f2bf(float x) {
  unsigned u = __float_as_uint(x);
  u += 0x7fff + ((u >> 16) & 1);   // round-to-nearest-even
  return (short)(u >> 16);
}
__device__ __forceinline__ float bf2f(short s) {
  return __uint_as_float(((unsigned)(unsigned short)s) << 16);
}

// Load 8 consecutive floats -> bf16 fragment (RNE).
__device__ __forceinline__ void load_afrag(const float* p, short8_t& h) {
  float4 u0 = *(const float4*)p;
  float4 u1 = *(const float4*)(p + 4);
  float v[8] = {u0.x, u0.y, u0.z, u0.w, u1.x, u1.y, u1.z, u1.w};
#pragma unroll
  for (int i = 0; i < 8; ++i) h[i] = f2bf(v[i]);
}

#define MFMA(ACC, A, B) ACC = __builtin_amdgcn_mfma_f32_16x16x32_bf16(A, B, ACC, 0, 0, 0)

// ---------------- fused fragment pack: all weights in one launch ----------------
struct PackSeg {
  const float* W;
  int Ksrc, N, KK, blk0, nblk;
  size_t off;
};
struct PackArgs { PackSeg s[11]; };

__global__ __launch_bounds__(256) void pack_all_kernel(PackArgs a, short* __restrict__ P) {
  const int b = blockIdx.x;
  PackSeg seg = a.s[0];
#pragma unroll
  for (int i = 1; i < 11; ++i)
    if (b >= a.s[i].blk0) seg = a.s[i];
  int p = (b - seg.blk0) * 256 + threadIdx.x;
  int i = p & 7, lane = (p >> 3) & 63, kk = (p >> 9) % seg.KK, ct = p / (seg.KK * 512);
  int e = kk * 32 + (lane >> 4) * 8 + i;
  int c = ct * 16 + (lane & 15);
  float w = (e < seg.Ksrc) ? seg.W[(size_t)e * seg.N + c] : 0.f;
  P[seg.off + p] = f2bf(w);
}

// ---------------- fused fc1 + GRU: h = GRUCell(relu(inputs@fc1+b), h_in) ----------------
__global__ __launch_bounds__(256) void gru_fused_kernel(
    const float* __restrict__ inputs, const float* __restrict__ Hin,
    const short* __restrict__ Fc1p, const float* __restrict__ fc1b,
    const short* __restrict__ WiP, const short* __restrict__ WhP,
    const float* __restrict__ gbi, const float* __restrict__ gbh,
    float* __restrict__ Hout) {
  __shared__ short mid[128 * 128];   // 32 KB, 256B rows, XOR-swizzled
  const int tid = threadIdx.x;
  const int wave = tid >> 6, lane = tid & 63;
  const int cl = lane & 15, kg = lane >> 4;
  const int row0g = blockIdx.x * 128 + wave * 32;
  const int row0l = wave * 32;

  // ---- stage 1: x = relu(inputs @ fc1 + b) ----
  {
    short8_t ah1[2][5];
#pragma unroll
    for (int m = 0; m < 2; ++m) {
      const float* ap = inputs + (size_t)(row0g + m * 16 + cl) * 160;
#pragma unroll
      for (int kk = 0; kk < 5; ++kk) load_afrag(ap + kk * 32 + kg * 8, ah1[m][kk]);
    }
    for (int ct = 0; ct < 8; ++ct) {
      f32x4_t a0 = (f32x4_t){0.f, 0.f, 0.f, 0.f};
      f32x4_t a1 = (f32x4_t){0.f, 0.f, 0.f, 0.f};
#pragma unroll
      for (int kk = 0; kk < 5; ++kk) {
        short8_t b_h = *(const short8_t*)(Fc1p + (((size_t)ct * 5 + kk) * 64 + lane) * 8);
        MFMA(a0, ah1[0][kk], b_h);
        MFMA(a1, ah1[1][kk], b_h);
      }
      int col = ct * 16 + cl;
      float bv = fc1b[col];
      int c2hi = (col * 2) & ~15, c2lo = (col * 2) & 15;
#pragma unroll
      for (int j = 0; j < 4; ++j) {
        float v0 = fmaxf(a0[j] + bv, 0.f);
        float v1 = fmaxf(a1[j] + bv, 0.f);
        int r0 = row0l + kg * 4 + j;
        int r1 = row0l + 16 + kg * 4 + j;
        int ad0 = ((r0 * 256 + c2hi) ^ ((r0 & 7) << 4)) + c2lo;
        int ad1 = ((r1 * 256 + c2hi) ^ ((r1 & 7) << 4)) + c2lo;
        *(short*)((char*)mid + ad0) = f2bf(v0);
        *(short*)((char*)mid + ad1) = f2bf(v1);
      }
    }
  }
  __syncthreads();

  // ---- stage 2: GRU ----
  short8_t xh[2][4], hh[2][4];
#pragma unroll
  for (int m = 0; m < 2; ++m) {
    int row = row0l + m * 16 + cl;
    const float* hp = Hin + (size_t)(row0g + m * 16 + cl) * 128;
#pragma unroll
    for (int kk = 0; kk < 4; ++kk) {
      int ad = (row * 256 + kk * 64 + kg * 16) ^ ((row & 7) << 4);
      xh[m][kk] = *(const short8_t*)((const char*)mid + ad);
      load_afrag(hp + kk * 32 + kg * 8, hh[m][kk]);
    }
  }
#define GLOAD(P, CT) *(const short8_t*)((P) + (((size_t)(CT) * 4 + kk) * 64 + lane) * 8)
  for (int ct = 0; ct < 8; ++ct) {
    f32x4_t aXr[2], aXz[2], aXn[2], aHr[2], aHz[2], aHn[2];
#pragma unroll
    for (int m = 0; m < 2; ++m) {
      aXr[m] = (f32x4_t){0.f, 0.f, 0.f, 0.f};
      aXz[m] = (f32x4_t){0.f, 0.f, 0.f, 0.f};
      aXn[m] = (f32x4_t){0.f, 0.f, 0.f, 0.f};
      aHr[m] = (f32x4_t){0.f, 0.f, 0.f, 0.f};
      aHz[m] = (f32x4_t){0.f, 0.f, 0.f, 0.f};
      aHn[m] = (f32x4_t){0.f, 0.f, 0.f, 0.f};
    }
#pragma unroll
    for (int kk = 0; kk < 4; ++kk) {
      short8_t b_h;
      b_h = GLOAD(WiP, ct);      MFMA(aXr[0], xh[0][kk], b_h); MFMA(aXr[1], xh[1][kk], b_h);
      b_h = GLOAD(WiP, ct + 8);  MFMA(aXz[0], xh[0][kk], b_h); MFMA(aXz[1], xh[1][kk], b_h);
      b_h = GLOAD(WiP, ct + 16); MFMA(aXn[0], xh[0][kk], b_h); MFMA(aXn[1], xh[1][kk], b_h);
      b_h = GLOAD(WhP, ct);      MFMA(aHr[0], hh[0][kk], b_h); MFMA(aHr[1], hh[1][kk], b_h);
      b_h = GLOAD(WhP, ct + 8);  MFMA(aHz[0], hh[0][kk], b_h); MFMA(aHz[1], hh[1][kk], b_h);
      b_h = GLOAD(WhP, ct + 16); MFMA(aHn[0], hh[0][kk], b_h); MFMA(aHn[1], hh[1][kk], b_h);
    }
    int col = ct * 16 + cl;
    float bir = gbi[col], biz = gbi[128 + col], bin = gbi[256 + col];
    float bhr = gbh[col], bhz = gbh[128 + col], bhn = gbh[256 + col];
#pragma unroll
    for (int m = 0; m < 2; ++m)
#pragma unroll
      for (int j = 0; j < 4; ++j) {
        int row = row0g + m * 16 + kg * 4 + j;
        float rg = sigmoidf_(aXr[m][j] + aHr[m][j] + bir + bhr);
        float zg = sigmoidf_(aXz[m][j] + aHz[m][j] + biz + bhz);
        float ng = tanhf(aXn[m][j] + bin + rg * (aHn[m][j] + bhn));
        float hv = Hin[(size_t)row * 128 + col];
        Hout[(size_t)row * 128 + col] = (1.f - zg) * ng + zg * hv;
      }
  }
#undef GLOAD
}

// ---------------- fused attention v2: MFMA proj + MFMA scores + parallel softmax --------
__global__ __launch_bounds__(256) void attn_fused_kernel(
    const float* __restrict__ Hh, const short* __restrict__ QKp,
    float* __restrict__ attn_out, short* __restrict__ si) {
  __shared__ short qkb[2][32 * 128];   // 2 x 8 KB, 256B rows, XOR-swizzled
  __shared__ float p[32][33];
  __shared__ float a2[32][33];
  const int b = blockIdx.x;
  const int tid = threadIdx.x;
  const int wave = tid >> 6, lane = tid & 63;
  const int cl = lane & 15, kg = lane >> 4;

  // ---- proj: q/k = h @ Wq/Wk -> bf16 LDS ----
  {
    short8_t ahf[2][4];
#pragma unroll
    for (int m = 0; m < 2; ++m) {
      const float* ap = Hh + (size_t)(b * 32 + m * 16 + cl) * 128;
#pragma unroll
      for (int kk = 0; kk < 4; ++kk) load_afrag(ap + kk * 32 + kg * 8, ahf[m][kk]);
    }
    const int proj = wave >> 1;
    const short* Wbase = QKp + (size_t)proj * 16384;
    short* dst = &qkb[proj][0];
#pragma unroll
    for (int ct4 = 0; ct4 < 4; ++ct4) {
      int ct = (wave & 1) * 4 + ct4;
      f32x4_t a0 = (f32x4_t){0.f, 0.f, 0.f, 0.f};
      f32x4_t a1 = (f32x4_t){0.f, 0.f, 0.f, 0.f};
#pragma unroll
      for (int kk = 0; kk < 4; ++kk) {
        short8_t b_h = *(const short8_t*)(Wbase + (((size_t)ct * 4 + kk) * 64 + lane) * 8);
        MFMA(a0, ahf[0][kk], b_h);
        MFMA(a1, ahf[1][kk], b_h);
      }
      int col = ct * 16 + cl;
      int c2hi = (col * 2) & ~15, c2lo = (col * 2) & 15;
#pragma unroll
      for (int j = 0; j < 4; ++j) {
        int r0 = kg * 4 + j;
        int r1 = 16 + kg * 4 + j;
        int ad0 = ((r0 * 256 + c2hi) ^ ((r0 & 7) << 4)) + c2lo;
        int ad1 = ((r1 * 256 + c2hi) ^ ((r1 & 7) << 4)) + c2lo;
        *(short*)((char*)dst + ad0) = f2bf(a0[j]);
        *(short*)((char*)dst + ad1) = f2bf(a1[j]);
      }
    }
  }
  __syncthreads();

  // ---- scores via MFMA: wave computes tile (mi, nj) ----
  {
    const int mi = wave >> 1, nj = wave & 1;
    short8_t qf[4], kf[4];
    int rq = mi * 16 + cl, rk = nj * 16 + cl;
#pragma unroll
    for (int kk = 0; kk < 4; ++kk) {
      int adq = (rq * 256 + kk * 64 + kg * 16) ^ ((rq & 7) << 4);
      int adk = (rk * 256 + kk * 64 + kg * 16) ^ ((rk & 7) << 4);
      qf[kk] = *(const short8_t*)((const char*)&qkb[0][0] + adq);
      kf[kk] = *(const short8_t*)((const char*)&qkb[1][0] + adk);
    }
    f32x4_t acc = (f32x4_t){0.f, 0.f, 0.f, 0.f};
#pragma unroll
    for (int kk = 0; kk < 4; ++kk) MFMA(acc, qf[kk], kf[kk]);
    const float scale = 0.088388347648318447f;  // 1/sqrt(128)
#pragma unroll
    for (int j = 0; j < 4; ++j) {
      int r = mi * 16 + kg * 4 + j;
      int c = nj * 16 + cl;
      p[r][c] = (r == c) ? -1e9f : acc[j] * scale;
    }
  }
  __syncthreads();

  // ---- softmax: 8 threads per row ----
  {
    int row = tid >> 3, g = tid & 7;
    float v[4];
    float mx = -1e30f;
#pragma unroll
    for (int c0 = 0; c0 < 4; ++c0) {
      v[c0] = p[row][g * 4 + c0];
      mx = fmaxf(mx, v[c0]);
    }
#pragma unroll
    for (int off = 1; off < 8; off <<= 1) mx = fmaxf(mx, __shfl_xor(mx, off, 64));
    float s = 0.f;
#pragma unroll
    for (int c0 = 0; c0 < 4; ++c0) {
      v[c0] = expf(v[c0] - mx);
      s += v[c0];
    }
#pragma unroll
    for (int off = 1; off < 8; off <<= 1) s += __shfl_xor(s, off, 64);
    float inv = 1.f / s;
#pragma unroll
    for (int c0 = 0; c0 < 4; ++c0) p[row][g * 4 + c0] = v[c0] * inv;
  }
  __syncthreads();

  // ---- symmetrize + attn_out ----
#pragma unroll
  for (int tI = 0; tI < 4; ++tI) {
    int t = tid + tI * 256;
    int i = t >> 5, j = t & 31;
    float v = (i == j) ? 0.f : 0.5f * (p[i][j] + p[j][i]);
    a2[i][j] = v;
    attn_out[(size_t)b * 1024 + t] = v;
  }
  __syncthreads();

  // ---- struct input: 8 threads per row ----
  {
    int row = tid >> 3, g = tid & 7;
    float vv[4];
    float d = 0.f, en = 0.f;
#pragma unroll
    for (int c0 = 0; c0 < 4; ++c0) {
      float v = a2[row][g * 4 + c0];
      vv[c0] = v;
      d += v;
      float c = fmaxf(v, 1e-8f);
      en -= c * logf(c);
    }
#pragma unroll
    for (int off = 1; off < 8; off <<= 1) {
      d += __shfl_xor(d, off, 64);
      en += __shfl_xor(en, off, 64);
    }
    short* srow = si + ((size_t)b * 32 + row) * 64;
#pragma unroll
    for (int c0 = 0; c0 < 4; ++c0) srow[g * 4 + c0] = f2bf(vv[c0]);
    if (g == 0) {
      srow[32] = f2bf(d);
      srow[33] = f2bf(en);
    }
    for (int z = 34 + g; z < 64; z += 8) srow[z] = 0;
  }
}

// ---------------- fused two-layer MLP: C = tanh(relu(A@W1+b1)@W2+b2) ----------------
// A bf16 [R,lda]; mid (128x256 bf16) in XOR-swizzled LDS. CMODE: 0 f32, 1 dual, 2 bf16.
template <int KK1, int CMODE>
__global__ __launch_bounds__(256) void fused2_kernel(
    const short* __restrict__ A, int lda,
    const short* __restrict__ W1p, const float* __restrict__ b1,
    const short* __restrict__ W2p, const float* __restrict__ b2,
    float* __restrict__ C, short* __restrict__ C16) {
  __shared__ short mid[128 * 256];   // 64 KB
  const int tid = threadIdx.x;
  const int wave = tid >> 6, lane = tid & 63;
  const int cl = lane & 15, kg = lane >> 4;
  const int row0g = blockIdx.x * 128 + wave * 32;
  const int row0l = wave * 32;

  {
    short8_t ah1[2][KK1];
#pragma unroll
    for (int m = 0; m < 2; ++m) {
      const short* ap = A + (size_t)(row0g + m * 16 + cl) * lda;
#pragma unroll
      for (int kk = 0; kk < KK1; ++kk)
        ah1[m][kk] = *(const short8_t*)(ap + kk * 32 + kg * 8);
    }
    for (int ct = 0; ct < 16; ++ct) {
      f32x4_t a0 = (f32x4_t){0.f, 0.f, 0.f, 0.f};
      f32x4_t a1 = (f32x4_t){0.f, 0.f, 0.f, 0.f};
#pragma unroll
      for (int kk = 0; kk < KK1; ++kk) {
        short8_t b_h = *(const short8_t*)(W1p + (((size_t)ct * KK1 + kk) * 64 + lane) * 8);
        MFMA(a0, ah1[0][kk], b_h);
        MFMA(a1, ah1[1][kk], b_h);
      }
      int col = ct * 16 + cl;
      float bv = b1[col];
      int c2hi = (col * 2) & ~15, c2lo = (col * 2) & 15;
#pragma unroll
      for (int j = 0; j < 4; ++j) {
        float v0 = fmaxf(a0[j] + bv, 0.f);
        float v1 = fmaxf(a1[j] + bv, 0.f);
        int r0 = row0l + kg * 4 + j;
        int r1 = row0l + 16 + kg * 4 + j;
        int ad0 = ((r0 * 512 + c2hi) ^ ((r0 & 7) << 4)) + c2lo;
        int ad1 = ((r1 * 512 + c2hi) ^ ((r1 & 7) << 4)) + c2lo;
        *(short*)((char*)mid + ad0) = f2bf(v0);
        *(short*)((char*)mid + ad1) = f2bf(v1);
      }
    }
  }
  __syncthreads();

  short8_t ah2[2][8];
#pragma unroll
  for (int m = 0; m < 2; ++m) {
    int row = row0l + m * 16 + cl;
#pragma unroll
    for (int kk = 0; kk < 8; ++kk) {
      int ad = (row * 512 + kk * 64 + kg * 16) ^ ((row & 7) << 4);
      ah2[m][kk] = *(const short8_t*)((const char*)mid + ad);
    }
  }
  for (int ct = 0; ct < 16; ++ct) {
    f32x4_t a0 = (f32x4_t){0.f, 0.f, 0.f, 0.f};
    f32x4_t a1 = (f32x4_t){0.f, 0.f, 0.f, 0.f};
#pragma unroll
    for (int kk = 0; kk < 8; ++kk) {
      short8_t b_h = *(const short8_t*)(W2p + (((size_t)ct * 8 + kk) * 64 + lane) * 8);
      MFMA(a0, ah2[0][kk], b_h);
      MFMA(a1, ah2[1][kk], b_h);
    }
    int col = ct * 16 + cl;
    float bv = b2[col];
#pragma unroll
    for (int j = 0; j < 4; ++j) {
      float v0 = tanhf(a0[j] + bv);
      float v1 = tanhf(a1[j] + bv);
      size_t r0 = (size_t)(row0g + kg * 4 + j) * 256 + col;
      size_t r1 = (size_t)(row0g + 16 + kg * 4 + j) * 256 + col;
      if (CMODE <= 1) { C[r0] = v0; C[r1] = v1; }
      if (CMODE >= 1) { C16[r0] = f2bf(v0); C16[r1] = f2bf(v1); }
    }
  }
}

// ---------------- fused group + group_decoder ----------------
__global__ __launch_bounds__(256) void fused_gd_group_kernel(
    const short* __restrict__ SF16,
    const float* __restrict__ ga_w, const float* __restrict__ ga_b,
    const float* __restrict__ gemb, float* __restrict__ probs,
    const short* __restrict__ W1p, const float* __restrict__ b1,
    const short* __restrict__ W2p, const float* __restrict__ b2,
    float* __restrict__ C, short* __restrict__ C16) {
  __shared__ short mid[128 * 256];   // 64 KB
  const int tid = threadIdx.x;
  const int wave = tid >> 6, lane = tid & 63;
  const int cl = lane & 15, kg = lane >> 4;
  const int row0g = blockIdx.x * 128 + wave * 32;
  const int row0l = wave * 32;

  short8_t ah1[2][8];
  {
    short8_t sfr[2][8];
    float lg[2][3] = {};
#pragma unroll
    for (int m = 0; m < 2; ++m) {
      const short* ap = SF16 + (size_t)(row0g + m * 16 + cl) * 256;
#pragma unroll
      for (int kk = 0; kk < 8; ++kk) {
        short8_t s = *(const short8_t*)(ap + kk * 32 + kg * 8);
        sfr[m][kk] = s;
        int e0 = kk * 32 + kg * 8;
#pragma unroll
        for (int i = 0; i < 8; ++i) {
          float v = bf2f(s[i]);
          lg[m][0] = fmaf(v, ga_w[(e0 + i) * 3 + 0], lg[m][0]);
          lg[m][1] = fmaf(v, ga_w[(e0 + i) * 3 + 1], lg[m][1]);
          lg[m][2] = fmaf(v, ga_w[(e0 + i) * 3 + 2], lg[m][2]);
        }
      }
    }
#pragma unroll
    for (int m = 0; m < 2; ++m)
#pragma unroll
      for (int g = 0; g < 3; ++g) {
        lg[m][g] += __shfl_xor(lg[m][g], 16, 64);
        lg[m][g] += __shfl_xor(lg[m][g], 32, 64);
      }
#pragma unroll
    for (int m = 0; m < 2; ++m) {
      float l0 = lg[m][0] + ga_b[0], l1 = lg[m][1] + ga_b[1], l2 = lg[m][2] + ga_b[2];
      float mx = fmaxf(l0, fmaxf(l1, l2));
      float e0 = expf(l0 - mx), e1 = expf(l1 - mx), e2 = expf(l2 - mx);
      float inv = 1.f / (e0 + e1 + e2);
      float p0 = e0 * inv, p1 = e1 * inv, p2 = e2 * inv;
      if (kg == 0) {
        size_t r = (size_t)(row0g + m * 16 + cl) * 3;
        probs[r + 0] = p0;
        probs[r + 1] = p1;
        probs[r + 2] = p2;
      }
#pragma unroll
      for (int kk = 0; kk < 8; ++kk) {
        int e0i = kk * 32 + kg * 8;
        short8_t tf;
#pragma unroll
        for (int i = 0; i < 8; ++i) {
          float tv = bf2f(sfr[m][kk][i]) + p0 * gemb[e0i + i] +
                     p1 * gemb[256 + e0i + i] + p2 * gemb[512 + e0i + i];
          tf[i] = f2bf(tv);
        }
        ah1[m][kk] = tf;
      }
    }
  }

  for (int ct = 0; ct < 16; ++ct) {
    f32x4_t a0 = (f32x4_t){0.f, 0.f, 0.f, 0.f};
    f32x4_t a1 = (f32x4_t){0.f, 0.f, 0.f, 0.f};
#pragma unroll
    for (int kk = 0; kk < 8; ++kk) {
      short8_t b_h = *(const short8_t*)(W1p + (((size_t)ct * 8 + kk) * 64 + lane) * 8);
      MFMA(a0, ah1[0][kk], b_h);
      MFMA(a1, ah1[1][kk], b_h);
    }
    int col = ct * 16 + cl;
    float bv = b1[col];
    int c2hi = (col * 2) & ~15, c2lo = (col * 2) & 15;
#pragma unroll
    for (int j = 0; j < 4; ++j) {
      float v0 = fmaxf(a0[j] + bv, 0.f);
      float v1 = fmaxf(a1[j] + bv, 0.f);
      int r0 = row0l + kg * 4 + j;
      int r1 = row0l + 16 + kg * 4 + j;
      int ad0 = ((r0 * 512 + c2hi) ^ ((r0 & 7) << 4)) + c2lo;
      int ad1 = ((r1 * 512 + c2hi) ^ ((r1 & 7) << 4)) + c2lo;
      *(short*)((char*)mid + ad0) = f2bf(v0);
      *(short*)((char*)mid + ad1) = f2bf(v1);
    }
  }
  __syncthreads();

  short8_t ah2[2][8];
#pragma unroll
  for (int m = 0; m < 2; ++m) {
    int row = row0l + m * 16 + cl;
#pragma unroll
    for (int kk = 0; kk < 8; ++kk) {
      int ad = (row * 512 + kk * 64 + kg * 16) ^ ((row & 7) << 4);
      ah2[m][kk] = *(const short8_t*)((const char*)mid + ad);
    }
  }
  for (int ct = 0; ct < 16; ++ct) {
    f32x4_t a0 = (f32x4_t){0.f, 0.f, 0.f, 0.f};
    f32x4_t a1 = (f32x4_t){0.f, 0.f, 0.f, 0.f};
#pragma unroll
    for (int kk = 0; kk < 8; ++kk) {
      short8_t b_h = *(const short8_t*)(W2p + (((size_t)ct * 8 + kk) * 64 + lane) * 8);
      MFMA(a0, ah2[0][kk], b_h);
      MFMA(a1, ah2[1][kk], b_h);
    }
    int col = ct * 16 + cl;
    float bv = b2[col];
#pragma unroll
    for (int j = 0; j < 4; ++j) {
      float v0 = tanhf(a0[j] + bv);
      float v1 = tanhf(a1[j] + bv);
      size_t r0 = (size_t)(row0g + kg * 4 + j) * 256 + col;
      size_t r1 = (size_t)(row0g + 16 + kg * 4 + j) * 256 + col;
      C[r0] = v0;
      C[r1] = v1;
      C16[r0] = f2bf(v0);
      C16[r1] = f2bf(v1);
    }
  }
}

// ---------------- MFMA hypernet q v9: half-split, h in LDS, ct-pair LDS dbuf ------------
// Grid 512: half = bid>>8 covers h cols [half*64,+64), W chunks [half*128,+128).
// 4 waves x 64 rows. h block (64 rows x 64 cols, bf16, stride 72) staged in LDS once
// per wave -> per-t2 hc reads are conflict-free LDS broadcasts (no VMEM in loop).
__global__ __launch_bounds__(256, 2) void hyper_q_v9_kernel(
    const short* __restrict__ GS16, const float* __restrict__ Hh,
    const short* __restrict__ Wp, const float* __restrict__ hwb,
    float* __restrict__ Qpart) {
  __shared__ short Bh[2][8192];        // 32 KB: two ct-pair buffers
  __shared__ short h_lds[4][64][72];   // 36.9 KB, stride 72 (16B-aligned rows)
  const int tid = threadIdx.x;
  const int wave = tid >> 6, lane = tid & 63;
  const int cl = lane & 15, kg = lane >> 4;
  const int half = blockIdx.x >> 8;
  const int wrow = (blockIdx.x & 255) * 256 + wave * 64;
  const int ct_base = half * 128;

  // ---- stage h block: lane owns row `lane`, 64 cols of this half -> bf16 LDS ----
  {
    const float* hp = Hh + (size_t)(wrow + lane) * 128 + half * 64;
#pragma unroll
    for (int c = 0; c < 64; c += 8) {
      float4 u0 = *(const float4*)(hp + c);
      float4 u1 = *(const float4*)(hp + c + 4);
      short8_t v;
      v[0] = f2bf(u0.x); v[1] = f2bf(u0.y); v[2] = f2bf(u0.z); v[3] = f2bf(u0.w);
      v[4] = f2bf(u1.x); v[5] = f2bf(u1.y); v[6] = f2bf(u1.z); v[7] = f2bf(u1.w);
      *(short8_t*)&h_lds[wave][lane][c] = v;
    }
  }

  // ---- A (gs bf16) -> registers: 4 m-frags x 8 kk ----
  short8_t ah[4][8];
#pragma unroll
  for (int m = 0; m < 4; ++m) {
    const short* ap = GS16 + (size_t)(wrow + m * 16 + cl) * 256;
#pragma unroll
    for (int kk = 0; kk < 8; ++kk) ah[m][kk] = *(const short8_t*)(ap + kk * 32 + kg * 8);
  }

  // ---- prologue: stage ct pair {base, base+1} into buf 0 ----
  {
    const short* wp0 = Wp + (size_t)ct_base * 4096;
#pragma unroll
    for (int k = 0; k < 4; ++k)
      *(short8_t*)&Bh[0][k * 2048 + tid * 8] = *(const short8_t*)(wp0 + k * 2048 + tid * 8);
  }
  __syncthreads();

  float qf[4][2][4] = {};
  int cur = 0;

#define COMPUTE_CT(BUFP, OH, WB)                                               \
  {                                                                            \
    f32x4_t acc[4];                                                            \
    _Pragma("unroll")                                                          \
    for (int m = 0; m < 4; ++m) acc[m] = (f32x4_t){0.f, 0.f, 0.f, 0.f};        \
    _Pragma("unroll")                                                          \
    for (int kk = 0; kk < 8; ++kk) {                                           \
      short8_t b_h = *(const short8_t*)((BUFP) + ((OH) * 4096 + (kk * 64 + lane) * 8)); \
      _Pragma("unroll")                                                        \
      for (int m = 0; m < 4; ++m) MFMA(acc[m], ah[m][kk], b_h);                \
    }                                                                          \
    _Pragma("unroll")                                                          \
    for (int m = 0; m < 4; ++m)                                                \
      _Pragma("unroll")                                                        \
      for (int j = 0; j < 4; ++j)                                              \
        qf[m][OH][j] = fmaf(hc[m * 4 + j], acc[m][j] + (WB), qf[m][OH][j]);    \
  }

  for (int t2 = 0; t2 < 64; ++t2) {
    const int ct0 = ct_base + t2 * 2;
    // h column t2 from LDS: 16 broadcast reads (same addr within cl-group)
    float hc[16];
#pragma unroll
    for (int m = 0; m < 4; ++m)
#pragma unroll
      for (int j = 0; j < 4; ++j)
        hc[m * 4 + j] = bf2f(h_lds[wave][m * 16 + kg * 4 + j][t2]);
    float wb0 = hwb[ct0 * 16 + cl];
    float wb1 = hwb[(ct0 + 1) * 16 + cl];
    // prefetch next ct pair to registers
    short8_t s[4];
    if (t2 < 63) {
      const short* wpn = Wp + (size_t)(ct0 + 2) * 4096;
#pragma unroll
      for (int k = 0; k < 4; ++k) s[k] = *(const short8_t*)(wpn + k * 2048 + tid * 8);
    }
    const short* bufp = &Bh[cur][0];
    COMPUTE_CT(bufp, 0, wb0)
    COMPUTE_CT(bufp, 1, wb1)
    if (t2 < 63) {
      short* bufn = &Bh[cur ^ 1][0];
#pragma unroll
      for (int k = 0; k < 4; ++k) *(short8_t*)(bufn + k * 2048 + tid * 8) = s[k];
    }
    __syncthreads();
    cur ^= 1;
  }
#undef COMPUTE_CT

  // ---- half 0 adds fc2_b = gs @ hb_w via packed chunks 256/257 (direct L2) ----
  if (half == 0) {
#pragma unroll
    for (int oh = 0; oh < 2; ++oh) {
      f32x4_t bacc[4];
#pragma unroll
      for (int m = 0; m < 4; ++m) bacc[m] = (f32x4_t){0.f, 0.f, 0.f, 0.f};
#pragma unroll
      for (int kk = 0; kk < 8; ++kk) {
        short8_t b_h = *(const short8_t*)(Wp + (((size_t)(256 + oh) * 8 + kk) * 64 + lane) * 8);
#pragma unroll
        for (int m = 0; m < 4; ++m) MFMA(bacc[m], ah[m][kk], b_h);
      }
#pragma unroll
      for (int m = 0; m < 4; ++m)
#pragma unroll
        for (int j = 0; j < 4; ++j) qf[m][oh][j] += bacc[m][j];
    }
  }

  // ---- write partial q ----
  float* qp = Qpart + (size_t)half * 2097152;
#pragma unroll
  for (int m = 0; m < 4; ++m)
#pragma unroll
    for (int j = 0; j < 4; ++j) {
      const size_t r = (size_t)(wrow + m * 16 + kg * 4 + j) * 32;
      qp[r + cl] = qf[m][0][j];
      qp[r + 16 + cl] = qf[m][1][j];
    }
}

// ---------------- combine: q = qpart0 + qpart1 + hb_b ----------------
__global__ __launch_bounds__(256) void qcombine_kernel(
    const float* __restrict__ Qpart, const float* __restrict__ hbb,
    float* __restrict__ Qout) {
  int i = blockIdx.x * 256 + threadIdx.x;  // 524288 float4s
  float4 a = ((const float4*)Qpart)[i];
  float4 b = ((const float4*)(Qpart + 2097152))[i];
  float4 e = ((const float4*)hbb)[i & 7];
  ((float4*)Qout)[i] = make_float4(a.x + b.x + e.x, a.y + b.y + e.y,
                                   a.z + b.z + e.z, a.w + b.w + e.w);
}

extern "C" void kernel_launch(void* const* d_in, const int* in_sizes, int n_in,
                              void* d_out, int out_size, void* d_ws, size_t ws_size,
                              hipStream_t stream) {
  const float* inputs   = (const float*)d_in[0];
  const float* hidden   = (const float*)d_in[1];
  const float* fc1_w    = (const float*)d_in[2];
  const float* fc1_b    = (const float*)d_in[3];
  const float* gru_wi   = (const float*)d_in[4];
  const float* gru_wh   = (const float*)d_in[5];
  const float* gru_bi   = (const float*)d_in[6];
  const float* gru_bh   = (const float*)d_in[7];
  const float* attn_q_w = (const float*)d_in[8];
  const float* attn_k_w = (const float*)d_in[9];
  const float* se1_w    = (const float*)d_in[10];
  const float* se1_b    = (const float*)d_in[11];
  const float* se2_w    = (const float*)d_in[12];
  const float* se2_b    = (const float*)d_in[13];
  const float* ga_w     = (const float*)d_in[14];
  const float* ga_b     = (const float*)d_in[15];
  const float* gemb     = (const float*)d_in[16];
  const float* gd1_w    = (const float*)d_in[17];
  const float* gd1_b    = (const float*)d_in[18];
  const float* gd2_w    = (const float*)d_in[19];
  const float* gd2_b    = (const float*)d_in[20];
  const float* hb_w     = (const float*)d_in[21];
  const float* hb_b     = (const float*)d_in[22];
  const float* hw_w     = (const float*)d_in[23];
  const float* hw_b     = (const float*)d_in[24];

  float* out = (float*)d_out;
  float* q_out     = out;              // [R,32]
  float* h_out     = out + 2097152;    // [R,128]
  float* gs_out    = out + 10485760;   // [R,256]
  float* probs_out = out + 27262976;   // [R,3]
  float* attn_out  = out + 27459584;   // [B,32,32]

  // workspace layout (bytes), all regions disjoint:
  //   [0,16M):   qpart f32 [2][R,32]
  //   [16M,24M): si bf16 [R,64]
  //   [24M,56M): sf16 bf16 [R,256]
  //   [56M,88M): gs16 bf16 [R,256]
  //   [88M,+2.9M): packs
  char* wsb = (char*)d_ws;
  float* qpart = (float*)wsb;
  short* si   = (short*)(wsb + (size_t)16 * 1024 * 1024);
  short* sf16 = (short*)(wsb + (size_t)24 * 1024 * 1024);
  short* gs16 = (short*)(wsb + (size_t)56 * 1024 * 1024);
  short* P    = (short*)(wsb + (size_t)88 * 1024 * 1024);

  // pack offsets (shorts); chunk = KK*512 shorts
  const size_t o_hw  = 0;        // K=256 KK=8, N=4096 (+hb chunks 256..257)
  const size_t o_hb  = 1048576;
  const size_t o_fc1 = 1056768;
  const size_t o_wi  = 1077248;
  const size_t o_wh  = 1126400;
  const size_t o_qkq = 1175552;
  const size_t o_qkk = 1191936;  // must be o_qkq + 16384 (attn assumes contiguity)
  const size_t o_se1 = 1208320;
  const size_t o_se2 = 1224704;
  const size_t o_gd1 = 1290240;
  const size_t o_gd2 = 1355776;

  PackArgs pa;
  pa.s[0]  = {hw_w,     256, 4096, 8, 0,    4096, o_hw};
  pa.s[1]  = {hb_w,     256, 32,   8, 4096, 32,   o_hb};
  pa.s[2]  = {fc1_w,    160, 128,  5, 4128, 80,   o_fc1};
  pa.s[3]  = {gru_wi,   128, 384,  4, 4208, 192,  o_wi};
  pa.s[4]  = {gru_wh,   128, 384,  4, 4400, 192,  o_wh};
  pa.s[5]  = {attn_q_w, 128, 128,  4, 4592, 64,   o_qkq};
  pa.s[6]  = {attn_k_w, 128, 128,  4, 4656, 64,   o_qkk};
  pa.s[7]  = {se1_w,    34,  256,  2, 4720, 64,   o_se1};
  pa.s[8]  = {se2_w,    256, 256,  8, 4784, 256,  o_se2};
  pa.s[9]  = {gd1_w,    256, 256,  8, 5040, 256,  o_gd1};
  pa.s[10] = {gd2_w,    256, 256,  8, 5296, 256,  o_gd2};

  dim3 blk(256);
  // 0) pack ALL weights in one launch
  pack_all_kernel<<<5552, blk, 0, stream>>>(pa, P);
  // 1) h = GRUCell(relu(inputs@fc1+b), hidden) -> h_out f32  (fc1 fused)
  gru_fused_kernel<<<512, blk, 0, stream>>>(inputs, hidden, P + o_fc1, fc1_b,
                                            P + o_wi, P + o_wh, gru_bi, gru_bh, h_out);
  // 2) attention v2 (MFMA proj + MFMA scores + parallel softmax) -> attn_out f32 + si bf16
  attn_fused_kernel<<<2048, blk, 0, stream>>>(h_out, P + o_qkq, attn_out, si);
  // 3) struct_feat = tanh(relu(si@se1+b1)@se2+b2) -> sf16 bf16 only
  fused2_kernel<2, 2><<<512, blk, 0, stream>>>(si, 64, P + o_se1, se1_b, P + o_se2, se2_b,
                                               nullptr, sf16);
  // 4) group assign + group_state -> probs + gs_out f32 + gs16
  fused_gd_group_kernel<<<512, blk, 0, stream>>>(sf16, ga_w, ga_b, gemb, probs_out,
                                                 P + o_gd1, gd1_b, P + o_gd2, gd2_b,
                                                 gs_out, gs16);
  // 5) q partials: half-split, h-in-LDS, ct-pair-dbuf MFMA hypernet
  hyper_q_v9_kernel<<<dim3(512), blk, 0, stream>>>(gs16, h_out, P + o_hw, hw_b, qpart);
  // 6) q = qpart0 + qpart1 + hb_b
  qcombine_kernel<<<2048, blk, 0, stream>>>(qpart, hb_b, q_out);
}

// Round 13
// 339.706 us; speedup vs baseline: 1.9620x; 1.0513x over previous
//
#include <hip/hip_runtime.h>
#include <math.h>

// B=2048, A=32 -> R=65536 rows. E_IN=160, H=128, HE=256, NACT=32, G=3, TAU=1.
#define R_TOTAL 65536

typedef __attribute__((ext_vector_type(8))) short short8_t;
typedef __attribute__((ext_vector_type(4))) short short4_t;
typedef __attribute__((ext_vector_type(4))) float f32x4_t;

__device__ __forceinline__ float sigmoidf_(float x) { return 1.f / (1.f + expf(-x)); }

__device__ __forceinline__ short f2bf(float x) {
  unsigned u = __float_as_uint(x);
  u += 0x7fff + ((u >> 16) & 1);   // round-to-nearest-even
  return (short)(u >> 16);
}
__device__ __forceinline__ float bf2f(short s) {
  return __uint_as_float(((unsigned)(unsigned short)s) << 16);
}

// Load 8 consecutive floats -> bf16 fragment (RNE).
__device__ __forceinline__ void load_afrag(const float* p, short8_t& h) {
  float4 u0 = *(const float4*)p;
  float4 u1 = *(const float4*)(p + 4);
  float v[8] = {u0.x, u0.y, u0.z, u0.w, u1.x, u1.y, u1.z, u1.w};
#pragma unroll
  for (int i = 0; i < 8; ++i) h[i] = f2bf(v[i]);
}

#define MFMA(ACC, A, B) ACC = __builtin_amdgcn_mfma_f32_16x16x32_bf16(A, B, ACC, 0, 0, 0)

// ---------------- fused fragment pack: all weights in one launch ----------------
struct PackSeg {
  const float* W;
  int Ksrc, N, KK, blk0, nblk;
  size_t off;
};
struct PackArgs { PackSeg s[11]; };

__global__ __launch_bounds__(256) void pack_all_kernel(PackArgs a, short* __restrict__ P) {
  const int b = blockIdx.x;
  PackSeg seg = a.s[0];
#pragma unroll
  for (int i = 1; i < 11; ++i)
    if (b >= a.s[i].blk0) seg = a.s[i];
  int p = (b - seg.blk0) * 256 + threadIdx.x;
  int i = p & 7, lane = (p >> 3) & 63, kk = (p >> 9) % seg.KK, ct = p / (seg.KK * 512);
  int e = kk * 32 + (lane >> 4) * 8 + i;
  int c = ct * 16 + (lane & 15);
  float w = (e < seg.Ksrc) ? seg.W[(size_t)e * seg.N + c] : 0.f;
  P[seg.off + p] = f2bf(w);
}

// ---------------- fused fc1 + GRU: h = GRUCell(relu(inputs@fc1+b), h_in) ----------------
__global__ __launch_bounds__(256) void gru_fused_kernel(
    const float* __restrict__ inputs, const float* __restrict__ Hin,
    const short* __restrict__ Fc1p, const float* __restrict__ fc1b,
    const short* __restrict__ WiP, const short* __restrict__ WhP,
    const float* __restrict__ gbi, const float* __restrict__ gbh,
    float* __restrict__ Hout) {
  __shared__ short mid[128 * 128];   // 32 KB, 256B rows, XOR-swizzled
  const int tid = threadIdx.x;
  const int wave = tid >> 6, lane = tid & 63;
  const int cl = lane & 15, kg = lane >> 4;
  const int row0g = blockIdx.x * 128 + wave * 32;
  const int row0l = wave * 32;

  // ---- stage 1: x = relu(inputs @ fc1 + b) ----
  {
    short8_t ah1[2][5];
#pragma unroll
    for (int m = 0; m < 2; ++m) {
      const float* ap = inputs + (size_t)(row0g + m * 16 + cl) * 160;
#pragma unroll
      for (int kk = 0; kk < 5; ++kk) load_afrag(ap + kk * 32 + kg * 8, ah1[m][kk]);
    }
    for (int ct = 0; ct < 8; ++ct) {
      f32x4_t a0 = (f32x4_t){0.f, 0.f, 0.f, 0.f};
      f32x4_t a1 = (f32x4_t){0.f, 0.f, 0.f, 0.f};
#pragma unroll
      for (int kk = 0; kk < 5; ++kk) {
        short8_t b_h = *(const short8_t*)(Fc1p + (((size_t)ct * 5 + kk) * 64 + lane) * 8);
        MFMA(a0, ah1[0][kk], b_h);
        MFMA(a1, ah1[1][kk], b_h);
      }
      int col = ct * 16 + cl;
      float bv = fc1b[col];
      int c2hi = (col * 2) & ~15, c2lo = (col * 2) & 15;
#pragma unroll
      for (int j = 0; j < 4; ++j) {
        float v0 = fmaxf(a0[j] + bv, 0.f);
        float v1 = fmaxf(a1[j] + bv, 0.f);
        int r0 = row0l + kg * 4 + j;
        int r1 = row0l + 16 + kg * 4 + j;
        int ad0 = ((r0 * 256 + c2hi) ^ ((r0 & 7) << 4)) + c2lo;
        int ad1 = ((r1 * 256 + c2hi) ^ ((r1 & 7) << 4)) + c2lo;
        *(short*)((char*)mid + ad0) = f2bf(v0);
        *(short*)((char*)mid + ad1) = f2bf(v1);
      }
    }
  }
  __syncthreads();

  // ---- stage 2: GRU ----
  short8_t xh[2][4], hh[2][4];
#pragma unroll
  for (int m = 0; m < 2; ++m) {
    int row = row0l + m * 16 + cl;
    const float* hp = Hin + (size_t)(row0g + m * 16 + cl) * 128;
#pragma unroll
    for (int kk = 0; kk < 4; ++kk) {
      int ad = (row * 256 + kk * 64 + kg * 16) ^ ((row & 7) << 4);
      xh[m][kk] = *(const short8_t*)((const char*)mid + ad);
      load_afrag(hp + kk * 32 + kg * 8, hh[m][kk]);
    }
  }
#define GLOAD(P, CT) *(const short8_t*)((P) + (((size_t)(CT) * 4 + kk) * 64 + lane) * 8)
  for (int ct = 0; ct < 8; ++ct) {
    f32x4_t aXr[2], aXz[2], aXn[2], aHr[2], aHz[2], aHn[2];
#pragma unroll
    for (int m = 0; m < 2; ++m) {
      aXr[m] = (f32x4_t){0.f, 0.f, 0.f, 0.f};
      aXz[m] = (f32x4_t){0.f, 0.f, 0.f, 0.f};
      aXn[m] = (f32x4_t){0.f, 0.f, 0.f, 0.f};
      aHr[m] = (f32x4_t){0.f, 0.f, 0.f, 0.f};
      aHz[m] = (f32x4_t){0.f, 0.f, 0.f, 0.f};
      aHn[m] = (f32x4_t){0.f, 0.f, 0.f, 0.f};
    }
#pragma unroll
    for (int kk = 0; kk < 4; ++kk) {
      short8_t b_h;
      b_h = GLOAD(WiP, ct);      MFMA(aXr[0], xh[0][kk], b_h); MFMA(aXr[1], xh[1][kk], b_h);
      b_h = GLOAD(WiP, ct + 8);  MFMA(aXz[0], xh[0][kk], b_h); MFMA(aXz[1], xh[1][kk], b_h);
      b_h = GLOAD(WiP, ct + 16); MFMA(aXn[0], xh[0][kk], b_h); MFMA(aXn[1], xh[1][kk], b_h);
      b_h = GLOAD(WhP, ct);      MFMA(aHr[0], hh[0][kk], b_h); MFMA(aHr[1], hh[1][kk], b_h);
      b_h = GLOAD(WhP, ct + 8);  MFMA(aHz[0], hh[0][kk], b_h); MFMA(aHz[1], hh[1][kk], b_h);
      b_h = GLOAD(WhP, ct + 16); MFMA(aHn[0], hh[0][kk], b_h); MFMA(aHn[1], hh[1][kk], b_h);
    }
    int col = ct * 16 + cl;
    float bir = gbi[col], biz = gbi[128 + col], bin = gbi[256 + col];
    float bhr = gbh[col], bhz = gbh[128 + col], bhn = gbh[256 + col];
#pragma unroll
    for (int m = 0; m < 2; ++m)
#pragma unroll
      for (int j = 0; j < 4; ++j) {
        int row = row0g + m * 16 + kg * 4 + j;
        float rg = sigmoidf_(aXr[m][j] + aHr[m][j] + bir + bhr);
        float zg = sigmoidf_(aXz[m][j] + aHz[m][j] + biz + bhz);
        float ng = tanhf(aXn[m][j] + bin + rg * (aHn[m][j] + bhn));
        float hv = Hin[(size_t)row * 128 + col];
        Hout[(size_t)row * 128 + col] = (1.f - zg) * ng + zg * hv;
      }
  }
#undef GLOAD
}

// ---------------- megakernel: attention + struct_encoder + group + group_decoder ----------
// Per 128-row block: 4x attention (si -> LDS), se1/se2 (sf -> LDS), group assign,
// gd1/gd2 -> gs_out f32 + gs16 bf16. si and sf never touch HBM.
__global__ __launch_bounds__(256, 2) void attn_se_gd_kernel(
    const float* __restrict__ Hh, const short* __restrict__ QKp,
    float* __restrict__ attn_out,
    const short* __restrict__ Se1p, const float* __restrict__ se1b,
    const short* __restrict__ Se2p, const float* __restrict__ se2b,
    const float* __restrict__ ga_w, const float* __restrict__ ga_b,
    const float* __restrict__ gemb, float* __restrict__ probs,
    const short* __restrict__ Gd1p, const float* __restrict__ gd1b,
    const short* __restrict__ Gd2p, const float* __restrict__ gd2b,
    float* __restrict__ gs_out, short* __restrict__ gs16) {
  __shared__ char smem[16384 + 65536];   // si_lds 16KB | R 64KB
  short* si_lds = (short*)smem;          // [128][64] bf16
  char* Rg = smem + 16384;
  short* mid = (short*)Rg;               // [128 rows][512B] swizzled (64KB), multi-use
  const int tid = threadIdx.x;
  const int wave = tid >> 6, lane = tid & 63;
  const int cl = lane & 15, kg = lane >> 4;
  const int row0g = blockIdx.x * 128;
  const int row0l = wave * 32;

  // ===== Stage A: attention for 4 sub-batches =====
  {
    short* qkb0 = (short*)Rg;                      // 8KB
    short* qkb1 = (short*)(Rg + 8192);             // 8KB
    float(*p)[33] = (float(*)[33])(Rg + 16384);    // 4224B
    for (int bb = 0; bb < 4; ++bb) {
      const int b = blockIdx.x * 4 + bb;
      // ---- proj: q/k = h @ Wq/Wk -> bf16 swizzled LDS ----
      {
        short8_t ahf[2][4];
#pragma unroll
        for (int m = 0; m < 2; ++m) {
          const float* ap = Hh + (size_t)(b * 32 + m * 16 + cl) * 128;
#pragma unroll
          for (int kk = 0; kk < 4; ++kk) load_afrag(ap + kk * 32 + kg * 8, ahf[m][kk]);
        }
        const int proj = wave >> 1;
        const short* Wbase = QKp + (size_t)proj * 16384;
        short* dst = proj ? qkb1 : qkb0;
#pragma unroll
        for (int ct4 = 0; ct4 < 4; ++ct4) {
          int ct = (wave & 1) * 4 + ct4;
          f32x4_t a0 = (f32x4_t){0.f, 0.f, 0.f, 0.f};
          f32x4_t a1 = (f32x4_t){0.f, 0.f, 0.f, 0.f};
#pragma unroll
          for (int kk = 0; kk < 4; ++kk) {
            short8_t b_h = *(const short8_t*)(Wbase + (((size_t)ct * 4 + kk) * 64 + lane) * 8);
            MFMA(a0, ahf[0][kk], b_h);
            MFMA(a1, ahf[1][kk], b_h);
          }
          int col = ct * 16 + cl;
          int c2hi = (col * 2) & ~15, c2lo = (col * 2) & 15;
#pragma unroll
          for (int j = 0; j < 4; ++j) {
            int r0 = kg * 4 + j;
            int r1 = 16 + kg * 4 + j;
            int ad0 = ((r0 * 256 + c2hi) ^ ((r0 & 7) << 4)) + c2lo;
            int ad1 = ((r1 * 256 + c2hi) ^ ((r1 & 7) << 4)) + c2lo;
            *(short*)((char*)dst + ad0) = f2bf(a0[j]);
            *(short*)((char*)dst + ad1) = f2bf(a1[j]);
          }
        }
      }
      __syncthreads();
      // ---- scores via MFMA: wave computes tile (mi, nj) ----
      {
        const int mi = wave >> 1, nj = wave & 1;
        short8_t qf[4], kf[4];
        int rq = mi * 16 + cl, rk = nj * 16 + cl;
#pragma unroll
        for (int kk = 0; kk < 4; ++kk) {
          int adq = (rq * 256 + kk * 64 + kg * 16) ^ ((rq & 7) << 4);
          int adk = (rk * 256 + kk * 64 + kg * 16) ^ ((rk & 7) << 4);
          qf[kk] = *(const short8_t*)((const char*)qkb0 + adq);
          kf[kk] = *(const short8_t*)((const char*)qkb1 + adk);
        }
        f32x4_t acc = (f32x4_t){0.f, 0.f, 0.f, 0.f};
#pragma unroll
        for (int kk = 0; kk < 4; ++kk) MFMA(acc, qf[kk], kf[kk]);
        const float scale = 0.088388347648318447f;  // 1/sqrt(128)
#pragma unroll
        for (int j = 0; j < 4; ++j) {
          int r = mi * 16 + kg * 4 + j;
          int c = nj * 16 + cl;
          p[r][c] = (r == c) ? -1e9f : acc[j] * scale;
        }
      }
      __syncthreads();
      // ---- softmax: 8 threads per row ----
      {
        int row = tid >> 3, g = tid & 7;
        float v[4];
        float mx = -1e30f;
#pragma unroll
        for (int c0 = 0; c0 < 4; ++c0) {
          v[c0] = p[row][g * 4 + c0];
          mx = fmaxf(mx, v[c0]);
        }
#pragma unroll
        for (int off = 1; off < 8; off <<= 1) mx = fmaxf(mx, __shfl_xor(mx, off, 64));
        float s = 0.f;
#pragma unroll
        for (int c0 = 0; c0 < 4; ++c0) {
          v[c0] = expf(v[c0] - mx);
          s += v[c0];
        }
#pragma unroll
        for (int off = 1; off < 8; off <<= 1) s += __shfl_xor(s, off, 64);
        float inv = 1.f / s;
#pragma unroll
        for (int c0 = 0; c0 < 4; ++c0) p[row][g * 4 + c0] = v[c0] * inv;
      }
      __syncthreads();
      // ---- symmetrize + attn_out + struct input + si_lds (a2 folded away) ----
      {
        int row = tid >> 3, g = tid & 7;
        float vv[4];
        float d = 0.f, en = 0.f;
#pragma unroll
        for (int c0 = 0; c0 < 4; ++c0) {
          int c = g * 4 + c0;
          float v = (row == c) ? 0.f : 0.5f * (p[row][c] + p[c][row]);
          vv[c0] = v;
          d += v;
          float cc = fmaxf(v, 1e-8f);
          en -= cc * logf(cc);
          attn_out[(size_t)b * 1024 + row * 32 + c] = v;
        }
#pragma unroll
        for (int off = 1; off < 8; off <<= 1) {
          d += __shfl_xor(d, off, 64);
          en += __shfl_xor(en, off, 64);
        }
        short* srow = si_lds + ((size_t)(bb * 32 + row)) * 64;
#pragma unroll
        for (int c0 = 0; c0 < 4; ++c0) srow[g * 4 + c0] = f2bf(vv[c0]);
        if (g == 0) {
          srow[32] = f2bf(d);
          srow[33] = f2bf(en);
        }
        for (int z = 34 + g; z < 64; z += 8) srow[z] = 0;
      }
      __syncthreads();
    }
  }

  // ===== Stage B: se1 -> mid =====
  {
    short8_t ah1[2][2];
#pragma unroll
    for (int m = 0; m < 2; ++m) {
      const short* ap = si_lds + (size_t)(row0l + m * 16 + cl) * 64;
#pragma unroll
      for (int kk = 0; kk < 2; ++kk)
        ah1[m][kk] = *(const short8_t*)(ap + kk * 32 + kg * 8);
    }
    for (int ct = 0; ct < 16; ++ct) {
      f32x4_t a0 = (f32x4_t){0.f, 0.f, 0.f, 0.f};
      f32x4_t a1 = (f32x4_t){0.f, 0.f, 0.f, 0.f};
#pragma unroll
      for (int kk = 0; kk < 2; ++kk) {
        short8_t b_h = *(const short8_t*)(Se1p + (((size_t)ct * 2 + kk) * 64 + lane) * 8);
        MFMA(a0, ah1[0][kk], b_h);
        MFMA(a1, ah1[1][kk], b_h);
      }
      int col = ct * 16 + cl;
      float bv = se1b[col];
      int c2hi = (col * 2) & ~15, c2lo = (col * 2) & 15;
#pragma unroll
      for (int j = 0; j < 4; ++j) {
        float v0 = fmaxf(a0[j] + bv, 0.f);
        float v1 = fmaxf(a1[j] + bv, 0.f);
        int r0 = row0l + kg * 4 + j;
        int r1 = row0l + 16 + kg * 4 + j;
        int ad0 = ((r0 * 512 + c2hi) ^ ((r0 & 7) << 4)) + c2lo;
        int ad1 = ((r1 * 512 + c2hi) ^ ((r1 & 7) << 4)) + c2lo;
        *(short*)((char*)mid + ad0) = f2bf(v0);
        *(short*)((char*)mid + ad1) = f2bf(v1);
      }
    }
  }
  __syncthreads();

  // ===== Stage C: se2 -> sf (written back into mid region) =====
  {
    short8_t ah2[2][8];
#pragma unroll
    for (int m = 0; m < 2; ++m) {
      int row = row0l + m * 16 + cl;
#pragma unroll
      for (int kk = 0; kk < 8; ++kk) {
        int ad = (row * 512 + kk * 64 + kg * 16) ^ ((row & 7) << 4);
        ah2[m][kk] = *(const short8_t*)((const char*)mid + ad);
      }
    }
    __syncthreads();  // all mid reads done; region reusable as sf
    for (int ct = 0; ct < 16; ++ct) {
      f32x4_t a0 = (f32x4_t){0.f, 0.f, 0.f, 0.f};
      f32x4_t a1 = (f32x4_t){0.f, 0.f, 0.f, 0.f};
#pragma unroll
      for (int kk = 0; kk < 8; ++kk) {
        short8_t b_h = *(const short8_t*)(Se2p + (((size_t)ct * 8 + kk) * 64 + lane) * 8);
        MFMA(a0, ah2[0][kk], b_h);
        MFMA(a1, ah2[1][kk], b_h);
      }
      int col = ct * 16 + cl;
      float bv = se2b[col];
      int c2hi = (col * 2) & ~15, c2lo = (col * 2) & 15;
#pragma unroll
      for (int j = 0; j < 4; ++j) {
        float v0 = tanhf(a0[j] + bv);
        float v1 = tanhf(a1[j] + bv);
        int r0 = row0l + kg * 4 + j;
        int r1 = row0l + 16 + kg * 4 + j;
        int ad0 = ((r0 * 512 + c2hi) ^ ((r0 & 7) << 4)) + c2lo;
        int ad1 = ((r1 * 512 + c2hi) ^ ((r1 & 7) << 4)) + c2lo;
        *(short*)((char*)mid + ad0) = f2bf(v0);
        *(short*)((char*)mid + ad1) = f2bf(v1);
      }
    }
  }
  __syncthreads();

  // ===== Stage D: group assign (sf from LDS) -> probs + t frags =====
  short8_t tfr[2][8];
  {
    short8_t sfr[2][8];
    float lg[2][3] = {};
#pragma unroll
    for (int m = 0; m < 2; ++m) {
      int row = row0l + m * 16 + cl;
#pragma unroll
      for (int kk = 0; kk < 8; ++kk) {
        int ad = (row * 512 + kk * 64 + kg * 16) ^ ((row & 7) << 4);
        short8_t s = *(const short8_t*)((const char*)mid + ad);
        sfr[m][kk] = s;
        int e0 = kk * 32 + kg * 8;
#pragma unroll
        for (int i = 0; i < 8; ++i) {
          float v = bf2f(s[i]);
          lg[m][0] = fmaf(v, ga_w[(e0 + i) * 3 + 0], lg[m][0]);
          lg[m][1] = fmaf(v, ga_w[(e0 + i) * 3 + 1], lg[m][1]);
          lg[m][2] = fmaf(v, ga_w[(e0 + i) * 3 + 2], lg[m][2]);
        }
      }
    }
#pragma unroll
    for (int m = 0; m < 2; ++m)
#pragma unroll
      for (int g = 0; g < 3; ++g) {
        lg[m][g] += __shfl_xor(lg[m][g], 16, 64);
        lg[m][g] += __shfl_xor(lg[m][g], 32, 64);
      }
#pragma unroll
    for (int m = 0; m < 2; ++m) {
      float l0 = lg[m][0] + ga_b[0], l1 = lg[m][1] + ga_b[1], l2 = lg[m][2] + ga_b[2];
      float mx = fmaxf(l0, fmaxf(l1, l2));
      float e0 = expf(l0 - mx), e1 = expf(l1 - mx), e2 = expf(l2 - mx);
      float inv = 1.f / (e0 + e1 + e2);
      float p0 = e0 * inv, p1 = e1 * inv, p2 = e2 * inv;
      if (kg == 0) {
        size_t r = (size_t)(row0g + row0l + m * 16 + cl) * 3;
        probs[r + 0] = p0;
        probs[r + 1] = p1;
        probs[r + 2] = p2;
      }
#pragma unroll
      for (int kk = 0; kk < 8; ++kk) {
        int e0i = kk * 32 + kg * 8;
        short8_t tf;
#pragma unroll
        for (int i = 0; i < 8; ++i) {
          float tv = bf2f(sfr[m][kk][i]) + p0 * gemb[e0i + i] +
                     p1 * gemb[256 + e0i + i] + p2 * gemb[512 + e0i + i];
          tf[i] = f2bf(tv);
        }
        tfr[m][kk] = tf;
      }
    }
  }
  __syncthreads();  // all sf reads done; mid region reusable

  // ===== Stage E: gd1 -> mid, gd2 -> gs_out f32 + gs16 bf16 =====
  for (int ct = 0; ct < 16; ++ct) {
    f32x4_t a0 = (f32x4_t){0.f, 0.f, 0.f, 0.f};
    f32x4_t a1 = (f32x4_t){0.f, 0.f, 0.f, 0.f};
#pragma unroll
    for (int kk = 0; kk < 8; ++kk) {
      short8_t b_h = *(const short8_t*)(Gd1p + (((size_t)ct * 8 + kk) * 64 + lane) * 8);
      MFMA(a0, tfr[0][kk], b_h);
      MFMA(a1, tfr[1][kk], b_h);
    }
    int col = ct * 16 + cl;
    float bv = gd1b[col];
    int c2hi = (col * 2) & ~15, c2lo = (col * 2) & 15;
#pragma unroll
    for (int j = 0; j < 4; ++j) {
      float v0 = fmaxf(a0[j] + bv, 0.f);
      float v1 = fmaxf(a1[j] + bv, 0.f);
      int r0 = row0l + kg * 4 + j;
      int r1 = row0l + 16 + kg * 4 + j;
      int ad0 = ((r0 * 512 + c2hi) ^ ((r0 & 7) << 4)) + c2lo;
      int ad1 = ((r1 * 512 + c2hi) ^ ((r1 & 7) << 4)) + c2lo;
      *(short*)((char*)mid + ad0) = f2bf(v0);
      *(short*)((char*)mid + ad1) = f2bf(v1);
    }
  }
  __syncthreads();
  {
    short8_t ah2[2][8];
#pragma unroll
    for (int m = 0; m < 2; ++m) {
      int row = row0l + m * 16 + cl;
#pragma unroll
      for (int kk = 0; kk < 8; ++kk) {
        int ad = (row * 512 + kk * 64 + kg * 16) ^ ((row & 7) << 4);
        ah2[m][kk] = *(const short8_t*)((const char*)mid + ad);
      }
    }
    for (int ct = 0; ct < 16; ++ct) {
      f32x4_t a0 = (f32x4_t){0.f, 0.f, 0.f, 0.f};
      f32x4_t a1 = (f32x4_t){0.f, 0.f, 0.f, 0.f};
#pragma unroll
      for (int kk = 0; kk < 8; ++kk) {
        short8_t b_h = *(const short8_t*)(Gd2p + (((size_t)ct * 8 + kk) * 64 + lane) * 8);
        MFMA(a0, ah2[0][kk], b_h);
        MFMA(a1, ah2[1][kk], b_h);
      }
      int col = ct * 16 + cl;
      float bv = gd2b[col];
#pragma unroll
      for (int j = 0; j < 4; ++j) {
        float v0 = tanhf(a0[j] + bv);
        float v1 = tanhf(a1[j] + bv);
        size_t r0 = (size_t)(row0g + row0l + kg * 4 + j) * 256 + col;
        size_t r1 = (size_t)(row0g + row0l + 16 + kg * 4 + j) * 256 + col;
        gs_out[r0] = v0;
        gs_out[r1] = v1;
        gs16[r0] = f2bf(v0);
        gs16[r1] = f2bf(v1);
      }
    }
  }
}

// ---------------- MFMA hypernet q v10: half-split, col-major h LDS, ct-pair dbuf --------
// Per-t2 hc reads: 4 broadcast ds_read_b64 (was 16 ds_read_u16).
__global__ __launch_bounds__(256, 2) void hyper_q_v10_kernel(
    const short* __restrict__ GS16, const float* __restrict__ Hh,
    const short* __restrict__ Wp, const float* __restrict__ hwb,
    float* __restrict__ Qpart) {
  __shared__ short Bh[2][8192];        // 32 KB: two ct-pair buffers
  __shared__ short h_lds[4][64][68];   // 34 KB, col-major: [wave][col][row], stride 68
  const int tid = threadIdx.x;
  const int wave = tid >> 6, lane = tid & 63;
  const int cl = lane & 15, kg = lane >> 4;
  const int half = blockIdx.x >> 8;
  const int wrow = (blockIdx.x & 255) * 256 + wave * 64;
  const int ct_base = half * 128;

  // ---- stage h block col-major: lane owns row `lane` ----
  {
    const float* hp = Hh + (size_t)(wrow + lane) * 128 + half * 64;
#pragma unroll
    for (int c = 0; c < 64; c += 4) {
      float4 u = *(const float4*)(hp + c);
      h_lds[wave][c + 0][lane] = f2bf(u.x);
      h_lds[wave][c + 1][lane] = f2bf(u.y);
      h_lds[wave][c + 2][lane] = f2bf(u.z);
      h_lds[wave][c + 3][lane] = f2bf(u.w);
    }
  }

  // ---- A (gs bf16) -> registers: 4 m-frags x 8 kk ----
  short8_t ah[4][8];
#pragma unroll
  for (int m = 0; m < 4; ++m) {
    const short* ap = GS16 + (size_t)(wrow + m * 16 + cl) * 256;
#pragma unroll
    for (int kk = 0; kk < 8; ++kk) ah[m][kk] = *(const short8_t*)(ap + kk * 32 + kg * 8);
  }

  // ---- prologue: stage ct pair {base, base+1} into buf 0 ----
  {
    const short* wp0 = Wp + (size_t)ct_base * 4096;
#pragma unroll
    for (int k = 0; k < 4; ++k)
      *(short8_t*)&Bh[0][k * 2048 + tid * 8] = *(const short8_t*)(wp0 + k * 2048 + tid * 8);
  }
  __syncthreads();

  float qf[4][2][4] = {};
  int cur = 0;

#define COMPUTE_CT(BUFP, OH, WB)                                               \
  {                                                                            \
    f32x4_t acc[4];                                                            \
    _Pragma("unroll")                                                          \
    for (int m = 0; m < 4; ++m) acc[m] = (f32x4_t){0.f, 0.f, 0.f, 0.f};        \
    _Pragma("unroll")                                                          \
    for (int kk = 0; kk < 8; ++kk) {                                           \
      short8_t b_h = *(const short8_t*)((BUFP) + ((OH) * 4096 + (kk * 64 + lane) * 8)); \
      _Pragma("unroll")                                                        \
      for (int m = 0; m < 4; ++m) MFMA(acc[m], ah[m][kk], b_h);                \
    }                                                                          \
    _Pragma("unroll")                                                          \
    for (int m = 0; m < 4; ++m)                                                \
      _Pragma("unroll")                                                        \
      for (int j = 0; j < 4; ++j)                                              \
        qf[m][OH][j] = fmaf(hc[m * 4 + j], acc[m][j] + (WB), qf[m][OH][j]);    \
  }

  for (int t2 = 0; t2 < 64; ++t2) {
    const int ct0 = ct_base + t2 * 2;
    // h column t2: 4 broadcast b64 reads (per m, 4 consecutive rows)
    float hc[16];
#pragma unroll
    for (int m = 0; m < 4; ++m) {
      short4_t v4 = *(const short4_t*)&h_lds[wave][t2][m * 16 + kg * 4];
#pragma unroll
      for (int j = 0; j < 4; ++j) hc[m * 4 + j] = bf2f(v4[j]);
    }
    float wb0 = hwb[ct0 * 16 + cl];
    float wb1 = hwb[(ct0 + 1) * 16 + cl];
    // prefetch next ct pair to registers
    short8_t s[4];
    if (t2 < 63) {
      const short* wpn = Wp + (size_t)(ct0 + 2) * 4096;
#pragma unroll
      for (int k = 0; k < 4; ++k) s[k] = *(const short8_t*)(wpn + k * 2048 + tid * 8);
    }
    const short* bufp = &Bh[cur][0];
    COMPUTE_CT(bufp, 0, wb0)
    COMPUTE_CT(bufp, 1, wb1)
    if (t2 < 63) {
      short* bufn = &Bh[cur ^ 1][0];
#pragma unroll
      for (int k = 0; k < 4; ++k) *(short8_t*)(bufn + k * 2048 + tid * 8) = s[k];
    }
    __syncthreads();
    cur ^= 1;
  }
#undef COMPUTE_CT

  // ---- half 0 adds fc2_b = gs @ hb_w via packed chunks 256/257 (direct L2) ----
  if (half == 0) {
#pragma unroll
    for (int oh = 0; oh < 2; ++oh) {
      f32x4_t bacc[4];
#pragma unroll
      for (int m = 0; m < 4; ++m) bacc[m] = (f32x4_t){0.f, 0.f, 0.f, 0.f};
#pragma unroll
      for (int kk = 0; kk < 8; ++kk) {
        short8_t b_h = *(const short8_t*)(Wp + (((size_t)(256 + oh) * 8 + kk) * 64 + lane) * 8);
#pragma unroll
        for (int m = 0; m < 4; ++m) MFMA(bacc[m], ah[m][kk], b_h);
      }
#pragma unroll
      for (int m = 0; m < 4; ++m)
#pragma unroll
        for (int j = 0; j < 4; ++j) qf[m][oh][j] += bacc[m][j];
    }
  }

  // ---- write partial q ----
  float* qp = Qpart + (size_t)half * 2097152;
#pragma unroll
  for (int m = 0; m < 4; ++m)
#pragma unroll
    for (int j = 0; j < 4; ++j) {
      const size_t r = (size_t)(wrow + m * 16 + kg * 4 + j) * 32;
      qp[r + cl] = qf[m][0][j];
      qp[r + 16 + cl] = qf[m][1][j];
    }
}

// ---------------- combine: q = qpart0 + qpart1 + hb_b ----------------
__global__ __launch_bounds__(256) void qcombine_kernel(
    const float* __restrict__ Qpart, const float* __restrict__ hbb,
    float* __restrict__ Qout) {
  int i = blockIdx.x * 256 + threadIdx.x;  // 524288 float4s
  float4 a = ((const float4*)Qpart)[i];
  float4 b = ((const float4*)(Qpart + 2097152))[i];
  float4 e = ((const float4*)hbb)[i & 7];
  ((float4*)Qout)[i] = make_float4(a.x + b.x + e.x, a.y + b.y + e.y,
                                   a.z + b.z + e.z, a.w + b.w + e.w);
}

extern "C" void kernel_launch(void* const* d_in, const int* in_sizes, int n_in,
                              void* d_out, int out_size, void* d_ws, size_t ws_size,
                              hipStream_t stream) {
  const float* inputs   = (const float*)d_in[0];
  const float* hidden   = (const float*)d_in[1];
  const float* fc1_w    = (const float*)d_in[2];
  const float* fc1_b    = (const float*)d_in[3];
  const float* gru_wi   = (const float*)d_in[4];
  const float* gru_wh   = (const float*)d_in[5];
  const float* gru_bi   = (const float*)d_in[6];
  const float* gru_bh   = (const float*)d_in[7];
  const float* attn_q_w = (const float*)d_in[8];
  const float* attn_k_w = (const float*)d_in[9];
  const float* se1_w    = (const float*)d_in[10];
  const float* se1_b    = (const float*)d_in[11];
  const float* se2_w    = (const float*)d_in[12];
  const float* se2_b    = (const float*)d_in[13];
  const float* ga_w     = (const float*)d_in[14];
  const float* ga_b     = (const float*)d_in[15];
  const float* gemb     = (const float*)d_in[16];
  const float* gd1_w    = (const float*)d_in[17];
  const float* gd1_b    = (const float*)d_in[18];
  const float* gd2_w    = (const float*)d_in[19];
  const float* gd2_b    = (const float*)d_in[20];
  const float* hb_w     = (const float*)d_in[21];
  const float* hb_b     = (const float*)d_in[22];
  const float* hw_w     = (const float*)d_in[23];
  const float* hw_b     = (const float*)d_in[24];

  float* out = (float*)d_out;
  float* q_out     = out;              // [R,32]
  float* h_out     = out + 2097152;    // [R,128]
  float* gs_out    = out + 10485760;   // [R,256]
  float* probs_out = out + 27262976;   // [R,3]
  float* attn_out  = out + 27459584;   // [B,32,32]

  // workspace layout (bytes), all regions disjoint:
  //   [0,16M):   qpart f32 [2][R,32]
  //   [16M,48M): gs16 bf16 [R,256]
  //   [48M,+2.9M): packs
  char* wsb = (char*)d_ws;
  float* qpart = (float*)wsb;
  short* gs16 = (short*)(wsb + (size_t)16 * 1024 * 1024);
  short* P    = (short*)(wsb + (size_t)48 * 1024 * 1024);

  // pack offsets (shorts); chunk = KK*512 shorts
  const size_t o_hw  = 0;        // K=256 KK=8, N=4096 (+hb chunks 256..257)
  const size_t o_hb  = 1048576;
  const size_t o_fc1 = 1056768;
  const size_t o_wi  = 1077248;
  const size_t o_wh  = 1126400;
  const size_t o_qkq = 1175552;
  const size_t o_qkk = 1191936;  // must be o_qkq + 16384 (attn assumes contiguity)
  const size_t o_se1 = 1208320;
  const size_t o_se2 = 1224704;
  const size_t o_gd1 = 1290240;
  const size_t o_gd2 = 1355776;

  PackArgs pa;
  pa.s[0]  = {hw_w,     256, 4096, 8, 0,    4096, o_hw};
  pa.s[1]  = {hb_w,     256, 32,   8, 4096, 32,   o_hb};
  pa.s[2]  = {fc1_w,    160, 128,  5, 4128, 80,   o_fc1};
  pa.s[3]  = {gru_wi,   128, 384,  4, 4208, 192,  o_wi};
  pa.s[4]  = {gru_wh,   128, 384,  4, 4400, 192,  o_wh};
  pa.s[5]  = {attn_q_w, 128, 128,  4, 4592, 64,   o_qkq};
  pa.s[6]  = {attn_k_w, 128, 128,  4, 4656, 64,   o_qkk};
  pa.s[7]  = {se1_w,    34,  256,  2, 4720, 64,   o_se1};
  pa.s[8]  = {se2_w,    256, 256,  8, 4784, 256,  o_se2};
  pa.s[9]  = {gd1_w,    256, 256,  8, 5040, 256,  o_gd1};
  pa.s[10] = {gd2_w,    256, 256,  8, 5296, 256,  o_gd2};

  dim3 blk(256);
  // 0) pack ALL weights in one launch
  pack_all_kernel<<<5552, blk, 0, stream>>>(pa, P);
  // 1) h = GRUCell(relu(inputs@fc1+b), hidden) -> h_out f32  (fc1 fused)
  gru_fused_kernel<<<512, blk, 0, stream>>>(inputs, hidden, P + o_fc1, fc1_b,
                                            P + o_wi, P + o_wh, gru_bi, gru_bh, h_out);
  // 2) megakernel: attention + struct_encoder + group + group_decoder
  attn_se_gd_kernel<<<512, blk, 0, stream>>>(h_out, P + o_qkq, attn_out,
                                             P + o_se1, se1_b, P + o_se2, se2_b,
                                             ga_w, ga_b, gemb, probs_out,
                                             P + o_gd1, gd1_b, P + o_gd2, gd2_b,
                                             gs_out, gs16);
  // 3) q partials: half-split, col-major h LDS, ct-pair-dbuf MFMA hypernet
  hyper_q_v10_kernel<<<dim3(512), blk, 0, stream>>>(gs16, h_out, P + o_hw, hw_b, qpart);
  // 4) q = qpart0 + qpart1 + hb_b
  qcombine_kernel<<<2048, blk, 0, stream>>>(qpart, hb_b, q_out);
}

// Round 14
// 332.988 us; speedup vs baseline: 2.0016x; 1.0202x over previous
//
#include <hip/hip_runtime.h>
#include <math.h>

// B=2048, A=32 -> R=65536 rows. E_IN=160, H=128, HE=256, NACT=32, G=3, TAU=1.
#define R_TOTAL 65536

typedef __attribute__((ext_vector_type(8))) short short8_t;
typedef __attribute__((ext_vector_type(4))) short short4_t;
typedef __attribute__((ext_vector_type(4))) float f32x4_t;

__device__ __forceinline__ float sigmoidf_(float x) { return 1.f / (1.f + expf(-x)); }

__device__ __forceinline__ short f2bf(float x) {
  unsigned u = __float_as_uint(x);
  u += 0x7fff + ((u >> 16) & 1);   // round-to-nearest-even
  return (short)(u >> 16);
}
__device__ __forceinline__ float bf2f(short s) {
  return __uint_as_float(((unsigned)(unsigned short)s) << 16);
}

// Load 8 consecutive floats -> bf16 fragment (RNE).
__device__ __forceinline__ void load_afrag(const float* p, short8_t& h) {
  float4 u0 = *(const float4*)p;
  float4 u1 = *(const float4*)(p + 4);
  float v[8] = {u0.x, u0.y, u0.z, u0.w, u1.x, u1.y, u1.z, u1.w};
#pragma unroll
  for (int i = 0; i < 8; ++i) h[i] = f2bf(v[i]);
}

#define MFMA(ACC, A, B) ACC = __builtin_amdgcn_mfma_f32_16x16x32_bf16(A, B, ACC, 0, 0, 0)

// ---------------- fused fragment pack: all weights in one launch ----------------
struct PackSeg {
  const float* W;
  int Ksrc, N, KK, blk0, nblk;
  size_t off;
};
struct PackArgs { PackSeg s[11]; };

__global__ __launch_bounds__(256) void pack_all_kernel(PackArgs a, short* __restrict__ P) {
  const int b = blockIdx.x;
  PackSeg seg = a.s[0];
#pragma unroll
  for (int i = 1; i < 11; ++i)
    if (b >= a.s[i].blk0) seg = a.s[i];
  int p = (b - seg.blk0) * 256 + threadIdx.x;
  int i = p & 7, lane = (p >> 3) & 63, kk = (p >> 9) % seg.KK, ct = p / (seg.KK * 512);
  int e = kk * 32 + (lane >> 4) * 8 + i;
  int c = ct * 16 + (lane & 15);
  float w = (e < seg.Ksrc) ? seg.W[(size_t)e * seg.N + c] : 0.f;
  P[seg.off + p] = f2bf(w);
}

// ---------------- fused fc1 + GRU: h = GRUCell(relu(inputs@fc1+b), h_in) ----------------
__global__ __launch_bounds__(256) void gru_fused_kernel(
    const float* __restrict__ inputs, const float* __restrict__ Hin,
    const short* __restrict__ Fc1p, const float* __restrict__ fc1b,
    const short* __restrict__ WiP, const short* __restrict__ WhP,
    const float* __restrict__ gbi, const float* __restrict__ gbh,
    float* __restrict__ Hout) {
  __shared__ short mid[128 * 128];   // 32 KB, 256B rows, XOR-swizzled
  const int tid = threadIdx.x;
  const int wave = tid >> 6, lane = tid & 63;
  const int cl = lane & 15, kg = lane >> 4;
  const int row0g = blockIdx.x * 128 + wave * 32;
  const int row0l = wave * 32;

  // ---- stage 1: x = relu(inputs @ fc1 + b) ----
  {
    short8_t ah1[2][5];
#pragma unroll
    for (int m = 0; m < 2; ++m) {
      const float* ap = inputs + (size_t)(row0g + m * 16 + cl) * 160;
#pragma unroll
      for (int kk = 0; kk < 5; ++kk) load_afrag(ap + kk * 32 + kg * 8, ah1[m][kk]);
    }
    for (int ct = 0; ct < 8; ++ct) {
      f32x4_t a0 = (f32x4_t){0.f, 0.f, 0.f, 0.f};
      f32x4_t a1 = (f32x4_t){0.f, 0.f, 0.f, 0.f};
#pragma unroll
      for (int kk = 0; kk < 5; ++kk) {
        short8_t b_h = *(const short8_t*)(Fc1p + (((size_t)ct * 5 + kk) * 64 + lane) * 8);
        MFMA(a0, ah1[0][kk], b_h);
        MFMA(a1, ah1[1][kk], b_h);
      }
      int col = ct * 16 + cl;
      float bv = fc1b[col];
      int c2hi = (col * 2) & ~15, c2lo = (col * 2) & 15;
#pragma unroll
      for (int j = 0; j < 4; ++j) {
        float v0 = fmaxf(a0[j] + bv, 0.f);
        float v1 = fmaxf(a1[j] + bv, 0.f);
        int r0 = row0l + kg * 4 + j;
        int r1 = row0l + 16 + kg * 4 + j;
        int ad0 = ((r0 * 256 + c2hi) ^ ((r0 & 7) << 4)) + c2lo;
        int ad1 = ((r1 * 256 + c2hi) ^ ((r1 & 7) << 4)) + c2lo;
        *(short*)((char*)mid + ad0) = f2bf(v0);
        *(short*)((char*)mid + ad1) = f2bf(v1);
      }
    }
  }
  __syncthreads();

  // ---- stage 2: GRU ----
  short8_t xh[2][4], hh[2][4];
#pragma unroll
  for (int m = 0; m < 2; ++m) {
    int row = row0l + m * 16 + cl;
    const float* hp = Hin + (size_t)(row0g + m * 16 + cl) * 128;
#pragma unroll
    for (int kk = 0; kk < 4; ++kk) {
      int ad = (row * 256 + kk * 64 + kg * 16) ^ ((row & 7) << 4);
      xh[m][kk] = *(const short8_t*)((const char*)mid + ad);
      load_afrag(hp + kk * 32 + kg * 8, hh[m][kk]);
    }
  }
#define GLOAD(P, CT) *(const short8_t*)((P) + (((size_t)(CT) * 4 + kk) * 64 + lane) * 8)
  for (int ct = 0; ct < 8; ++ct) {
    f32x4_t aXr[2], aXz[2], aXn[2], aHr[2], aHz[2], aHn[2];
#pragma unroll
    for (int m = 0; m < 2; ++m) {
      aXr[m] = (f32x4_t){0.f, 0.f, 0.f, 0.f};
      aXz[m] = (f32x4_t){0.f, 0.f, 0.f, 0.f};
      aXn[m] = (f32x4_t){0.f, 0.f, 0.f, 0.f};
      aHr[m] = (f32x4_t){0.f, 0.f, 0.f, 0.f};
      aHz[m] = (f32x4_t){0.f, 0.f, 0.f, 0.f};
      aHn[m] = (f32x4_t){0.f, 0.f, 0.f, 0.f};
    }
#pragma unroll
    for (int kk = 0; kk < 4; ++kk) {
      short8_t b_h;
      b_h = GLOAD(WiP, ct);      MFMA(aXr[0], xh[0][kk], b_h); MFMA(aXr[1], xh[1][kk], b_h);
      b_h = GLOAD(WiP, ct + 8);  MFMA(aXz[0], xh[0][kk], b_h); MFMA(aXz[1], xh[1][kk], b_h);
      b_h = GLOAD(WiP, ct + 16); MFMA(aXn[0], xh[0][kk], b_h); MFMA(aXn[1], xh[1][kk], b_h);
      b_h = GLOAD(WhP, ct);      MFMA(aHr[0], hh[0][kk], b_h); MFMA(aHr[1], hh[1][kk], b_h);
      b_h = GLOAD(WhP, ct + 8);  MFMA(aHz[0], hh[0][kk], b_h); MFMA(aHz[1], hh[1][kk], b_h);
      b_h = GLOAD(WhP, ct + 16); MFMA(aHn[0], hh[0][kk], b_h); MFMA(aHn[1], hh[1][kk], b_h);
    }
    int col = ct * 16 + cl;
    float bir = gbi[col], biz = gbi[128 + col], bin = gbi[256 + col];
    float bhr = gbh[col], bhz = gbh[128 + col], bhn = gbh[256 + col];
#pragma unroll
    for (int m = 0; m < 2; ++m)
#pragma unroll
      for (int j = 0; j < 4; ++j) {
        int row = row0g + m * 16 + kg * 4 + j;
        float rg = sigmoidf_(aXr[m][j] + aHr[m][j] + bir + bhr);
        float zg = sigmoidf_(aXz[m][j] + aHz[m][j] + biz + bhz);
        float ng = tanhf(aXn[m][j] + bin + rg * (aHn[m][j] + bhn));
        float hv = Hin[(size_t)row * 128 + col];
        Hout[(size_t)row * 128 + col] = (1.f - zg) * ng + zg * hv;
      }
  }
#undef GLOAD
}

// ---------------- fused attention: MFMA proj + MFMA scores + parallel softmax ------------
// One b per block (2048 blocks). Writes attn_out f32 + si bf16 [R,64] to HBM.
__global__ __launch_bounds__(256) void attn_fused_kernel(
    const float* __restrict__ Hh, const short* __restrict__ QKp,
    float* __restrict__ attn_out, short* __restrict__ si) {
  __shared__ short qkb[2][32 * 128];   // 2 x 8 KB, 256B rows, XOR-swizzled
  __shared__ float p[32][33];
  __shared__ float a2[32][33];
  const int b = blockIdx.x;
  const int tid = threadIdx.x;
  const int wave = tid >> 6, lane = tid & 63;
  const int cl = lane & 15, kg = lane >> 4;

  // ---- proj: q/k = h @ Wq/Wk -> bf16 LDS ----
  {
    short8_t ahf[2][4];
#pragma unroll
    for (int m = 0; m < 2; ++m) {
      const float* ap = Hh + (size_t)(b * 32 + m * 16 + cl) * 128;
#pragma unroll
      for (int kk = 0; kk < 4; ++kk) load_afrag(ap + kk * 32 + kg * 8, ahf[m][kk]);
    }
    const int proj = wave >> 1;
    const short* Wbase = QKp + (size_t)proj * 16384;
    short* dst = &qkb[proj][0];
#pragma unroll
    for (int ct4 = 0; ct4 < 4; ++ct4) {
      int ct = (wave & 1) * 4 + ct4;
      f32x4_t a0 = (f32x4_t){0.f, 0.f, 0.f, 0.f};
      f32x4_t a1 = (f32x4_t){0.f, 0.f, 0.f, 0.f};
#pragma unroll
      for (int kk = 0; kk < 4; ++kk) {
        short8_t b_h = *(const short8_t*)(Wbase + (((size_t)ct * 4 + kk) * 64 + lane) * 8);
        MFMA(a0, ahf[0][kk], b_h);
        MFMA(a1, ahf[1][kk], b_h);
      }
      int col = ct * 16 + cl;
      int c2hi = (col * 2) & ~15, c2lo = (col * 2) & 15;
#pragma unroll
      for (int j = 0; j < 4; ++j) {
        int r0 = kg * 4 + j;
        int r1 = 16 + kg * 4 + j;
        int ad0 = ((r0 * 256 + c2hi) ^ ((r0 & 7) << 4)) + c2lo;
        int ad1 = ((r1 * 256 + c2hi) ^ ((r1 & 7) << 4)) + c2lo;
        *(short*)((char*)dst + ad0) = f2bf(a0[j]);
        *(short*)((char*)dst + ad1) = f2bf(a1[j]);
      }
    }
  }
  __syncthreads();

  // ---- scores via MFMA: wave computes tile (mi, nj) ----
  {
    const int mi = wave >> 1, nj = wave & 1;
    short8_t qf[4], kf[4];
    int rq = mi * 16 + cl, rk = nj * 16 + cl;
#pragma unroll
    for (int kk = 0; kk < 4; ++kk) {
      int adq = (rq * 256 + kk * 64 + kg * 16) ^ ((rq & 7) << 4);
      int adk = (rk * 256 + kk * 64 + kg * 16) ^ ((rk & 7) << 4);
      qf[kk] = *(const short8_t*)((const char*)&qkb[0][0] + adq);
      kf[kk] = *(const short8_t*)((const char*)&qkb[1][0] + adk);
    }
    f32x4_t acc = (f32x4_t){0.f, 0.f, 0.f, 0.f};
#pragma unroll
    for (int kk = 0; kk < 4; ++kk) MFMA(acc, qf[kk], kf[kk]);
    const float scale = 0.088388347648318447f;  // 1/sqrt(128)
#pragma unroll
    for (int j = 0; j < 4; ++j) {
      int r = mi * 16 + kg * 4 + j;
      int c = nj * 16 + cl;
      p[r][c] = (r == c) ? -1e9f : acc[j] * scale;
    }
  }
  __syncthreads();

  // ---- softmax: 8 threads per row ----
  {
    int row = tid >> 3, g = tid & 7;
    float v[4];
    float mx = -1e30f;
#pragma unroll
    for (int c0 = 0; c0 < 4; ++c0) {
      v[c0] = p[row][g * 4 + c0];
      mx = fmaxf(mx, v[c0]);
    }
#pragma unroll
    for (int off = 1; off < 8; off <<= 1) mx = fmaxf(mx, __shfl_xor(mx, off, 64));
    float s = 0.f;
#pragma unroll
    for (int c0 = 0; c0 < 4; ++c0) {
      v[c0] = expf(v[c0] - mx);
      s += v[c0];
    }
#pragma unroll
    for (int off = 1; off < 8; off <<= 1) s += __shfl_xor(s, off, 64);
    float inv = 1.f / s;
#pragma unroll
    for (int c0 = 0; c0 < 4; ++c0) p[row][g * 4 + c0] = v[c0] * inv;
  }
  __syncthreads();

  // ---- symmetrize + attn_out ----
#pragma unroll
  for (int tI = 0; tI < 4; ++tI) {
    int t = tid + tI * 256;
    int i = t >> 5, j = t & 31;
    float v = (i == j) ? 0.f : 0.5f * (p[i][j] + p[j][i]);
    a2[i][j] = v;
    attn_out[(size_t)b * 1024 + t] = v;
  }
  __syncthreads();

  // ---- struct input: 8 threads per row ----
  {
    int row = tid >> 3, g = tid & 7;
    float vv[4];
    float d = 0.f, en = 0.f;
#pragma unroll
    for (int c0 = 0; c0 < 4; ++c0) {
      float v = a2[row][g * 4 + c0];
      vv[c0] = v;
      d += v;
      float c = fmaxf(v, 1e-8f);
      en -= c * logf(c);
    }
#pragma unroll
    for (int off = 1; off < 8; off <<= 1) {
      d += __shfl_xor(d, off, 64);
      en += __shfl_xor(en, off, 64);
    }
    short* srow = si + ((size_t)b * 32 + row) * 64;
#pragma unroll
    for (int c0 = 0; c0 < 4; ++c0) srow[g * 4 + c0] = f2bf(vv[c0]);
    if (g == 0) {
      srow[32] = f2bf(d);
      srow[33] = f2bf(en);
    }
    for (int z = 34 + g; z < 64; z += 8) srow[z] = 0;
  }
}

// ---------------- fused se1+se2+group+gd1+gd2: si(HBM) -> probs + gs_out + gs16 ----------
// sf and gd-mid live only in the 64KB swizzled LDS region (recycled across stages).
__global__ __launch_bounds__(256, 2) void se_gd_kernel(
    const short* __restrict__ SI,
    const short* __restrict__ Se1p, const float* __restrict__ se1b,
    const short* __restrict__ Se2p, const float* __restrict__ se2b,
    const float* __restrict__ ga_w, const float* __restrict__ ga_b,
    const float* __restrict__ gemb, float* __restrict__ probs,
    const short* __restrict__ Gd1p, const float* __restrict__ gd1b,
    const short* __restrict__ Gd2p, const float* __restrict__ gd2b,
    float* __restrict__ gs_out, short* __restrict__ gs16) {
  __shared__ short mid[128 * 256];   // 64 KB, 512B rows, XOR-swizzled
  const int tid = threadIdx.x;
  const int wave = tid >> 6, lane = tid & 63;
  const int cl = lane & 15, kg = lane >> 4;
  const int row0g = blockIdx.x * 128;
  const int row0l = wave * 32;

  // ===== Stage B: se1 -> mid =====
  {
    short8_t ah1[2][2];
#pragma unroll
    for (int m = 0; m < 2; ++m) {
      const short* ap = SI + (size_t)(row0g + row0l + m * 16 + cl) * 64;
#pragma unroll
      for (int kk = 0; kk < 2; ++kk)
        ah1[m][kk] = *(const short8_t*)(ap + kk * 32 + kg * 8);
    }
    for (int ct = 0; ct < 16; ++ct) {
      f32x4_t a0 = (f32x4_t){0.f, 0.f, 0.f, 0.f};
      f32x4_t a1 = (f32x4_t){0.f, 0.f, 0.f, 0.f};
#pragma unroll
      for (int kk = 0; kk < 2; ++kk) {
        short8_t b_h = *(const short8_t*)(Se1p + (((size_t)ct * 2 + kk) * 64 + lane) * 8);
        MFMA(a0, ah1[0][kk], b_h);
        MFMA(a1, ah1[1][kk], b_h);
      }
      int col = ct * 16 + cl;
      float bv = se1b[col];
      int c2hi = (col * 2) & ~15, c2lo = (col * 2) & 15;
#pragma unroll
      for (int j = 0; j < 4; ++j) {
        float v0 = fmaxf(a0[j] + bv, 0.f);
        float v1 = fmaxf(a1[j] + bv, 0.f);
        int r0 = row0l + kg * 4 + j;
        int r1 = row0l + 16 + kg * 4 + j;
        int ad0 = ((r0 * 512 + c2hi) ^ ((r0 & 7) << 4)) + c2lo;
        int ad1 = ((r1 * 512 + c2hi) ^ ((r1 & 7) << 4)) + c2lo;
        *(short*)((char*)mid + ad0) = f2bf(v0);
        *(short*)((char*)mid + ad1) = f2bf(v1);
      }
    }
  }
  __syncthreads();

  // ===== Stage C: se2 -> sf (written back into mid region) =====
  {
    short8_t ah2[2][8];
#pragma unroll
    for (int m = 0; m < 2; ++m) {
      int row = row0l + m * 16 + cl;
#pragma unroll
      for (int kk = 0; kk < 8; ++kk) {
        int ad = (row * 512 + kk * 64 + kg * 16) ^ ((row & 7) << 4);
        ah2[m][kk] = *(const short8_t*)((const char*)mid + ad);
      }
    }
    __syncthreads();  // all mid reads done; region reusable as sf
    for (int ct = 0; ct < 16; ++ct) {
      f32x4_t a0 = (f32x4_t){0.f, 0.f, 0.f, 0.f};
      f32x4_t a1 = (f32x4_t){0.f, 0.f, 0.f, 0.f};
#pragma unroll
      for (int kk = 0; kk < 8; ++kk) {
        short8_t b_h = *(const short8_t*)(Se2p + (((size_t)ct * 8 + kk) * 64 + lane) * 8);
        MFMA(a0, ah2[0][kk], b_h);
        MFMA(a1, ah2[1][kk], b_h);
      }
      int col = ct * 16 + cl;
      float bv = se2b[col];
      int c2hi = (col * 2) & ~15, c2lo = (col * 2) & 15;
#pragma unroll
      for (int j = 0; j < 4; ++j) {
        float v0 = tanhf(a0[j] + bv);
        float v1 = tanhf(a1[j] + bv);
        int r0 = row0l + kg * 4 + j;
        int r1 = row0l + 16 + kg * 4 + j;
        int ad0 = ((r0 * 512 + c2hi) ^ ((r0 & 7) << 4)) + c2lo;
        int ad1 = ((r1 * 512 + c2hi) ^ ((r1 & 7) << 4)) + c2lo;
        *(short*)((char*)mid + ad0) = f2bf(v0);
        *(short*)((char*)mid + ad1) = f2bf(v1);
      }
    }
  }
  __syncthreads();

  // ===== Stage D: group assign (sf from LDS) -> probs + t frags =====
  short8_t tfr[2][8];
  {
    short8_t sfr[2][8];
    float lg[2][3] = {};
#pragma unroll
    for (int m = 0; m < 2; ++m) {
      int row = row0l + m * 16 + cl;
#pragma unroll
      for (int kk = 0; kk < 8; ++kk) {
        int ad = (row * 512 + kk * 64 + kg * 16) ^ ((row & 7) << 4);
        short8_t s = *(const short8_t*)((const char*)mid + ad);
        sfr[m][kk] = s;
        int e0 = kk * 32 + kg * 8;
#pragma unroll
        for (int i = 0; i < 8; ++i) {
          float v = bf2f(s[i]);
          lg[m][0] = fmaf(v, ga_w[(e0 + i) * 3 + 0], lg[m][0]);
          lg[m][1] = fmaf(v, ga_w[(e0 + i) * 3 + 1], lg[m][1]);
          lg[m][2] = fmaf(v, ga_w[(e0 + i) * 3 + 2], lg[m][2]);
        }
      }
    }
#pragma unroll
    for (int m = 0; m < 2; ++m)
#pragma unroll
      for (int g = 0; g < 3; ++g) {
        lg[m][g] += __shfl_xor(lg[m][g], 16, 64);
        lg[m][g] += __shfl_xor(lg[m][g], 32, 64);
      }
#pragma unroll
    for (int m = 0; m < 2; ++m) {
      float l0 = lg[m][0] + ga_b[0], l1 = lg[m][1] + ga_b[1], l2 = lg[m][2] + ga_b[2];
      float mx = fmaxf(l0, fmaxf(l1, l2));
      float e0 = expf(l0 - mx), e1 = expf(l1 - mx), e2 = expf(l2 - mx);
      float inv = 1.f / (e0 + e1 + e2);
      float p0 = e0 * inv, p1 = e1 * inv, p2 = e2 * inv;
      if (kg == 0) {
        size_t r = (size_t)(row0g + row0l + m * 16 + cl) * 3;
        probs[r + 0] = p0;
        probs[r + 1] = p1;
        probs[r + 2] = p2;
      }
#pragma unroll
      for (int kk = 0; kk < 8; ++kk) {
        int e0i = kk * 32 + kg * 8;
        short8_t tf;
#pragma unroll
        for (int i = 0; i < 8; ++i) {
          float tv = bf2f(sfr[m][kk][i]) + p0 * gemb[e0i + i] +
                     p1 * gemb[256 + e0i + i] + p2 * gemb[512 + e0i + i];
          tf[i] = f2bf(tv);
        }
        tfr[m][kk] = tf;
      }
    }
  }
  __syncthreads();  // all sf reads done; mid region reusable

  // ===== Stage E: gd1 -> mid, gd2 -> gs_out f32 + gs16 bf16 =====
  for (int ct = 0; ct < 16; ++ct) {
    f32x4_t a0 = (f32x4_t){0.f, 0.f, 0.f, 0.f};
    f32x4_t a1 = (f32x4_t){0.f, 0.f, 0.f, 0.f};
#pragma unroll
    for (int kk = 0; kk < 8; ++kk) {
      short8_t b_h = *(const short8_t*)(Gd1p + (((size_t)ct * 8 + kk) * 64 + lane) * 8);
      MFMA(a0, tfr[0][kk], b_h);
      MFMA(a1, tfr[1][kk], b_h);
    }
    int col = ct * 16 + cl;
    float bv = gd1b[col];
    int c2hi = (col * 2) & ~15, c2lo = (col * 2) & 15;
#pragma unroll
    for (int j = 0; j < 4; ++j) {
      float v0 = fmaxf(a0[j] + bv, 0.f);
      float v1 = fmaxf(a1[j] + bv, 0.f);
      int r0 = row0l + kg * 4 + j;
      int r1 = row0l + 16 + kg * 4 + j;
      int ad0 = ((r0 * 512 + c2hi) ^ ((r0 & 7) << 4)) + c2lo;
      int ad1 = ((r1 * 512 + c2hi) ^ ((r1 & 7) << 4)) + c2lo;
      *(short*)((char*)mid + ad0) = f2bf(v0);
      *(short*)((char*)mid + ad1) = f2bf(v1);
    }
  }
  __syncthreads();
  {
    short8_t ah2[2][8];
#pragma unroll
    for (int m = 0; m < 2; ++m) {
      int row = row0l + m * 16 + cl;
#pragma unroll
      for (int kk = 0; kk < 8; ++kk) {
        int ad = (row * 512 + kk * 64 + kg * 16) ^ ((row & 7) << 4);
        ah2[m][kk] = *(const short8_t*)((const char*)mid + ad);
      }
    }
    for (int ct = 0; ct < 16; ++ct) {
      f32x4_t a0 = (f32x4_t){0.f, 0.f, 0.f, 0.f};
      f32x4_t a1 = (f32x4_t){0.f, 0.f, 0.f, 0.f};
#pragma unroll
      for (int kk = 0; kk < 8; ++kk) {
        short8_t b_h = *(const short8_t*)(Gd2p + (((size_t)ct * 8 + kk) * 64 + lane) * 8);
        MFMA(a0, ah2[0][kk], b_h);
        MFMA(a1, ah2[1][kk], b_h);
      }
      int col = ct * 16 + cl;
      float bv = gd2b[col];
#pragma unroll
      for (int j = 0; j < 4; ++j) {
        float v0 = tanhf(a0[j] + bv);
        float v1 = tanhf(a1[j] + bv);
        size_t r0 = (size_t)(row0g + row0l + kg * 4 + j) * 256 + col;
        size_t r1 = (size_t)(row0g + row0l + 16 + kg * 4 + j) * 256 + col;
        gs_out[r0] = v0;
        gs_out[r1] = v1;
        gs16[r0] = f2bf(v0);
        gs16[r1] = f2bf(v1);
      }
    }
  }
}

// ---------------- MFMA hypernet q v10: half-split, col-major h LDS, ct-pair dbuf --------
__global__ __launch_bounds__(256, 2) void hyper_q_v10_kernel(
    const short* __restrict__ GS16, const float* __restrict__ Hh,
    const short* __restrict__ Wp, const float* __restrict__ hwb,
    float* __restrict__ Qpart) {
  __shared__ short Bh[2][8192];        // 32 KB: two ct-pair buffers
  __shared__ short h_lds[4][64][68];   // 34 KB, col-major: [wave][col][row], stride 68
  const int tid = threadIdx.x;
  const int wave = tid >> 6, lane = tid & 63;
  const int cl = lane & 15, kg = lane >> 4;
  const int half = blockIdx.x >> 8;
  const int wrow = (blockIdx.x & 255) * 256 + wave * 64;
  const int ct_base = half * 128;

  // ---- stage h block col-major: lane owns row `lane` ----
  {
    const float* hp = Hh + (size_t)(wrow + lane) * 128 + half * 64;
#pragma unroll
    for (int c = 0; c < 64; c += 4) {
      float4 u = *(const float4*)(hp + c);
      h_lds[wave][c + 0][lane] = f2bf(u.x);
      h_lds[wave][c + 1][lane] = f2bf(u.y);
      h_lds[wave][c + 2][lane] = f2bf(u.z);
      h_lds[wave][c + 3][lane] = f2bf(u.w);
    }
  }

  // ---- A (gs bf16) -> registers: 4 m-frags x 8 kk ----
  short8_t ah[4][8];
#pragma unroll
  for (int m = 0; m < 4; ++m) {
    const short* ap = GS16 + (size_t)(wrow + m * 16 + cl) * 256;
#pragma unroll
    for (int kk = 0; kk < 8; ++kk) ah[m][kk] = *(const short8_t*)(ap + kk * 32 + kg * 8);
  }

  // ---- prologue: stage ct pair {base, base+1} into buf 0 ----
  {
    const short* wp0 = Wp + (size_t)ct_base * 4096;
#pragma unroll
    for (int k = 0; k < 4; ++k)
      *(short8_t*)&Bh[0][k * 2048 + tid * 8] = *(const short8_t*)(wp0 + k * 2048 + tid * 8);
  }
  __syncthreads();

  float qf[4][2][4] = {};
  int cur = 0;

#define COMPUTE_CT(BUFP, OH, WB)                                               \
  {                                                                            \
    f32x4_t acc[4];                                                            \
    _Pragma("unroll")                                                          \
    for (int m = 0; m < 4; ++m) acc[m] = (f32x4_t){0.f, 0.f, 0.f, 0.f};        \
    _Pragma("unroll")                                                          \
    for (int kk = 0; kk < 8; ++kk) {                                           \
      short8_t b_h = *(const short8_t*)((BUFP) + ((OH) * 4096 + (kk * 64 + lane) * 8)); \
      _Pragma("unroll")                                                        \
      for (int m = 0; m < 4; ++m) MFMA(acc[m], ah[m][kk], b_h);                \
    }                                                                          \
    _Pragma("unroll")                                                          \
    for (int m = 0; m < 4; ++m)                                                \
      _Pragma("unroll")                                                        \
      for (int j = 0; j < 4; ++j)                                              \
        qf[m][OH][j] = fmaf(hc[m * 4 + j], acc[m][j] + (WB), qf[m][OH][j]);    \
  }

  for (int t2 = 0; t2 < 64; ++t2) {
    const int ct0 = ct_base + t2 * 2;
    // h column t2: 4 broadcast b64 reads (per m, 4 consecutive rows)
    float hc[16];
#pragma unroll
    for (int m = 0; m < 4; ++m) {
      short4_t v4 = *(const short4_t*)&h_lds[wave][t2][m * 16 + kg * 4];
#pragma unroll
      for (int j = 0; j < 4; ++j) hc[m * 4 + j] = bf2f(v4[j]);
    }
    float wb0 = hwb[ct0 * 16 + cl];
    float wb1 = hwb[(ct0 + 1) * 16 + cl];
    // prefetch next ct pair to registers
    short8_t s[4];
    if (t2 < 63) {
      const short* wpn = Wp + (size_t)(ct0 + 2) * 4096;
#pragma unroll
      for (int k = 0; k < 4; ++k) s[k] = *(const short8_t*)(wpn + k * 2048 + tid * 8);
    }
    const short* bufp = &Bh[cur][0];
    COMPUTE_CT(bufp, 0, wb0)
    COMPUTE_CT(bufp, 1, wb1)
    if (t2 < 63) {
      short* bufn = &Bh[cur ^ 1][0];
#pragma unroll
      for (int k = 0; k < 4; ++k) *(short8_t*)(bufn + k * 2048 + tid * 8) = s[k];
    }
    __syncthreads();
    cur ^= 1;
  }
#undef COMPUTE_CT

  // ---- half 0 adds fc2_b = gs @ hb_w via packed chunks 256/257 (direct L2) ----
  if (half == 0) {
#pragma unroll
    for (int oh = 0; oh < 2; ++oh) {
      f32x4_t bacc[4];
#pragma unroll
      for (int m = 0; m < 4; ++m) bacc[m] = (f32x4_t){0.f, 0.f, 0.f, 0.f};
#pragma unroll
      for (int kk = 0; kk < 8; ++kk) {
        short8_t b_h = *(const short8_t*)(Wp + (((size_t)(256 + oh) * 8 + kk) * 64 + lane) * 8);
#pragma unroll
        for (int m = 0; m < 4; ++m) MFMA(bacc[m], ah[m][kk], b_h);
      }
#pragma unroll
      for (int m = 0; m < 4; ++m)
#pragma unroll
        for (int j = 0; j < 4; ++j) qf[m][oh][j] += bacc[m][j];
    }
  }

  // ---- write partial q ----
  float* qp = Qpart + (size_t)half * 2097152;
#pragma unroll
  for (int m = 0; m < 4; ++m)
#pragma unroll
    for (int j = 0; j < 4; ++j) {
      const size_t r = (size_t)(wrow + m * 16 + kg * 4 + j) * 32;
      qp[r + cl] = qf[m][0][j];
      qp[r + 16 + cl] = qf[m][1][j];
    }
}

// ---------------- combine: q = qpart0 + qpart1 + hb_b ----------------
__global__ __launch_bounds__(256) void qcombine_kernel(
    const float* __restrict__ Qpart, const float* __restrict__ hbb,
    float* __restrict__ Qout) {
  int i = blockIdx.x * 256 + threadIdx.x;  // 524288 float4s
  float4 a = ((const float4*)Qpart)[i];
  float4 b = ((const float4*)(Qpart + 2097152))[i];
  float4 e = ((const float4*)hbb)[i & 7];
  ((float4*)Qout)[i] = make_float4(a.x + b.x + e.x, a.y + b.y + e.y,
                                   a.z + b.z + e.z, a.w + b.w + e.w);
}

extern "C" void kernel_launch(void* const* d_in, const int* in_sizes, int n_in,
                              void* d_out, int out_size, void* d_ws, size_t ws_size,
                              hipStream_t stream) {
  const float* inputs   = (const float*)d_in[0];
  const float* hidden   = (const float*)d_in[1];
  const float* fc1_w    = (const float*)d_in[2];
  const float* fc1_b    = (const float*)d_in[3];
  const float* gru_wi   = (const float*)d_in[4];
  const float* gru_wh   = (const float*)d_in[5];
  const float* gru_bi   = (const float*)d_in[6];
  const float* gru_bh   = (const float*)d_in[7];
  const float* attn_q_w = (const float*)d_in[8];
  const float* attn_k_w = (const float*)d_in[9];
  const float* se1_w    = (const float*)d_in[10];
  const float* se1_b    = (const float*)d_in[11];
  const float* se2_w    = (const float*)d_in[12];
  const float* se2_b    = (const float*)d_in[13];
  const float* ga_w     = (const float*)d_in[14];
  const float* ga_b     = (const float*)d_in[15];
  const float* gemb     = (const float*)d_in[16];
  const float* gd1_w    = (const float*)d_in[17];
  const float* gd1_b    = (const float*)d_in[18];
  const float* gd2_w    = (const float*)d_in[19];
  const float* gd2_b    = (const float*)d_in[20];
  const float* hb_w     = (const float*)d_in[21];
  const float* hb_b     = (const float*)d_in[22];
  const float* hw_w     = (const float*)d_in[23];
  const float* hw_b     = (const float*)d_in[24];

  float* out = (float*)d_out;
  float* q_out     = out;              // [R,32]
  float* h_out     = out + 2097152;    // [R,128]
  float* gs_out    = out + 10485760;   // [R,256]
  float* probs_out = out + 27262976;   // [R,3]
  float* attn_out  = out + 27459584;   // [B,32,32]

  // workspace layout (bytes), all regions disjoint:
  //   [0,16M):   qpart f32 [2][R,32]
  //   [16M,24M): si bf16 [R,64]
  //   [24M,56M): gs16 bf16 [R,256]
  //   [56M,+2.9M): packs
  char* wsb = (char*)d_ws;
  float* qpart = (float*)wsb;
  short* si   = (short*)(wsb + (size_t)16 * 1024 * 1024);
  short* gs16 = (short*)(wsb + (size_t)24 * 1024 * 1024);
  short* P    = (short*)(wsb + (size_t)56 * 1024 * 1024);

  // pack offsets (shorts); chunk = KK*512 shorts
  const size_t o_hw  = 0;        // K=256 KK=8, N=4096 (+hb chunks 256..257)
  const size_t o_hb  = 1048576;
  const size_t o_fc1 = 1056768;
  const size_t o_wi  = 1077248;
  const size_t o_wh  = 1126400;
  const size_t o_qkq = 1175552;
  const size_t o_qkk = 1191936;  // must be o_qkq + 16384 (attn assumes contiguity)
  const size_t o_se1 = 1208320;
  const size_t o_se2 = 1224704;
  const size_t o_gd1 = 1290240;
  const size_t o_gd2 = 1355776;

  PackArgs pa;
  pa.s[0]  = {hw_w,     256, 4096, 8, 0,    4096, o_hw};
  pa.s[1]  = {hb_w,     256, 32,   8, 4096, 32,   o_hb};
  pa.s[2]  = {fc1_w,    160, 128,  5, 4128, 80,   o_fc1};
  pa.s[3]  = {gru_wi,   128, 384,  4, 4208, 192,  o_wi};
  pa.s[4]  = {gru_wh,   128, 384,  4, 4400, 192,  o_wh};
  pa.s[5]  = {attn_q_w, 128, 128,  4, 4592, 64,   o_qkq};
  pa.s[6]  = {attn_k_w, 128, 128,  4, 4656, 64,   o_qkk};
  pa.s[7]  = {se1_w,    34,  256,  2, 4720, 64,   o_se1};
  pa.s[8]  = {se2_w,    256, 256,  8, 4784, 256,  o_se2};
  pa.s[9]  = {gd1_w,    256, 256,  8, 5040, 256,  o_gd1};
  pa.s[10] = {gd2_w,    256, 256,  8, 5296, 256,  o_gd2};

  dim3 blk(256);
  // 0) pack ALL weights in one launch
  pack_all_kernel<<<5552, blk, 0, stream>>>(pa, P);
  // 1) h = GRUCell(relu(inputs@fc1+b), hidden) -> h_out f32  (fc1 fused)
  gru_fused_kernel<<<512, blk, 0, stream>>>(inputs, hidden, P + o_fc1, fc1_b,
                                            P + o_wi, P + o_wh, gru_bi, gru_bh, h_out);
  // 2) attention (standalone, 2048 blocks) -> attn_out f32 + si bf16
  attn_fused_kernel<<<2048, blk, 0, stream>>>(h_out, P + o_qkq, attn_out, si);
  // 3) se1+se2+group+gd1+gd2 fused -> probs + gs_out f32 + gs16 bf16
  se_gd_kernel<<<512, blk, 0, stream>>>(si, P + o_se1, se1_b, P + o_se2, se2_b,
                                        ga_w, ga_b, gemb, probs_out,
                                        P + o_gd1, gd1_b, P + o_gd2, gd2_b,
                                        gs_out, gs16);
  // 4) q partials: half-split, col-major h LDS, ct-pair-dbuf MFMA hypernet
  hyper_q_v10_kernel<<<dim3(512), blk, 0, stream>>>(gs16, h_out, P + o_hw, hw_b, qpart);
  // 5) q = qpart0 + qpart1 + hb_b
  qcombine_kernel<<<2048, blk, 0, stream>>>(qpart, hb_b, q_out);
}

// Round 15
// 264.152 us; speedup vs baseline: 2.5232x; 1.2606x over previous
//
#include <hip/hip_runtime.h>
#include <math.h>

// B=2048, A=32 -> R=65536 rows. E_IN=160, H=128, HE=256, NACT=32, G=3, TAU=1.
#define R_TOTAL 65536

typedef __attribute__((ext_vector_type(8))) short short8_t;
typedef __attribute__((ext_vector_type(4))) short short4_t;
typedef __attribute__((ext_vector_type(4))) float f32x4_t;

__device__ __forceinline__ float frcp_(float x) { return __builtin_amdgcn_rcpf(x); }
__device__ __forceinline__ float fast_sigmoid(float x) { return frcp_(1.f + __expf(-x)); }
__device__ __forceinline__ float fast_tanh(float x) {
  float xc = fminf(fmaxf(x, -15.f), 15.f);
  float t = __expf(2.f * xc);
  return (t - 1.f) * frcp_(t + 1.f);
}

__device__ __forceinline__ short f2bf(float x) {
  unsigned u = __float_as_uint(x);
  u += 0x7fff + ((u >> 16) & 1);   // round-to-nearest-even
  return (short)(u >> 16);
}
__device__ __forceinline__ float bf2f(short s) {
  return __uint_as_float(((unsigned)(unsigned short)s) << 16);
}

// Load 8 consecutive floats -> bf16 fragment (RNE).
__device__ __forceinline__ void load_afrag(const float* p, short8_t& h) {
  float4 u0 = *(const float4*)p;
  float4 u1 = *(const float4*)(p + 4);
  float v[8] = {u0.x, u0.y, u0.z, u0.w, u1.x, u1.y, u1.z, u1.w};
#pragma unroll
  for (int i = 0; i < 8; ++i) h[i] = f2bf(v[i]);
}

#define MFMA(ACC, A, B) ACC = __builtin_amdgcn_mfma_f32_16x16x32_bf16(A, B, ACC, 0, 0, 0)

// ---------------- fused fragment pack: all weights in one launch ----------------
struct PackSeg {
  const float* W;
  int Ksrc, N, KK, blk0, nblk;
  size_t off;
};
struct PackArgs { PackSeg s[11]; };

__global__ __launch_bounds__(256) void pack_all_kernel(PackArgs a, short* __restrict__ P) {
  const int b = blockIdx.x;
  PackSeg seg = a.s[0];
#pragma unroll
  for (int i = 1; i < 11; ++i)
    if (b >= a.s[i].blk0) seg = a.s[i];
  int p = (b - seg.blk0) * 256 + threadIdx.x;
  int i = p & 7, lane = (p >> 3) & 63, kk = (p >> 9) % seg.KK, ct = p / (seg.KK * 512);
  int e = kk * 32 + (lane >> 4) * 8 + i;
  int c = ct * 16 + (lane & 15);
  float w = (e < seg.Ksrc) ? seg.W[(size_t)e * seg.N + c] : 0.f;
  P[seg.off + p] = f2bf(w);
}

// ---------------- fused fc1 + GRU: 64-row blocks, 1 m-frag/wave (grid 1024) ----------------
__global__ __launch_bounds__(256, 4) void gru_fused_kernel(
    const float* __restrict__ inputs, const float* __restrict__ Hin,
    const short* __restrict__ Fc1p, const float* __restrict__ fc1b,
    const short* __restrict__ WiP, const short* __restrict__ WhP,
    const float* __restrict__ gbi, const float* __restrict__ gbh,
    float* __restrict__ Hout) {
  __shared__ short mid[64 * 128];   // 16 KB, 256B rows, XOR-swizzled
  const int tid = threadIdx.x;
  const int wave = tid >> 6, lane = tid & 63;
  const int cl = lane & 15, kg = lane >> 4;
  const int row0g = blockIdx.x * 64 + wave * 16;
  const int row0l = wave * 16;

  // ---- stage 1: x = relu(inputs @ fc1 + b) ----
  {
    short8_t ah1[5];
    {
      const float* ap = inputs + (size_t)(row0g + cl) * 160;
#pragma unroll
      for (int kk = 0; kk < 5; ++kk) load_afrag(ap + kk * 32 + kg * 8, ah1[kk]);
    }
    for (int ct = 0; ct < 8; ++ct) {
      f32x4_t a0 = (f32x4_t){0.f, 0.f, 0.f, 0.f};
#pragma unroll
      for (int kk = 0; kk < 5; ++kk) {
        short8_t b_h = *(const short8_t*)(Fc1p + (((size_t)ct * 5 + kk) * 64 + lane) * 8);
        MFMA(a0, ah1[kk], b_h);
      }
      int col = ct * 16 + cl;
      float bv = fc1b[col];
      int c2hi = (col * 2) & ~15, c2lo = (col * 2) & 15;
#pragma unroll
      for (int j = 0; j < 4; ++j) {
        float v0 = fmaxf(a0[j] + bv, 0.f);
        int r0 = row0l + kg * 4 + j;
        int ad0 = ((r0 * 256 + c2hi) ^ ((r0 & 7) << 4)) + c2lo;
        *(short*)((char*)mid + ad0) = f2bf(v0);
      }
    }
  }
  __syncthreads();

  // ---- stage 2: GRU ----
  short8_t xh[4], hh[4];
  {
    int row = row0l + cl;
    const float* hp = Hin + (size_t)(row0g + cl) * 128;
#pragma unroll
    for (int kk = 0; kk < 4; ++kk) {
      int ad = (row * 256 + kk * 64 + kg * 16) ^ ((row & 7) << 4);
      xh[kk] = *(const short8_t*)((const char*)mid + ad);
      load_afrag(hp + kk * 32 + kg * 8, hh[kk]);
    }
  }
#define GLOAD(P, CT) *(const short8_t*)((P) + (((size_t)(CT) * 4 + kk) * 64 + lane) * 8)
  for (int ct = 0; ct < 8; ++ct) {
    f32x4_t aXr = (f32x4_t){0.f, 0.f, 0.f, 0.f}, aXz = aXr, aXn = aXr;
    f32x4_t aHr = aXr, aHz = aXr, aHn = aXr;
#pragma unroll
    for (int kk = 0; kk < 4; ++kk) {
      short8_t b_h;
      b_h = GLOAD(WiP, ct);      MFMA(aXr, xh[kk], b_h);
      b_h = GLOAD(WiP, ct + 8);  MFMA(aXz, xh[kk], b_h);
      b_h = GLOAD(WiP, ct + 16); MFMA(aXn, xh[kk], b_h);
      b_h = GLOAD(WhP, ct);      MFMA(aHr, hh[kk], b_h);
      b_h = GLOAD(WhP, ct + 8);  MFMA(aHz, hh[kk], b_h);
      b_h = GLOAD(WhP, ct + 16); MFMA(aHn, hh[kk], b_h);
    }
    int col = ct * 16 + cl;
    float bir = gbi[col], biz = gbi[128 + col], bin = gbi[256 + col];
    float bhr = gbh[col], bhz = gbh[128 + col], bhn = gbh[256 + col];
#pragma unroll
    for (int j = 0; j < 4; ++j) {
      int row = row0g + kg * 4 + j;
      float rg = fast_sigmoid(aXr[j] + aHr[j] + bir + bhr);
      float zg = fast_sigmoid(aXz[j] + aHz[j] + biz + bhz);
      float ng = fast_tanh(aXn[j] + bin + rg * (aHn[j] + bhn));
      float hv = Hin[(size_t)row * 128 + col];
      Hout[(size_t)row * 128 + col] = (1.f - zg) * ng + zg * hv;
    }
  }
#undef GLOAD
}

// ---------------- fused attention: MFMA proj + MFMA scores + parallel softmax ------------
__global__ __launch_bounds__(256) void attn_fused_kernel(
    const float* __restrict__ Hh, const short* __restrict__ QKp,
    float* __restrict__ attn_out, short* __restrict__ si) {
  __shared__ short qkb[2][32 * 128];   // 2 x 8 KB, 256B rows, XOR-swizzled
  __shared__ float p[32][33];
  __shared__ float a2[32][33];
  const int b = blockIdx.x;
  const int tid = threadIdx.x;
  const int wave = tid >> 6, lane = tid & 63;
  const int cl = lane & 15, kg = lane >> 4;

  // ---- proj: q/k = h @ Wq/Wk -> bf16 LDS ----
  {
    short8_t ahf[2][4];
#pragma unroll
    for (int m = 0; m < 2; ++m) {
      const float* ap = Hh + (size_t)(b * 32 + m * 16 + cl) * 128;
#pragma unroll
      for (int kk = 0; kk < 4; ++kk) load_afrag(ap + kk * 32 + kg * 8, ahf[m][kk]);
    }
    const int proj = wave >> 1;
    const short* Wbase = QKp + (size_t)proj * 16384;
    short* dst = &qkb[proj][0];
#pragma unroll
    for (int ct4 = 0; ct4 < 4; ++ct4) {
      int ct = (wave & 1) * 4 + ct4;
      f32x4_t a0 = (f32x4_t){0.f, 0.f, 0.f, 0.f};
      f32x4_t a1 = (f32x4_t){0.f, 0.f, 0.f, 0.f};
#pragma unroll
      for (int kk = 0; kk < 4; ++kk) {
        short8_t b_h = *(const short8_t*)(Wbase + (((size_t)ct * 4 + kk) * 64 + lane) * 8);
        MFMA(a0, ahf[0][kk], b_h);
        MFMA(a1, ahf[1][kk], b_h);
      }
      int col = ct * 16 + cl;
      int c2hi = (col * 2) & ~15, c2lo = (col * 2) & 15;
#pragma unroll
      for (int j = 0; j < 4; ++j) {
        int r0 = kg * 4 + j;
        int r1 = 16 + kg * 4 + j;
        int ad0 = ((r0 * 256 + c2hi) ^ ((r0 & 7) << 4)) + c2lo;
        int ad1 = ((r1 * 256 + c2hi) ^ ((r1 & 7) << 4)) + c2lo;
        *(short*)((char*)dst + ad0) = f2bf(a0[j]);
        *(short*)((char*)dst + ad1) = f2bf(a1[j]);
      }
    }
  }
  __syncthreads();

  // ---- scores via MFMA: wave computes tile (mi, nj) ----
  {
    const int mi = wave >> 1, nj = wave & 1;
    short8_t qf[4], kf[4];
    int rq = mi * 16 + cl, rk = nj * 16 + cl;
#pragma unroll
    for (int kk = 0; kk < 4; ++kk) {
      int adq = (rq * 256 + kk * 64 + kg * 16) ^ ((rq & 7) << 4);
      int adk = (rk * 256 + kk * 64 + kg * 16) ^ ((rk & 7) << 4);
      qf[kk] = *(const short8_t*)((const char*)&qkb[0][0] + adq);
      kf[kk] = *(const short8_t*)((const char*)&qkb[1][0] + adk);
    }
    f32x4_t acc = (f32x4_t){0.f, 0.f, 0.f, 0.f};
#pragma unroll
    for (int kk = 0; kk < 4; ++kk) MFMA(acc, qf[kk], kf[kk]);
    const float scale = 0.088388347648318447f;  // 1/sqrt(128)
#pragma unroll
    for (int j = 0; j < 4; ++j) {
      int r = mi * 16 + kg * 4 + j;
      int c = nj * 16 + cl;
      p[r][c] = (r == c) ? -1e9f : acc[j] * scale;
    }
  }
  __syncthreads();

  // ---- softmax: 8 threads per row ----
  {
    int row = tid >> 3, g = tid & 7;
    float v[4];
    float mx = -1e30f;
#pragma unroll
    for (int c0 = 0; c0 < 4; ++c0) {
      v[c0] = p[row][g * 4 + c0];
      mx = fmaxf(mx, v[c0]);
    }
#pragma unroll
    for (int off = 1; off < 8; off <<= 1) mx = fmaxf(mx, __shfl_xor(mx, off, 64));
    float s = 0.f;
#pragma unroll
    for (int c0 = 0; c0 < 4; ++c0) {
      v[c0] = __expf(v[c0] - mx);
      s += v[c0];
    }
#pragma unroll
    for (int off = 1; off < 8; off <<= 1) s += __shfl_xor(s, off, 64);
    float inv = frcp_(s);
#pragma unroll
    for (int c0 = 0; c0 < 4; ++c0) p[row][g * 4 + c0] = v[c0] * inv;
  }
  __syncthreads();

  // ---- symmetrize + attn_out ----
#pragma unroll
  for (int tI = 0; tI < 4; ++tI) {
    int t = tid + tI * 256;
    int i = t >> 5, j = t & 31;
    float v = (i == j) ? 0.f : 0.5f * (p[i][j] + p[j][i]);
    a2[i][j] = v;
    attn_out[(size_t)b * 1024 + t] = v;
  }
  __syncthreads();

  // ---- struct input: 8 threads per row ----
  {
    int row = tid >> 3, g = tid & 7;
    float vv[4];
    float d = 0.f, en = 0.f;
#pragma unroll
    for (int c0 = 0; c0 < 4; ++c0) {
      float v = a2[row][g * 4 + c0];
      vv[c0] = v;
      d += v;
      float c = fmaxf(v, 1e-8f);
      en -= c * __logf(c);
    }
#pragma unroll
    for (int off = 1; off < 8; off <<= 1) {
      d += __shfl_xor(d, off, 64);
      en += __shfl_xor(en, off, 64);
    }
    short* srow = si + ((size_t)b * 32 + row) * 64;
#pragma unroll
    for (int c0 = 0; c0 < 4; ++c0) srow[g * 4 + c0] = f2bf(vv[c0]);
    if (g == 0) {
      srow[32] = f2bf(d);
      srow[33] = f2bf(en);
    }
    for (int z = 34 + g; z < 64; z += 8) srow[z] = 0;
  }
}

// ---------------- fused se1+se2+group+gd1+gd2: 64-row blocks, 1 m-frag/wave (grid 1024) ----
__global__ __launch_bounds__(256, 4) void se_gd_kernel(
    const short* __restrict__ SI,
    const short* __restrict__ Se1p, const float* __restrict__ se1b,
    const short* __restrict__ Se2p, const float* __restrict__ se2b,
    const float* __restrict__ ga_w, const float* __restrict__ ga_b,
    const float* __restrict__ gemb, float* __restrict__ probs,
    const short* __restrict__ Gd1p, const float* __restrict__ gd1b,
    const short* __restrict__ Gd2p, const float* __restrict__ gd2b,
    float* __restrict__ gs_out, short* __restrict__ gs16) {
  __shared__ short mid[64 * 256];   // 32 KB, 512B rows, XOR-swizzled
  const int tid = threadIdx.x;
  const int wave = tid >> 6, lane = tid & 63;
  const int cl = lane & 15, kg = lane >> 4;
  const int row0g = blockIdx.x * 64;
  const int row0l = wave * 16;

  // ===== se1 -> mid =====
  {
    short8_t ah1[2];
    {
      const short* ap = SI + (size_t)(row0g + row0l + cl) * 64;
#pragma unroll
      for (int kk = 0; kk < 2; ++kk)
        ah1[kk] = *(const short8_t*)(ap + kk * 32 + kg * 8);
    }
    for (int ct = 0; ct < 16; ++ct) {
      f32x4_t a0 = (f32x4_t){0.f, 0.f, 0.f, 0.f};
#pragma unroll
      for (int kk = 0; kk < 2; ++kk) {
        short8_t b_h = *(const short8_t*)(Se1p + (((size_t)ct * 2 + kk) * 64 + lane) * 8);
        MFMA(a0, ah1[kk], b_h);
      }
      int col = ct * 16 + cl;
      float bv = se1b[col];
      int c2hi = (col * 2) & ~15, c2lo = (col * 2) & 15;
#pragma unroll
      for (int j = 0; j < 4; ++j) {
        float v0 = fmaxf(a0[j] + bv, 0.f);
        int r0 = row0l + kg * 4 + j;
        int ad0 = ((r0 * 512 + c2hi) ^ ((r0 & 7) << 4)) + c2lo;
        *(short*)((char*)mid + ad0) = f2bf(v0);
      }
    }
  }
  __syncthreads();

  // ===== se2 -> sf (back into mid) =====
  {
    short8_t ah2[8];
    {
      int row = row0l + cl;
#pragma unroll
      for (int kk = 0; kk < 8; ++kk) {
        int ad = (row * 512 + kk * 64 + kg * 16) ^ ((row & 7) << 4);
        ah2[kk] = *(const short8_t*)((const char*)mid + ad);
      }
    }
    __syncthreads();  // all mid reads done; region reusable as sf
    for (int ct = 0; ct < 16; ++ct) {
      f32x4_t a0 = (f32x4_t){0.f, 0.f, 0.f, 0.f};
#pragma unroll
      for (int kk = 0; kk < 8; ++kk) {
        short8_t b_h = *(const short8_t*)(Se2p + (((size_t)ct * 8 + kk) * 64 + lane) * 8);
        MFMA(a0, ah2[kk], b_h);
      }
      int col = ct * 16 + cl;
      float bv = se2b[col];
      int c2hi = (col * 2) & ~15, c2lo = (col * 2) & 15;
#pragma unroll
      for (int j = 0; j < 4; ++j) {
        float v0 = fast_tanh(a0[j] + bv);
        int r0 = row0l + kg * 4 + j;
        int ad0 = ((r0 * 512 + c2hi) ^ ((r0 & 7) << 4)) + c2lo;
        *(short*)((char*)mid + ad0) = f2bf(v0);
      }
    }
  }
  __syncthreads();

  // ===== group assign -> probs + t frags =====
  short8_t tfr[8];
  {
    short8_t sfr[8];
    float lg[3] = {};
    {
      int row = row0l + cl;
#pragma unroll
      for (int kk = 0; kk < 8; ++kk) {
        int ad = (row * 512 + kk * 64 + kg * 16) ^ ((row & 7) << 4);
        short8_t s = *(const short8_t*)((const char*)mid + ad);
        sfr[kk] = s;
        int e0 = kk * 32 + kg * 8;
#pragma unroll
        for (int i = 0; i < 8; ++i) {
          float v = bf2f(s[i]);
          lg[0] = fmaf(v, ga_w[(e0 + i) * 3 + 0], lg[0]);
          lg[1] = fmaf(v, ga_w[(e0 + i) * 3 + 1], lg[1]);
          lg[2] = fmaf(v, ga_w[(e0 + i) * 3 + 2], lg[2]);
        }
      }
    }
#pragma unroll
    for (int g = 0; g < 3; ++g) {
      lg[g] += __shfl_xor(lg[g], 16, 64);
      lg[g] += __shfl_xor(lg[g], 32, 64);
    }
    float l0 = lg[0] + ga_b[0], l1 = lg[1] + ga_b[1], l2 = lg[2] + ga_b[2];
    float mx = fmaxf(l0, fmaxf(l1, l2));
    float e0 = __expf(l0 - mx), e1 = __expf(l1 - mx), e2 = __expf(l2 - mx);
    float inv = frcp_(e0 + e1 + e2);
    float p0 = e0 * inv, p1 = e1 * inv, p2 = e2 * inv;
    if (kg == 0) {
      size_t r = (size_t)(row0g + row0l + cl) * 3;
      probs[r + 0] = p0;
      probs[r + 1] = p1;
      probs[r + 2] = p2;
    }
#pragma unroll
    for (int kk = 0; kk < 8; ++kk) {
      int e0i = kk * 32 + kg * 8;
      short8_t tf;
#pragma unroll
      for (int i = 0; i < 8; ++i) {
        float tv = bf2f(sfr[kk][i]) + p0 * gemb[e0i + i] +
                   p1 * gemb[256 + e0i + i] + p2 * gemb[512 + e0i + i];
        tf[i] = f2bf(tv);
      }
      tfr[kk] = tf;
    }
  }
  __syncthreads();  // all sf reads done; mid region reusable

  // ===== gd1 -> mid, gd2 -> gs_out f32 + gs16 bf16 =====
  for (int ct = 0; ct < 16; ++ct) {
    f32x4_t a0 = (f32x4_t){0.f, 0.f, 0.f, 0.f};
#pragma unroll
    for (int kk = 0; kk < 8; ++kk) {
      short8_t b_h = *(const short8_t*)(Gd1p + (((size_t)ct * 8 + kk) * 64 + lane) * 8);
      MFMA(a0, tfr[kk], b_h);
    }
    int col = ct * 16 + cl;
    float bv = gd1b[col];
    int c2hi = (col * 2) & ~15, c2lo = (col * 2) & 15;
#pragma unroll
    for (int j = 0; j < 4; ++j) {
      float v0 = fmaxf(a0[j] + bv, 0.f);
      int r0 = row0l + kg * 4 + j;
      int ad0 = ((r0 * 512 + c2hi) ^ ((r0 & 7) << 4)) + c2lo;
      *(short*)((char*)mid + ad0) = f2bf(v0);
    }
  }
  __syncthreads();
  {
    short8_t ah2[8];
    {
      int row = row0l + cl;
#pragma unroll
      for (int kk = 0; kk < 8; ++kk) {
        int ad = (row * 512 + kk * 64 + kg * 16) ^ ((row & 7) << 4);
        ah2[kk] = *(const short8_t*)((const char*)mid + ad);
      }
    }
    for (int ct = 0; ct < 16; ++ct) {
      f32x4_t a0 = (f32x4_t){0.f, 0.f, 0.f, 0.f};
#pragma unroll
      for (int kk = 0; kk < 8; ++kk) {
        short8_t b_h = *(const short8_t*)(Gd2p + (((size_t)ct * 8 + kk) * 64 + lane) * 8);
        MFMA(a0, ah2[kk], b_h);
      }
      int col = ct * 16 + cl;
      float bv = gd2b[col];
#pragma unroll
      for (int j = 0; j < 4; ++j) {
        float v0 = fast_tanh(a0[j] + bv);
        size_t r0 = (size_t)(row0g + row0l + kg * 4 + j) * 256 + col;
        gs_out[r0] = v0;
        gs16[r0] = f2bf(v0);
      }
    }
  }
}

// ---------------- MFMA hypernet q v10: half-split, col-major h LDS, ct-pair dbuf --------
__global__ __launch_bounds__(256, 2) void hyper_q_v10_kernel(
    const short* __restrict__ GS16, const float* __restrict__ Hh,
    const short* __restrict__ Wp, const float* __restrict__ hwb,
    float* __restrict__ Qpart) {
  __shared__ short Bh[2][8192];        // 32 KB: two ct-pair buffers
  __shared__ short h_lds[4][64][68];   // 34 KB, col-major: [wave][col][row], stride 68
  const int tid = threadIdx.x;
  const int wave = tid >> 6, lane = tid & 63;
  const int cl = lane & 15, kg = lane >> 4;
  const int half = blockIdx.x >> 8;
  const int wrow = (blockIdx.x & 255) * 256 + wave * 64;
  const int ct_base = half * 128;

  // ---- stage h block col-major: lane owns row `lane` ----
  {
    const float* hp = Hh + (size_t)(wrow + lane) * 128 + half * 64;
#pragma unroll
    for (int c = 0; c < 64; c += 4) {
      float4 u = *(const float4*)(hp + c);
      h_lds[wave][c + 0][lane] = f2bf(u.x);
      h_lds[wave][c + 1][lane] = f2bf(u.y);
      h_lds[wave][c + 2][lane] = f2bf(u.z);
      h_lds[wave][c + 3][lane] = f2bf(u.w);
    }
  }

  // ---- A (gs bf16) -> registers: 4 m-frags x 8 kk ----
  short8_t ah[4][8];
#pragma unroll
  for (int m = 0; m < 4; ++m) {
    const short* ap = GS16 + (size_t)(wrow + m * 16 + cl) * 256;
#pragma unroll
    for (int kk = 0; kk < 8; ++kk) ah[m][kk] = *(const short8_t*)(ap + kk * 32 + kg * 8);
  }

  // ---- prologue: stage ct pair {base, base+1} into buf 0 ----
  {
    const short* wp0 = Wp + (size_t)ct_base * 4096;
#pragma unroll
    for (int k = 0; k < 4; ++k)
      *(short8_t*)&Bh[0][k * 2048 + tid * 8] = *(const short8_t*)(wp0 + k * 2048 + tid * 8);
  }
  __syncthreads();

  float qf[4][2][4] = {};
  int cur = 0;

#define COMPUTE_CT(BUFP, OH, WB)                                               \
  {                                                                            \
    f32x4_t acc[4];                                                            \
    _Pragma("unroll")                                                          \
    for (int m = 0; m < 4; ++m) acc[m] = (f32x4_t){0.f, 0.f, 0.f, 0.f};        \
    _Pragma("unroll")                                                          \
    for (int kk = 0; kk < 8; ++kk) {                                           \
      short8_t b_h = *(const short8_t*)((BUFP) + ((OH) * 4096 + (kk * 64 + lane) * 8)); \
      _Pragma("unroll")                                                        \
      for (int m = 0; m < 4; ++m) MFMA(acc[m], ah[m][kk], b_h);                \
    }                                                                          \
    _Pragma("unroll")                                                          \
    for (int m = 0; m < 4; ++m)                                                \
      _Pragma("unroll")                                                        \
      for (int j = 0; j < 4; ++j)                                              \
        qf[m][OH][j] = fmaf(hc[m * 4 + j], acc[m][j] + (WB), qf[m][OH][j]);    \
  }

  for (int t2 = 0; t2 < 64; ++t2) {
    const int ct0 = ct_base + t2 * 2;
    // h column t2: 4 broadcast b64 reads (per m, 4 consecutive rows)
    float hc[16];
#pragma unroll
    for (int m = 0; m < 4; ++m) {
      short4_t v4 = *(const short4_t*)&h_lds[wave][t2][m * 16 + kg * 4];
#pragma unroll
      for (int j = 0; j < 4; ++j) hc[m * 4 + j] = bf2f(v4[j]);
    }
    float wb0 = hwb[ct0 * 16 + cl];
    float wb1 = hwb[(ct0 + 1) * 16 + cl];
    // prefetch next ct pair to registers
    short8_t s[4];
    if (t2 < 63) {
      const short* wpn = Wp + (size_t)(ct0 + 2) * 4096;
#pragma unroll
      for (int k = 0; k < 4; ++k) s[k] = *(const short8_t*)(wpn + k * 2048 + tid * 8);
    }
    const short* bufp = &Bh[cur][0];
    COMPUTE_CT(bufp, 0, wb0)
    COMPUTE_CT(bufp, 1, wb1)
    if (t2 < 63) {
      short* bufn = &Bh[cur ^ 1][0];
#pragma unroll
      for (int k = 0; k < 4; ++k) *(short8_t*)(bufn + k * 2048 + tid * 8) = s[k];
    }
    __syncthreads();
    cur ^= 1;
  }
#undef COMPUTE_CT

  // ---- half 0 adds fc2_b = gs @ hb_w via packed chunks 256/257 (direct L2) ----
  if (half == 0) {
#pragma unroll
    for (int oh = 0; oh < 2; ++oh) {
      f32x4_t bacc[4];
#pragma unroll
      for (int m = 0; m < 4; ++m) bacc[m] = (f32x4_t){0.f, 0.f, 0.f, 0.f};
#pragma unroll
      for (int kk = 0; kk < 8; ++kk) {
        short8_t b_h = *(const short8_t*)(Wp + (((size_t)(256 + oh) * 8 + kk) * 64 + lane) * 8);
#pragma unroll
        for (int m = 0; m < 4; ++m) MFMA(bacc[m], ah[m][kk], b_h);
      }
#pragma unroll
      for (int m = 0; m < 4; ++m)
#pragma unroll
        for (int j = 0; j < 4; ++j) qf[m][oh][j] += bacc[m][j];
    }
  }

  // ---- write partial q ----
  float* qp = Qpart + (size_t)half * 2097152;
#pragma unroll
  for (int m = 0; m < 4; ++m)
#pragma unroll
    for (int j = 0; j < 4; ++j) {
      const size_t r = (size_t)(wrow + m * 16 + kg * 4 + j) * 32;
      qp[r + cl] = qf[m][0][j];
      qp[r + 16 + cl] = qf[m][1][j];
    }
}

// ---------------- combine: q = qpart0 + qpart1 + hb_b ----------------
__global__ __launch_bounds__(256) void qcombine_kernel(
    const float* __restrict__ Qpart, const float* __restrict__ hbb,
    float* __restrict__ Qout) {
  int i = blockIdx.x * 256 + threadIdx.x;  // 524288 float4s
  float4 a = ((const float4*)Qpart)[i];
  float4 b = ((const float4*)(Qpart + 2097152))[i];
  float4 e = ((const float4*)hbb)[i & 7];
  ((float4*)Qout)[i] = make_float4(a.x + b.x + e.x, a.y + b.y + e.y,
                                   a.z + b.z + e.z, a.w + b.w + e.w);
}

extern "C" void kernel_launch(void* const* d_in, const int* in_sizes, int n_in,
                              void* d_out, int out_size, void* d_ws, size_t ws_size,
                              hipStream_t stream) {
  const float* inputs   = (const float*)d_in[0];
  const float* hidden   = (const float*)d_in[1];
  const float* fc1_w    = (const float*)d_in[2];
  const float* fc1_b    = (const float*)d_in[3];
  const float* gru_wi   = (const float*)d_in[4];
  const float* gru_wh   = (const float*)d_in[5];
  const float* gru_bi   = (const float*)d_in[6];
  const float* gru_bh   = (const float*)d_in[7];
  const float* attn_q_w = (const float*)d_in[8];
  const float* attn_k_w = (const float*)d_in[9];
  const float* se1_w    = (const float*)d_in[10];
  const float* se1_b    = (const float*)d_in[11];
  const float* se2_w    = (const float*)d_in[12];
  const float* se2_b    = (const float*)d_in[13];
  const float* ga_w     = (const float*)d_in[14];
  const float* ga_b     = (const float*)d_in[15];
  const float* gemb     = (const float*)d_in[16];
  const float* gd1_w    = (const float*)d_in[17];
  const float* gd1_b    = (const float*)d_in[18];
  const float* gd2_w    = (const float*)d_in[19];
  const float* gd2_b    = (const float*)d_in[20];
  const float* hb_w     = (const float*)d_in[21];
  const float* hb_b     = (const float*)d_in[22];
  const float* hw_w     = (const float*)d_in[23];
  const float* hw_b     = (const float*)d_in[24];

  float* out = (float*)d_out;
  float* q_out     = out;              // [R,32]
  float* h_out     = out + 2097152;    // [R,128]
  float* gs_out    = out + 10485760;   // [R,256]
  float* probs_out = out + 27262976;   // [R,3]
  float* attn_out  = out + 27459584;   // [B,32,32]

  // workspace layout (bytes), all regions disjoint:
  //   [0,16M):   qpart f32 [2][R,32]
  //   [16M,24M): si bf16 [R,64]
  //   [24M,56M): gs16 bf16 [R,256]
  //   [56M,+2.9M): packs
  char* wsb = (char*)d_ws;
  float* qpart = (float*)wsb;
  short* si   = (short*)(wsb + (size_t)16 * 1024 * 1024);
  short* gs16 = (short*)(wsb + (size_t)24 * 1024 * 1024);
  short* P    = (short*)(wsb + (size_t)56 * 1024 * 1024);

  // pack offsets (shorts); chunk = KK*512 shorts
  const size_t o_hw  = 0;        // K=256 KK=8, N=4096 (+hb chunks 256..257)
  const size_t o_hb  = 1048576;
  const size_t o_fc1 = 1056768;
  const size_t o_wi  = 1077248;
  const size_t o_wh  = 1126400;
  const size_t o_qkq = 1175552;
  const size_t o_qkk = 1191936;  // must be o_qkq + 16384 (attn assumes contiguity)
  const size_t o_se1 = 1208320;
  const size_t o_se2 = 1224704;
  const size_t o_gd1 = 1290240;
  const size_t o_gd2 = 1355776;

  PackArgs pa;
  pa.s[0]  = {hw_w,     256, 4096, 8, 0,    4096, o_hw};
  pa.s[1]  = {hb_w,     256, 32,   8, 4096, 32,   o_hb};
  pa.s[2]  = {fc1_w,    160, 128,  5, 4128, 80,   o_fc1};
  pa.s[3]  = {gru_wi,   128, 384,  4, 4208, 192,  o_wi};
  pa.s[4]  = {gru_wh,   128, 384,  4, 4400, 192,  o_wh};
  pa.s[5]  = {attn_q_w, 128, 128,  4, 4592, 64,   o_qkq};
  pa.s[6]  = {attn_k_w, 128, 128,  4, 4656, 64,   o_qkk};
  pa.s[7]  = {se1_w,    34,  256,  2, 4720, 64,   o_se1};
  pa.s[8]  = {se2_w,    256, 256,  8, 4784, 256,  o_se2};
  pa.s[9]  = {gd1_w,    256, 256,  8, 5040, 256,  o_gd1};
  pa.s[10] = {gd2_w,    256, 256,  8, 5296, 256,  o_gd2};

  dim3 blk(256);
  // 0) pack ALL weights in one launch
  pack_all_kernel<<<5552, blk, 0, stream>>>(pa, P);
  // 1) h = GRUCell(relu(inputs@fc1+b), hidden) -> h_out f32  (64-row blocks)
  gru_fused_kernel<<<1024, blk, 0, stream>>>(inputs, hidden, P + o_fc1, fc1_b,
                                             P + o_wi, P + o_wh, gru_bi, gru_bh, h_out);
  // 2) attention (standalone, 2048 blocks) -> attn_out f32 + si bf16
  attn_fused_kernel<<<2048, blk, 0, stream>>>(h_out, P + o_qkq, attn_out, si);
  // 3) se1+se2+group+gd1+gd2 fused (64-row blocks) -> probs + gs_out f32 + gs16 bf16
  se_gd_kernel<<<1024, blk, 0, stream>>>(si, P + o_se1, se1_b, P + o_se2, se2_b,
                                         ga_w, ga_b, gemb, probs_out,
                                         P + o_gd1, gd1_b, P + o_gd2, gd2_b,
                                         gs_out, gs16);
  // 4) q partials: half-split, col-major h LDS, ct-pair-dbuf MFMA hypernet
  hyper_q_v10_kernel<<<dim3(512), blk, 0, stream>>>(gs16, h_out, P + o_hw, hw_b, qpart);
  // 5) q = qpart0 + qpart1 + hb_b
  qcombine_kernel<<<2048, blk, 0, stream>>>(qpart, hb_b, q_out);
}